// Round 1
// baseline (538.611 us; speedup 1.0000x reference)
//
#include <hip/hip_runtime.h>
#include <hip/hip_bf16.h>
#include <stdint.h>

typedef unsigned short u16;
typedef __attribute__((ext_vector_type(8))) short bf16x8;
typedef __attribute__((ext_vector_type(4))) float f32x4;

#define S_LEN 577
#define DMODEL 768
#define NHEAD 12
#define DH 64
#define BATCH 16
#define M_ROWS (BATCH * S_LEN)   /* 9232 */
#define M_PAD 9344               /* 73 * 128 */
#define VT_STRIDE 640            /* padded S so 16B frag loads stay aligned */

__device__ __forceinline__ u16 f2bu(float f) {
  uint32_t u = __float_as_uint(f);
  u += 0x7FFFu + ((u >> 16) & 1u);      // RNE; inputs are finite
  return (u16)(u >> 16);
}
__device__ __forceinline__ float bu2f(u16 b) {
  return __uint_as_float(((uint32_t)b) << 16);
}
// async global->LDS, 16B per lane; LDS dest = wave-uniform base + lane*16
__device__ __forceinline__ void gl2lds16(const u16* g, u16* l) {
  __builtin_amdgcn_global_load_lds(
      (const __attribute__((address_space(1))) unsigned int*)g,
      (__attribute__((address_space(3))) unsigned int*)l, 16, 0, 0);
}

// ---------------- prep: x fp32 -> bf16 [M_PAD,768], pad rows zeroed ----------
__global__ __launch_bounds__(256) void prep_x(const float* __restrict__ x,
                                              u16* __restrict__ xb) {
  int e = (blockIdx.x * 256 + threadIdx.x) * 8;
  u16 o[8];
  if (e < M_ROWS * DMODEL) {
    float4 f0 = *(const float4*)(x + e);
    float4 f1 = *(const float4*)(x + e + 4);
    o[0] = f2bu(f0.x); o[1] = f2bu(f0.y); o[2] = f2bu(f0.z); o[3] = f2bu(f0.w);
    o[4] = f2bu(f1.x); o[5] = f2bu(f1.y); o[6] = f2bu(f1.z); o[7] = f2bu(f1.w);
  } else {
#pragma unroll
    for (int i = 0; i < 8; ++i) o[i] = 0;
  }
  *(uint4*)(xb + e) = *(const uint4*)o;
}

// ------------- prep: weights fp32 [K,N] -> bf16 transposed [N,K], tiled ------
// wtqkv rows: [0,1536)=Wq^T, [1536,3072)=Wk^T, [3072,3840)=Wv^T ; wot = Wo^T
__global__ __launch_bounds__(256) void prep_w(
    const float* __restrict__ Wq, const float* __restrict__ Wk,
    const float* __restrict__ Wv, const float* __restrict__ Wo,
    u16* __restrict__ wtqkv, u16* __restrict__ wot) {
  __shared__ u16 tile[32][33];
  int blk = blockIdx.x;
  const float* W; int N; u16* dst; int rowbase;
  if (blk < 1152)      { W = Wq; N = 1536; dst = wtqkv; rowbase = 0; }
  else if (blk < 2304) { W = Wk; N = 1536; dst = wtqkv; rowbase = 1536; blk -= 1152; }
  else if (blk < 2880) { W = Wv; N = 768;  dst = wtqkv; rowbase = 3072; blk -= 2304; }
  else                 { W = Wo; N = 768;  dst = wot;   rowbase = 0;    blk -= 2880; }
  const int ntiles = N >> 5;
  const int tk = blk / ntiles, tn = blk - tk * ntiles;
  const int c = threadIdx.x & 31, r0 = threadIdx.x >> 5;
#pragma unroll
  for (int i = 0; i < 4; ++i) {
    int r = i * 8 + r0;
    tile[r][c] = f2bu(W[(size_t)(tk * 32 + r) * N + tn * 32 + c]);
  }
  __syncthreads();
#pragma unroll
  for (int i = 0; i < 4; ++i) {
    int r = i * 8 + r0;
    dst[(size_t)(rowbase + tn * 32 + r) * 768 + tk * 32 + c] = tile[c][r];
  }
}

// ---------------- bf16 MFMA GEMM: C[M,N] = A[M,768] * Bt[N,768]^T ------------
// m97 structure: global_load_lds width-16 staging into unpadded 128x32 tiles.
// mode 0: out fp32 [M_ROWS,N] + biasO[n]  (output projection)
// mode 1: scatter -> q1/q2/k1/k2 [B,H,S,64] bf16, v -> vt [B,H,64,640]
__global__ __launch_bounds__(256, 2) void gemm_bf16(
    const u16* __restrict__ A, const u16* __restrict__ Bt, int N, int mode,
    float* __restrict__ outF, const float* __restrict__ biasO,
    u16* __restrict__ q1p, u16* __restrict__ q2p,
    u16* __restrict__ k1p, u16* __restrict__ k2p, u16* __restrict__ vtp,
    const float* __restrict__ bq, const float* __restrict__ bk,
    const float* __restrict__ bvp) {
  __shared__ u16 lA[128 * 32];
  __shared__ u16 lB[128 * 32];
  const int t = threadIdx.x;
  const int lane = t & 63, wave = t >> 6;
  const int quad = lane >> 4, l16 = lane & 15;
  const int wm = wave & 1, wn = wave >> 1;
  const int m0 = blockIdx.x * 128;
  const int n0 = blockIdx.y * 128;

  f32x4 zero = {0.f, 0.f, 0.f, 0.f};
  f32x4 acc[4][4];
  for (int i = 0; i < 4; ++i) for (int j = 0; j < 4; ++j) acc[i][j] = zero;

  // staging: wave w owns rows w*32..w*32+31 (2 chunks of 16 rows);
  // lane -> row base + lane/4, col (lane%4)*8  (LDS offset == lane*16 B)
  const int srow = wave * 32 + (lane >> 2);
  const int scol = (lane & 3) * 8;
  const u16* gA = A + (size_t)(m0 + srow) * 768 + scol;
  const u16* gB = Bt + (size_t)(n0 + srow) * 768 + scol;
  u16* sA = lA + wave * 1024;   // wave-uniform LDS base
  u16* sB = lB + wave * 1024;

  for (int k0 = 0; k0 < 768; k0 += 32) {
    gl2lds16(gA + k0, sA);
    gl2lds16(gA + k0 + 16 * 768, sA + 512);
    gl2lds16(gB + k0, sB);
    gl2lds16(gB + k0 + 16 * 768, sB + 512);
    __syncthreads();
    bf16x8 af[4], bfr[4];
#pragma unroll
    for (int i = 0; i < 4; ++i)
      af[i] = *(const bf16x8*)(lA + (wm * 64 + i * 16 + l16) * 32 + quad * 8);
#pragma unroll
    for (int j = 0; j < 4; ++j)
      bfr[j] = *(const bf16x8*)(lB + (wn * 64 + j * 16 + l16) * 32 + quad * 8);
#pragma unroll
    for (int i = 0; i < 4; ++i)
#pragma unroll
      for (int j = 0; j < 4; ++j)
        acc[i][j] = __builtin_amdgcn_mfma_f32_16x16x32_bf16(af[i], bfr[j], acc[i][j], 0, 0, 0);
    __syncthreads();
  }

#pragma unroll
  for (int i = 0; i < 4; ++i) {
#pragma unroll
    for (int j = 0; j < 4; ++j) {
      int n = n0 + wn * 64 + j * 16 + l16;
#pragma unroll
      for (int r = 0; r < 4; ++r) {
        int m = m0 + wm * 64 + i * 16 + quad * 4 + r;
        if (m >= M_ROWS) continue;
        float v = acc[i][j][r];
        if (mode == 0) {
          outF[(size_t)m * N + n] = v + biasO[n];
        } else {
          int b = m / 577;
          int s = m - b * 577;
          if (n < 1536) {
            int ch = (n < 768) ? n : (n - 768);
            u16* dst = (n < 768) ? q1p : q2p;
            dst[(((size_t)b * 12 + (ch >> 6)) * 577 + s) * 64 + (ch & 63)] = f2bu(v + bq[n]);
          } else if (n < 3072) {
            int nn = n - 1536;
            int ch = (nn < 768) ? nn : (nn - 768);
            u16* dst = (nn < 768) ? k1p : k2p;
            dst[(((size_t)b * 12 + (ch >> 6)) * 577 + s) * 64 + (ch & 63)] = f2bu(v + bk[nn]);
          } else {
            int ch = n - 3072;
            vtp[(((size_t)b * 12 + (ch >> 6)) * 64 + (ch & 63)) * VT_STRIDE + s] = f2bu(v + bvp[ch]);
          }
        }
      }
    }
  }
}

// ---------------- flash-style differential attention (no-max softmax) --------
// R6: latency-bound fix pass.
//  * 2 independent waves / 128-thread workgroup (lifts the per-CU workgroup
//    slot cap that held single-wave blocks to ~13 waves/CU).
//  * K software pipeline: block kb+1's K fragments are loaded into registers
//    while block kb computes -> load latency hides under exp/LDS/PV.
//    __launch_bounds__(128,4) keeps the VGPR cap at 128 (4 waves/SIMD).
//  * swapped QK^T: s = mfma(K,Q) gives P^T with each lane owning one q-row's
//    k-slice -> P staging is 4x ds_write_b64 (was 32x ds_write_b16), row-sums
//    are lane-local scalars (one shfl_xor pair at the end), and the tail mask
//    is peeled out of the main loop (blocks 0..17 need no masking).
//  * s_setprio(1) around MFMA clusters (T5, +4-7% on attn per m191).
__global__ __launch_bounds__(128, 4) void attn(
    const u16* __restrict__ q1, const u16* __restrict__ q2,
    const u16* __restrict__ k1, const u16* __restrict__ k2,
    const u16* __restrict__ vt, u16* __restrict__ ctx_t,
    const float* __restrict__ lam_p) {
  __shared__ u16 pls[2][2][16 * 40];   // [wave][stream][q=16][k-slot stride 40]
  const int bh = blockIdx.x;
  const int wave = threadIdx.x >> 6;
  const int lane = threadIdx.x & 63;
  const int quad = lane >> 4, l16 = lane & 15;
  const int q0 = (blockIdx.y * 2 + wave) * 16;

  const float lam = lam_p[0];
  const float CEXP = 0.125f * 1.44269504f;   // scale * log2(e), folded
  const size_t qkbase = (size_t)bh * S_LEN * DH;
  const size_t vbase = (size_t)bh * 64 * VT_STRIDE;

  int qr = q0 + l16; if (qr > 576) qr = 576;   // clamp tail (results discarded)
  bf16x8 q1f[2], q2f[2];
#pragma unroll
  for (int c = 0; c < 2; ++c) {
    q1f[c] = *(const bf16x8*)(q1 + qkbase + (size_t)qr * 64 + c * 32 + quad * 8);
    q2f[c] = *(const bf16x8*)(q2 + qkbase + (size_t)qr * 64 + c * 32 + quad * 8);
  }

  f32x4 zero = {0.f, 0.f, 0.f, 0.f};
  f32x4 O1[4], O2[4];
#pragma unroll
  for (int i = 0; i < 4; ++i) { O1[i] = zero; O2[i] = zero; }
  float l1p = 0.f, l2p = 0.f;   // per-lane partial row-sums (q-row = l16)

  u16* p1w = &pls[wave][0][0];
  u16* p2w = &pls[wave][1][0];

  // preload K fragments for block 0 (rows tt*16+l16, k = c*32+quad*8)
  bf16x8 k1f[2][2], k2f[2][2];
#pragma unroll
  for (int tt = 0; tt < 2; ++tt) {
    size_t off = qkbase + (size_t)(tt * 16 + l16) * 64 + quad * 8;
    k1f[tt][0] = *(const bf16x8*)(k1 + off);
    k1f[tt][1] = *(const bf16x8*)(k1 + off + 32);
    k2f[tt][0] = *(const bf16x8*)(k2 + off);
    k2f[tt][1] = *(const bf16x8*)(k2 + off + 32);
  }

  // main loop: blocks 0..17 are fully in-range (k <= 575) -> no masking
  for (int kb = 0; kb < 18; ++kb) {
    const int kv0 = kb * 32;
    f32x4 s1[2], s2[2];
    __builtin_amdgcn_s_setprio(1);
#pragma unroll
    for (int tt = 0; tt < 2; ++tt) {
      s1[tt] = __builtin_amdgcn_mfma_f32_16x16x32_bf16(k1f[tt][0], q1f[0], zero, 0, 0, 0);
      s1[tt] = __builtin_amdgcn_mfma_f32_16x16x32_bf16(k1f[tt][1], q1f[1], s1[tt], 0, 0, 0);
      s2[tt] = __builtin_amdgcn_mfma_f32_16x16x32_bf16(k2f[tt][0], q2f[0], zero, 0, 0, 0);
      s2[tt] = __builtin_amdgcn_mfma_f32_16x16x32_bf16(k2f[tt][1], q2f[1], s2[tt], 0, 0, 0);
    }
    __builtin_amdgcn_s_setprio(0);
    // prefetch next block's K into the same registers (block kb+1 <= 18)
    {
      const int kn = kv0 + 32;
#pragma unroll
      for (int tt = 0; tt < 2; ++tt) {
        int kr = kn + tt * 16 + l16; if (kr > 576) kr = 576;
        size_t off = qkbase + (size_t)kr * 64 + quad * 8;
        k1f[tt][0] = *(const bf16x8*)(k1 + off);
        k1f[tt][1] = *(const bf16x8*)(k1 + off + 32);
        k2f[tt][0] = *(const bf16x8*)(k2 + off);
        k2f[tt][1] = *(const bf16x8*)(k2 + off + 32);
      }
    }
    bf16x8 vf[4];
#pragma unroll
    for (int tt = 0; tt < 4; ++tt)
      vf[tt] = *(const bf16x8*)(vt + vbase + (size_t)(tt * 16 + l16) * VT_STRIDE + kv0 + quad * 8);

    // exp + lane-local sums + packed b64 stage: lane owns q-row l16,
    // k = kv0 + tt*16 + quad*4 + r
#pragma unroll
    for (int tt = 0; tt < 2; ++tt) {
      float pa[4], pb[4];
#pragma unroll
      for (int r = 0; r < 4; ++r) {
        pa[r] = exp2f(s1[tt][r] * CEXP); l1p += pa[r];
        pb[r] = exp2f(s2[tt][r] * CEXP); l2p += pb[r];
      }
      // truncating bf16 convert (cheap; ~0.1% bias, well under budget)
      uint2 wa, wb;
      wa.x = (__float_as_uint(pa[1]) & 0xffff0000u) | (__float_as_uint(pa[0]) >> 16);
      wa.y = (__float_as_uint(pa[3]) & 0xffff0000u) | (__float_as_uint(pa[2]) >> 16);
      wb.x = (__float_as_uint(pb[1]) & 0xffff0000u) | (__float_as_uint(pb[0]) >> 16);
      wb.y = (__float_as_uint(pb[3]) & 0xffff0000u) | (__float_as_uint(pb[2]) >> 16);
      *(uint2*)(p1w + l16 * 40 + tt * 16 + quad * 4) = wa;
      *(uint2*)(p2w + l16 * 40 + tt * 16 + quad * 4) = wb;
    }
    bf16x8 p1a = *(const bf16x8*)(p1w + l16 * 40 + quad * 8);
    bf16x8 p2a = *(const bf16x8*)(p2w + l16 * 40 + quad * 8);
    __builtin_amdgcn_s_setprio(1);
#pragma unroll
    for (int tt = 0; tt < 4; ++tt) {
      O1[tt] = __builtin_amdgcn_mfma_f32_16x16x32_bf16(p1a, vf[tt], O1[tt], 0, 0, 0);
      O2[tt] = __builtin_amdgcn_mfma_f32_16x16x32_bf16(p2a, vf[tt], O2[tt], 0, 0, 0);
    }
    __builtin_amdgcn_s_setprio(0);
  }

  // epilogue: block 18 (kv0 = 576), masked, K already prefetched
  {
    const int kv0 = 576;
    f32x4 s1[2], s2[2];
#pragma unroll
    for (int tt = 0; tt < 2; ++tt) {
      s1[tt] = __builtin_amdgcn_mfma_f32_16x16x32_bf16(k1f[tt][0], q1f[0], zero, 0, 0, 0);
      s1[tt] = __builtin_amdgcn_mfma_f32_16x16x32_bf16(k1f[tt][1], q1f[1], s1[tt], 0, 0, 0);
      s2[tt] = __builtin_amdgcn_mfma_f32_16x16x32_bf16(k2f[tt][0], q2f[0], zero, 0, 0, 0);
      s2[tt] = __builtin_amdgcn_mfma_f32_16x16x32_bf16(k2f[tt][1], q2f[1], s2[tt], 0, 0, 0);
    }
    bf16x8 vf[4];
#pragma unroll
    for (int tt = 0; tt < 4; ++tt)
      vf[tt] = *(const bf16x8*)(vt + vbase + (size_t)(tt * 16 + l16) * VT_STRIDE + kv0 + quad * 8);
#pragma unroll
    for (int tt = 0; tt < 2; ++tt) {
      float pa[4], pb[4];
#pragma unroll
      for (int r = 0; r < 4; ++r) {
        bool ok = (kv0 + tt * 16 + quad * 4 + r) < S_LEN;
        pa[r] = ok ? exp2f(s1[tt][r] * CEXP) : 0.f; l1p += pa[r];
        pb[r] = ok ? exp2f(s2[tt][r] * CEXP) : 0.f; l2p += pb[r];
      }
      uint2 wa, wb;
      wa.x = (__float_as_uint(pa[1]) & 0xffff0000u) | (__float_as_uint(pa[0]) >> 16);
      wa.y = (__float_as_uint(pa[3]) & 0xffff0000u) | (__float_as_uint(pa[2]) >> 16);
      wb.x = (__float_as_uint(pb[1]) & 0xffff0000u) | (__float_as_uint(pb[0]) >> 16);
      wb.y = (__float_as_uint(pb[3]) & 0xffff0000u) | (__float_as_uint(pb[2]) >> 16);
      *(uint2*)(p1w + l16 * 40 + tt * 16 + quad * 4) = wa;
      *(uint2*)(p2w + l16 * 40 + tt * 16 + quad * 4) = wb;
    }
    bf16x8 p1a = *(const bf16x8*)(p1w + l16 * 40 + quad * 8);
    bf16x8 p2a = *(const bf16x8*)(p2w + l16 * 40 + quad * 8);
#pragma unroll
    for (int tt = 0; tt < 4; ++tt) {
      O1[tt] = __builtin_amdgcn_mfma_f32_16x16x32_bf16(p1a, vf[tt], O1[tt], 0, 0, 0);
      O2[tt] = __builtin_amdgcn_mfma_f32_16x16x32_bf16(p2a, vf[tt], O2[tt], 0, 0, 0);
    }
  }

  // full row-sums: combine the 4 quads holding the same q-row (l16)
  l1p += __shfl_xor(l1p, 16); l1p += __shfl_xor(l1p, 32);
  l2p += __shfl_xor(l2p, 16); l2p += __shfl_xor(l2p, 32);
  float inv1 = 1.f / l1p, inv2 = 1.f / l2p;   // valid for q-row = l16
  float a1[4], a2[4];
#pragma unroll
  for (int i = 0; i < 4; ++i) {
    a1[i] = __shfl(inv1, quad * 4 + i);   // lane (quad*4+i) holds q-row quad*4+i
    a2[i] = __shfl(inv2, quad * 4 + i);
  }
#pragma unroll
  for (int tt = 0; tt < 4; ++tt) {
    size_t cb = ((size_t)bh * 64 + tt * 16 + l16) * S_LEN;
#pragma unroll
    for (int i = 0; i < 4; ++i) {
      int s = q0 + quad * 4 + i;
      if (s < S_LEN)
        ctx_t[cb + s] = f2bu(O1[tt][i] * a1[i] - lam * O2[tt][i] * a2[i]);
    }
  }
}

// ---------------- GroupNorm over (b,h): Dh*S elements, then affine ----------
// ctx_t [B,H,64,S] -> context flat [B][D*S] (== reference's reinterpret trick)
__global__ __launch_bounds__(256) void gnorm(
    const u16* __restrict__ ctx_t, u16* __restrict__ context,
    const float* __restrict__ gw, const float* __restrict__ gb) {
  const int bh = blockIdx.x;
  const int h = bh % 12;
  const int NEL = 64 * S_LEN;          // 36928
  const int NV = NEL / 8;              // 4616
  const u16* src = ctx_t + (size_t)bh * NEL;
  float sum = 0.f, sq = 0.f;
  for (int v = threadIdx.x; v < NV; v += 256) {
    uint4 raw = *(const uint4*)(src + v * 8);
    uint32_t w[4] = {raw.x, raw.y, raw.z, raw.w};
#pragma unroll
    for (int j = 0; j < 4; ++j) {
      float f0 = bu2f((u16)(w[j] & 0xffff));
      float f1 = bu2f((u16)(w[j] >> 16));
      sum += f0 + f1; sq += f0 * f0 + f1 * f1;
    }
  }
#pragma unroll
  for (int d = 1; d < 64; d <<= 1) {
    sum += __shfl_xor(sum, d);
    sq += __shfl_xor(sq, d);
  }
  __shared__ float rs[4], rq[4];
  __shared__ float wv[64], bv2[64];
  int wave = threadIdx.x >> 6;
  if ((threadIdx.x & 63) == 0) { rs[wave] = sum; rq[wave] = sq; }
  __syncthreads();
  float ts = rs[0] + rs[1] + rs[2] + rs[3];
  float tq = rq[0] + rq[1] + rq[2] + rq[3];
  const float Ninv = 1.0f / (float)NEL;
  float mu = ts * Ninv;
  float var = tq * Ninv - mu * mu;
  float rstd = rsqrtf(var + 1e-5f);
  if (threadIdx.x < 64) {
    float w = gw[h * 64 + threadIdx.x] * rstd;
    wv[threadIdx.x] = w;
    bv2[threadIdx.x] = gb[h * 64 + threadIdx.x] - mu * w;
  }
  __syncthreads();
  u16* dst = context + (size_t)bh * NEL;   // b*(768*577) + h*(64*577)
  for (int v = threadIdx.x; v < NV; v += 256) {
    uint4 raw = *(const uint4*)(src + v * 8);
    uint32_t w[4] = {raw.x, raw.y, raw.z, raw.w};
    int base = v * 8;
    int d0 = base / 577;
    int r0 = base - d0 * 577;
    u16 o[8];
#pragma unroll
    for (int j = 0; j < 4; ++j) {
#pragma unroll
      for (int e = 0; e < 2; ++e) {
        int ii = j * 2 + e;
        int dd = (r0 + ii >= 577) ? d0 + 1 : d0;
        float f = bu2f((u16)(e == 0 ? (w[j] & 0xffff) : (w[j] >> 16)));
        o[ii] = f2bu(f * wv[dd] + bv2[dd]);
      }
    }
    *(uint4*)(dst + base) = *(const uint4*)o;
  }
}

extern "C" void kernel_launch(void* const* d_in, const int* in_sizes, int n_in,
                              void* d_out, int out_size, void* d_ws, size_t ws_size,
                              hipStream_t stream) {
  const float* x   = (const float*)d_in[0];
  const float* Wq  = (const float*)d_in[1];
  const float* bq  = (const float*)d_in[2];
  const float* Wk  = (const float*)d_in[3];
  const float* bk  = (const float*)d_in[4];
  const float* Wv  = (const float*)d_in[5];
  const float* bv  = (const float*)d_in[6];
  const float* Wo  = (const float*)d_in[7];
  const float* bo  = (const float*)d_in[8];
  const float* lam = (const float*)d_in[9];
  const float* gw  = (const float*)d_in[10];
  const float* gb  = (const float*)d_in[11];
  float* out = (float*)d_out;

  char* p = (char*)d_ws;
  auto alloc = [&](size_t bytes) {
    char* r = p;
    p += (bytes + 255) & ~(size_t)255;
    return r;
  };
  u16* xb     = (u16*)alloc((size_t)M_PAD * 768 * 2);   // also reused as ctxbuf
  u16* wtqkv  = (u16*)alloc((size_t)3840 * 768 * 2);
  u16* wot    = (u16*)alloc((size_t)768 * 768 * 2);
  u16* q1b    = (u16*)alloc((size_t)192 * 577 * 64 * 2);
  u16* q2b    = (u16*)alloc((size_t)192 * 577 * 64 * 2);
  u16* k1b    = (u16*)alloc((size_t)192 * 577 * 64 * 2);
  u16* k2b    = (u16*)alloc((size_t)192 * 577 * 64 * 2);
  u16* vtb    = (u16*)alloc((size_t)192 * 64 * VT_STRIDE * 2);
  u16* ctxt   = (u16*)alloc((size_t)192 * 64 * S_LEN * 2);
  u16* ctxbuf = xb;   // alias: xb is dead after the QKV GEMM; keeps ws ~108 MB

  prep_x<<<(M_PAD * 768 / 8 + 255) / 256, 256, 0, stream>>>(x, xb);
  prep_w<<<3456, 256, 0, stream>>>(Wq, Wk, Wv, Wo, wtqkv, wot);

  gemm_bf16<<<dim3(73, 30), 256, 0, stream>>>(xb, wtqkv, 3840, 1,
      nullptr, nullptr, q1b, q2b, k1b, k2b, vtb, bq, bk, bv);

  attn<<<dim3(192, 19), 128, 0, stream>>>(q1b, q2b, k1b, k2b, vtb, ctxt, lam);

  gnorm<<<192, 256, 0, stream>>>(ctxt, ctxbuf, gw, gb);

  gemm_bf16<<<dim3(73, 6), 256, 0, stream>>>(ctxbuf, wot, 768, 0,
      out, bo, nullptr, nullptr, nullptr, nullptr, nullptr, nullptr, nullptr, nullptr);
}

// Round 2
// 474.865 us; speedup vs baseline: 1.1342x; 1.1342x over previous
//
#include <hip/hip_runtime.h>
#include <hip/hip_bf16.h>
#include <stdint.h>

typedef unsigned short u16;
typedef __attribute__((ext_vector_type(8))) short bf16x8;
typedef __attribute__((ext_vector_type(4))) float f32x4;

#define S_LEN 577
#define DMODEL 768
#define NHEAD 12
#define DH 64
#define BATCH 16
#define M_ROWS (BATCH * S_LEN)   /* 9232 */
#define M_PAD 9344               /* 73 * 128 */
#define VT_STRIDE 640            /* padded S so 16B frag loads stay aligned */

__device__ __forceinline__ u16 f2bu(float f) {
  uint32_t u = __float_as_uint(f);
  u += 0x7FFFu + ((u >> 16) & 1u);      // RNE; inputs are finite
  return (u16)(u >> 16);
}
__device__ __forceinline__ float bu2f(u16 b) {
  return __uint_as_float(((uint32_t)b) << 16);
}
// async global->LDS, 16B per lane; LDS dest = wave-uniform base + lane*16
__device__ __forceinline__ void gl2lds16(const u16* g, u16* l) {
  __builtin_amdgcn_global_load_lds(
      (const __attribute__((address_space(1))) unsigned int*)g,
      (__attribute__((address_space(3))) unsigned int*)l, 16, 0, 0);
}

// ---------------- prep: x fp32 -> bf16 [M_PAD,768], pad rows zeroed ----------
__global__ __launch_bounds__(256) void prep_x(const float* __restrict__ x,
                                              u16* __restrict__ xb) {
  int e = (blockIdx.x * 256 + threadIdx.x) * 8;
  u16 o[8];
  if (e < M_ROWS * DMODEL) {
    float4 f0 = *(const float4*)(x + e);
    float4 f1 = *(const float4*)(x + e + 4);
    o[0] = f2bu(f0.x); o[1] = f2bu(f0.y); o[2] = f2bu(f0.z); o[3] = f2bu(f0.w);
    o[4] = f2bu(f1.x); o[5] = f2bu(f1.y); o[6] = f2bu(f1.z); o[7] = f2bu(f1.w);
  } else {
#pragma unroll
    for (int i = 0; i < 8; ++i) o[i] = 0;
  }
  *(uint4*)(xb + e) = *(const uint4*)o;
}

// ------------- prep: weights fp32 [K,N] -> bf16 transposed [N,K], tiled ------
// wtqkv rows: [0,1536)=Wq^T, [1536,3072)=Wk^T, [3072,3840)=Wv^T ; wot = Wo^T
__global__ __launch_bounds__(256) void prep_w(
    const float* __restrict__ Wq, const float* __restrict__ Wk,
    const float* __restrict__ Wv, const float* __restrict__ Wo,
    u16* __restrict__ wtqkv, u16* __restrict__ wot) {
  __shared__ u16 tile[32][33];
  int blk = blockIdx.x;
  const float* W; int N; u16* dst; int rowbase;
  if (blk < 1152)      { W = Wq; N = 1536; dst = wtqkv; rowbase = 0; }
  else if (blk < 2304) { W = Wk; N = 1536; dst = wtqkv; rowbase = 1536; blk -= 1152; }
  else if (blk < 2880) { W = Wv; N = 768;  dst = wtqkv; rowbase = 3072; blk -= 2304; }
  else                 { W = Wo; N = 768;  dst = wot;   rowbase = 0;    blk -= 2880; }
  const int ntiles = N >> 5;
  const int tk = blk / ntiles, tn = blk - tk * ntiles;
  const int c = threadIdx.x & 31, r0 = threadIdx.x >> 5;
#pragma unroll
  for (int i = 0; i < 4; ++i) {
    int r = i * 8 + r0;
    tile[r][c] = f2bu(W[(size_t)(tk * 32 + r) * N + tn * 32 + c]);
  }
  __syncthreads();
#pragma unroll
  for (int i = 0; i < 4; ++i) {
    int r = i * 8 + r0;
    dst[(size_t)(rowbase + tn * 32 + r) * 768 + tk * 32 + c] = tile[c][r];
  }
}

// ---------------- bf16 MFMA GEMM: C[M,N] = A[M,768] * Bt[N,768]^T ------------
// m97 structure: global_load_lds width-16 staging into unpadded 128x32 tiles.
// mode 0: out fp32 [M_ROWS,N] + biasO[n]  (output projection)
// mode 1: scatter -> q1/q2/k1/k2 [B,H,S,64] bf16, v -> vt [B,H,64,640]
__global__ __launch_bounds__(256, 2) void gemm_bf16(
    const u16* __restrict__ A, const u16* __restrict__ Bt, int N, int mode,
    float* __restrict__ outF, const float* __restrict__ biasO,
    u16* __restrict__ q1p, u16* __restrict__ q2p,
    u16* __restrict__ k1p, u16* __restrict__ k2p, u16* __restrict__ vtp,
    const float* __restrict__ bq, const float* __restrict__ bk,
    const float* __restrict__ bvp) {
  __shared__ u16 lA[128 * 32];
  __shared__ u16 lB[128 * 32];
  const int t = threadIdx.x;
  const int lane = t & 63, wave = t >> 6;
  const int quad = lane >> 4, l16 = lane & 15;
  const int wm = wave & 1, wn = wave >> 1;
  const int m0 = blockIdx.x * 128;
  const int n0 = blockIdx.y * 128;

  f32x4 zero = {0.f, 0.f, 0.f, 0.f};
  f32x4 acc[4][4];
  for (int i = 0; i < 4; ++i) for (int j = 0; j < 4; ++j) acc[i][j] = zero;

  // staging: wave w owns rows w*32..w*32+31 (2 chunks of 16 rows);
  // lane -> row base + lane/4, col (lane%4)*8  (LDS offset == lane*16 B)
  const int srow = wave * 32 + (lane >> 2);
  const int scol = (lane & 3) * 8;
  const u16* gA = A + (size_t)(m0 + srow) * 768 + scol;
  const u16* gB = Bt + (size_t)(n0 + srow) * 768 + scol;
  u16* sA = lA + wave * 1024;   // wave-uniform LDS base
  u16* sB = lB + wave * 1024;

  for (int k0 = 0; k0 < 768; k0 += 32) {
    gl2lds16(gA + k0, sA);
    gl2lds16(gA + k0 + 16 * 768, sA + 512);
    gl2lds16(gB + k0, sB);
    gl2lds16(gB + k0 + 16 * 768, sB + 512);
    __syncthreads();
    bf16x8 af[4], bfr[4];
#pragma unroll
    for (int i = 0; i < 4; ++i)
      af[i] = *(const bf16x8*)(lA + (wm * 64 + i * 16 + l16) * 32 + quad * 8);
#pragma unroll
    for (int j = 0; j < 4; ++j)
      bfr[j] = *(const bf16x8*)(lB + (wn * 64 + j * 16 + l16) * 32 + quad * 8);
#pragma unroll
    for (int i = 0; i < 4; ++i)
#pragma unroll
      for (int j = 0; j < 4; ++j)
        acc[i][j] = __builtin_amdgcn_mfma_f32_16x16x32_bf16(af[i], bfr[j], acc[i][j], 0, 0, 0);
    __syncthreads();
  }

#pragma unroll
  for (int i = 0; i < 4; ++i) {
#pragma unroll
    for (int j = 0; j < 4; ++j) {
      int n = n0 + wn * 64 + j * 16 + l16;
#pragma unroll
      for (int r = 0; r < 4; ++r) {
        int m = m0 + wm * 64 + i * 16 + quad * 4 + r;
        if (m >= M_ROWS) continue;
        float v = acc[i][j][r];
        if (mode == 0) {
          outF[(size_t)m * N + n] = v + biasO[n];
        } else {
          int b = m / 577;
          int s = m - b * 577;
          if (n < 1536) {
            int ch = (n < 768) ? n : (n - 768);
            u16* dst = (n < 768) ? q1p : q2p;
            dst[(((size_t)b * 12 + (ch >> 6)) * 577 + s) * 64 + (ch & 63)] = f2bu(v + bq[n]);
          } else if (n < 3072) {
            int nn = n - 1536;
            int ch = (nn < 768) ? nn : (nn - 768);
            u16* dst = (nn < 768) ? k1p : k2p;
            dst[(((size_t)b * 12 + (ch >> 6)) * 577 + s) * 64 + (ch & 63)] = f2bu(v + bk[nn]);
          } else {
            int ch = n - 3072;
            vtp[(((size_t)b * 12 + (ch >> 6)) * 64 + (ch & 63)) * VT_STRIDE + s] = f2bu(v + bvp[ch]);
          }
        }
      }
    }
  }
}

// ---------------- flash-style differential attention (no-max softmax) --------
// R7: exact R5 structure (known-good 196us) + ONE change: XCD/L2-locality
// block swizzle. 1D grid of 7104; round-robin XCD assignment (bid%8) is
// decoded so each XCD works through 3 groups of 8 bh, all 37 q-tiles per
// group, before moving on. Per-XCD live K/V working set drops from ~43MB
// (L2 thrashed, everything served by L3) to ~1.8MB (< 4MB L2).
__global__ __launch_bounds__(64, 4) void attn(
    const u16* __restrict__ q1, const u16* __restrict__ q2,
    const u16* __restrict__ k1, const u16* __restrict__ k2,
    const u16* __restrict__ vt, u16* __restrict__ ctx_t,
    const float* __restrict__ lam_p) {
  __shared__ u16 pls[2][16 * 40];   // P staging (D-layout -> A-layout)
  // swizzle decode: xcd = bid%8 owns bh in {xcd*24 .. xcd*24+23}
  const int bid = blockIdx.x;
  const int xcd = bid & 7;
  const int slot = bid >> 3;            // 0..887
  const int group = slot / 296;         // 3 groups of 8 bh per XCD
  const int rem = slot - group * 296;   // 0..295
  const int qtile = rem >> 3;           // 0..36
  const int bh = xcd * 24 + group * 8 + (rem & 7);
  const int q0 = qtile * 16;

  const int lane = threadIdx.x & 63;
  const int quad = lane >> 4, l16 = lane & 15;

  const float lam = lam_p[0];
  const float CEXP = 0.125f * 1.44269504f;   // scale * log2(e), folded
  const size_t qkbase = (size_t)bh * S_LEN * DH;

  int qr = q0 + l16; if (qr > 576) qr = 576;   // clamp tail (results discarded)
  bf16x8 q1f[2], q2f[2];
#pragma unroll
  for (int c = 0; c < 2; ++c) {
    q1f[c] = *(const bf16x8*)(q1 + qkbase + (size_t)qr * 64 + c * 32 + quad * 8);
    q2f[c] = *(const bf16x8*)(q2 + qkbase + (size_t)qr * 64 + c * 32 + quad * 8);
  }

  f32x4 zero = {0.f, 0.f, 0.f, 0.f};
  f32x4 O1[4], O2[4];
  float l1[4], l2[4];
#pragma unroll
  for (int i = 0; i < 4; ++i) { O1[i] = zero; O2[i] = zero; l1[i] = 0.f; l2[i] = 0.f; }

  u16* p1w = &pls[0][0];
  u16* p2w = &pls[1][0];
  const size_t vbase = (size_t)bh * 64 * VT_STRIDE;

  for (int kb = 0; kb < 19; ++kb) {
    const int kv0 = kb * 32;
    bf16x8 k1f[2][2], k2f[2][2];
#pragma unroll
    for (int tt = 0; tt < 2; ++tt) {
      int kr = kv0 + tt * 16 + l16; if (kr > 576) kr = 576;
      size_t off = qkbase + (size_t)kr * 64 + quad * 8;
      k1f[tt][0] = *(const bf16x8*)(k1 + off);
      k1f[tt][1] = *(const bf16x8*)(k1 + off + 32);
      k2f[tt][0] = *(const bf16x8*)(k2 + off);
      k2f[tt][1] = *(const bf16x8*)(k2 + off + 32);
    }
    f32x4 s1[2], s2[2];
#pragma unroll
    for (int tt = 0; tt < 2; ++tt) {
      s1[tt] = __builtin_amdgcn_mfma_f32_16x16x32_bf16(q1f[0], k1f[tt][0], zero, 0, 0, 0);
      s1[tt] = __builtin_amdgcn_mfma_f32_16x16x32_bf16(q1f[1], k1f[tt][1], s1[tt], 0, 0, 0);
      s2[tt] = __builtin_amdgcn_mfma_f32_16x16x32_bf16(q2f[0], k2f[tt][0], zero, 0, 0, 0);
      s2[tt] = __builtin_amdgcn_mfma_f32_16x16x32_bf16(q2f[1], k2f[tt][1], s2[tt], 0, 0, 0);
    }
    bool ok0 = (kv0 + l16) < S_LEN;
    bool ok1 = (kv0 + 16 + l16) < S_LEN;
    bf16x8 vf[4];
#pragma unroll
    for (int tt = 0; tt < 4; ++tt)
      vf[tt] = *(const bf16x8*)(vt + vbase + (size_t)(tt * 16 + l16) * VT_STRIDE + kv0 + quad * 8);
#pragma unroll
    for (int i = 0; i < 4; ++i) {
      float p10 = ok0 ? exp2f(s1[0][i] * CEXP) : 0.f;
      float p11 = ok1 ? exp2f(s1[1][i] * CEXP) : 0.f;
      float p20 = ok0 ? exp2f(s2[0][i] * CEXP) : 0.f;
      float p21 = ok1 ? exp2f(s2[1][i] * CEXP) : 0.f;
      l1[i] += p10 + p11;
      l2[i] += p20 + p21;
      // truncating bf16 convert (cheap; ~0.1% bias, well under budget)
      p1w[(quad * 4 + i) * 40 + l16]      = (u16)(__float_as_uint(p10) >> 16);
      p1w[(quad * 4 + i) * 40 + l16 + 16] = (u16)(__float_as_uint(p11) >> 16);
      p2w[(quad * 4 + i) * 40 + l16]      = (u16)(__float_as_uint(p20) >> 16);
      p2w[(quad * 4 + i) * 40 + l16 + 16] = (u16)(__float_as_uint(p21) >> 16);
    }
    bf16x8 p1a = *(const bf16x8*)(p1w + l16 * 40 + quad * 8);
    bf16x8 p2a = *(const bf16x8*)(p2w + l16 * 40 + quad * 8);
#pragma unroll
    for (int tt = 0; tt < 4; ++tt) {
      O1[tt] = __builtin_amdgcn_mfma_f32_16x16x32_bf16(p1a, vf[tt], O1[tt], 0, 0, 0);
      O2[tt] = __builtin_amdgcn_mfma_f32_16x16x32_bf16(p2a, vf[tt], O2[tt], 0, 0, 0);
    }
  }
  // reduce partial row-sums across the quad's 16 lanes
#pragma unroll
  for (int d = 1; d < 16; d <<= 1)
#pragma unroll
    for (int i = 0; i < 4; ++i) {
      l1[i] += __shfl_xor(l1[i], d);
      l2[i] += __shfl_xor(l2[i], d);
    }
  float inv1[4], inv2[4];
#pragma unroll
  for (int i = 0; i < 4; ++i) { inv1[i] = 1.f / l1[i]; inv2[i] = 1.f / l2[i]; }
#pragma unroll
  for (int tt = 0; tt < 4; ++tt) {
    size_t cb = ((size_t)bh * 64 + tt * 16 + l16) * S_LEN;
#pragma unroll
    for (int i = 0; i < 4; ++i) {
      int s = q0 + quad * 4 + i;
      if (s < S_LEN)
        ctx_t[cb + s] = f2bu(O1[tt][i] * inv1[i] - lam * O2[tt][i] * inv2[i]);
    }
  }
}

// ---------------- GroupNorm over (b,h): Dh*S elements, then affine ----------
// ctx_t [B,H,64,S] -> context flat [B][D*S] (== reference's reinterpret trick)
__global__ __launch_bounds__(256) void gnorm(
    const u16* __restrict__ ctx_t, u16* __restrict__ context,
    const float* __restrict__ gw, const float* __restrict__ gb) {
  const int bh = blockIdx.x;
  const int h = bh % 12;
  const int NEL = 64 * S_LEN;          // 36928
  const int NV = NEL / 8;              // 4616
  const u16* src = ctx_t + (size_t)bh * NEL;
  float sum = 0.f, sq = 0.f;
  for (int v = threadIdx.x; v < NV; v += 256) {
    uint4 raw = *(const uint4*)(src + v * 8);
    uint32_t w[4] = {raw.x, raw.y, raw.z, raw.w};
#pragma unroll
    for (int j = 0; j < 4; ++j) {
      float f0 = bu2f((u16)(w[j] & 0xffff));
      float f1 = bu2f((u16)(w[j] >> 16));
      sum += f0 + f1; sq += f0 * f0 + f1 * f1;
    }
  }
#pragma unroll
  for (int d = 1; d < 64; d <<= 1) {
    sum += __shfl_xor(sum, d);
    sq += __shfl_xor(sq, d);
  }
  __shared__ float rs[4], rq[4];
  __shared__ float wv[64], bv2[64];
  int wave = threadIdx.x >> 6;
  if ((threadIdx.x & 63) == 0) { rs[wave] = sum; rq[wave] = sq; }
  __syncthreads();
  float ts = rs[0] + rs[1] + rs[2] + rs[3];
  float tq = rq[0] + rq[1] + rq[2] + rq[3];
  const float Ninv = 1.0f / (float)NEL;
  float mu = ts * Ninv;
  float var = tq * Ninv - mu * mu;
  float rstd = rsqrtf(var + 1e-5f);
  if (threadIdx.x < 64) {
    float w = gw[h * 64 + threadIdx.x] * rstd;
    wv[threadIdx.x] = w;
    bv2[threadIdx.x] = gb[h * 64 + threadIdx.x] - mu * w;
  }
  __syncthreads();
  u16* dst = context + (size_t)bh * NEL;   // b*(768*577) + h*(64*577)
  for (int v = threadIdx.x; v < NV; v += 256) {
    uint4 raw = *(const uint4*)(src + v * 8);
    uint32_t w[4] = {raw.x, raw.y, raw.z, raw.w};
    int base = v * 8;
    int d0 = base / 577;
    int r0 = base - d0 * 577;
    u16 o[8];
#pragma unroll
    for (int j = 0; j < 4; ++j) {
#pragma unroll
      for (int e = 0; e < 2; ++e) {
        int ii = j * 2 + e;
        int dd = (r0 + ii >= 577) ? d0 + 1 : d0;
        float f = bu2f((u16)(e == 0 ? (w[j] & 0xffff) : (w[j] >> 16)));
        o[ii] = f2bu(f * wv[dd] + bv2[dd]);
      }
    }
    *(uint4*)(dst + base) = *(const uint4*)o;
  }
}

extern "C" void kernel_launch(void* const* d_in, const int* in_sizes, int n_in,
                              void* d_out, int out_size, void* d_ws, size_t ws_size,
                              hipStream_t stream) {
  const float* x   = (const float*)d_in[0];
  const float* Wq  = (const float*)d_in[1];
  const float* bq  = (const float*)d_in[2];
  const float* Wk  = (const float*)d_in[3];
  const float* bk  = (const float*)d_in[4];
  const float* Wv  = (const float*)d_in[5];
  const float* bv  = (const float*)d_in[6];
  const float* Wo  = (const float*)d_in[7];
  const float* bo  = (const float*)d_in[8];
  const float* lam = (const float*)d_in[9];
  const float* gw  = (const float*)d_in[10];
  const float* gb  = (const float*)d_in[11];
  float* out = (float*)d_out;

  char* p = (char*)d_ws;
  auto alloc = [&](size_t bytes) {
    char* r = p;
    p += (bytes + 255) & ~(size_t)255;
    return r;
  };
  u16* xb     = (u16*)alloc((size_t)M_PAD * 768 * 2);   // also reused as ctxbuf
  u16* wtqkv  = (u16*)alloc((size_t)3840 * 768 * 2);
  u16* wot    = (u16*)alloc((size_t)768 * 768 * 2);
  u16* q1b    = (u16*)alloc((size_t)192 * 577 * 64 * 2);
  u16* q2b    = (u16*)alloc((size_t)192 * 577 * 64 * 2);
  u16* k1b    = (u16*)alloc((size_t)192 * 577 * 64 * 2);
  u16* k2b    = (u16*)alloc((size_t)192 * 577 * 64 * 2);
  u16* vtb    = (u16*)alloc((size_t)192 * 64 * VT_STRIDE * 2);
  u16* ctxt   = (u16*)alloc((size_t)192 * 64 * S_LEN * 2);
  u16* ctxbuf = xb;   // alias: xb is dead after the QKV GEMM; keeps ws ~108 MB

  prep_x<<<(M_PAD * 768 / 8 + 255) / 256, 256, 0, stream>>>(x, xb);
  prep_w<<<3456, 256, 0, stream>>>(Wq, Wk, Wv, Wo, wtqkv, wot);

  gemm_bf16<<<dim3(73, 30), 256, 0, stream>>>(xb, wtqkv, 3840, 1,
      nullptr, nullptr, q1b, q2b, k1b, k2b, vtb, bq, bk, bv);

  attn<<<dim3(7104), 64, 0, stream>>>(q1b, q2b, k1b, k2b, vtb, ctxt, lam);

  gnorm<<<192, 256, 0, stream>>>(ctxt, ctxbuf, gw, gb);

  gemm_bf16<<<dim3(73, 6), 256, 0, stream>>>(ctxbuf, wot, 768, 0,
      out, bo, nullptr, nullptr, nullptr, nullptr, nullptr, nullptr, nullptr, nullptr);
}

// Round 4
// 365.402 us; speedup vs baseline: 1.4740x; 1.2996x over previous
//
#include <hip/hip_runtime.h>
#include <hip/hip_bf16.h>
#include <stdint.h>

typedef unsigned short u16;
typedef __attribute__((ext_vector_type(8))) short bf16x8;
typedef __attribute__((ext_vector_type(4))) float f32x4;

#define S_LEN 577
#define DMODEL 768
#define NHEAD 12
#define DH 64
#define BATCH 16
#define M_ROWS (BATCH * S_LEN)   /* 9232 */
#define M_PAD 9344               /* 73 * 128 */
#define VT_STRIDE 640            /* padded S so 16B frag loads stay aligned */

__device__ __forceinline__ u16 f2bu(float f) {
  uint32_t u = __float_as_uint(f);
  u += 0x7FFFu + ((u >> 16) & 1u);      // RNE; inputs are finite
  return (u16)(u >> 16);
}
__device__ __forceinline__ float bu2f(u16 b) {
  return __uint_as_float(((uint32_t)b) << 16);
}
// async global->LDS, 16B per lane; LDS dest = wave-uniform base + lane*16
__device__ __forceinline__ void gl2lds16(const u16* g, u16* l) {
  __builtin_amdgcn_global_load_lds(
      (const __attribute__((address_space(1))) unsigned int*)g,
      (__attribute__((address_space(3))) unsigned int*)l, 16, 0, 0);
}

// ---------------- prep: x fp32 -> bf16 [M_PAD,768], pad rows zeroed ----------
__global__ __launch_bounds__(256) void prep_x(const float* __restrict__ x,
                                              u16* __restrict__ xb) {
  int e = (blockIdx.x * 256 + threadIdx.x) * 8;
  u16 o[8];
  if (e < M_ROWS * DMODEL) {
    float4 f0 = *(const float4*)(x + e);
    float4 f1 = *(const float4*)(x + e + 4);
    o[0] = f2bu(f0.x); o[1] = f2bu(f0.y); o[2] = f2bu(f0.z); o[3] = f2bu(f0.w);
    o[4] = f2bu(f1.x); o[5] = f2bu(f1.y); o[6] = f2bu(f1.z); o[7] = f2bu(f1.w);
  } else {
#pragma unroll
    for (int i = 0; i < 8; ++i) o[i] = 0;
  }
  *(uint4*)(xb + e) = *(const uint4*)o;
}

// ------------- prep: weights fp32 [K,N] -> bf16 transposed [N,K], tiled ------
// wtqkv rows: [0,1536)=Wq^T, [1536,3072)=Wk^T, [3072,3840)=Wv^T ; wot = Wo^T
__global__ __launch_bounds__(256) void prep_w(
    const float* __restrict__ Wq, const float* __restrict__ Wk,
    const float* __restrict__ Wv, const float* __restrict__ Wo,
    u16* __restrict__ wtqkv, u16* __restrict__ wot) {
  __shared__ u16 tile[32][33];
  int blk = blockIdx.x;
  const float* W; int N; u16* dst; int rowbase;
  if (blk < 1152)      { W = Wq; N = 1536; dst = wtqkv; rowbase = 0; }
  else if (blk < 2304) { W = Wk; N = 1536; dst = wtqkv; rowbase = 1536; blk -= 1152; }
  else if (blk < 2880) { W = Wv; N = 768;  dst = wtqkv; rowbase = 3072; blk -= 2304; }
  else                 { W = Wo; N = 768;  dst = wot;   rowbase = 0;    blk -= 2880; }
  const int ntiles = N >> 5;
  const int tk = blk / ntiles, tn = blk - tk * ntiles;
  const int c = threadIdx.x & 31, r0 = threadIdx.x >> 5;
#pragma unroll
  for (int i = 0; i < 4; ++i) {
    int r = i * 8 + r0;
    tile[r][c] = f2bu(W[(size_t)(tk * 32 + r) * N + tn * 32 + c]);
  }
  __syncthreads();
#pragma unroll
  for (int i = 0; i < 4; ++i) {
    int r = i * 8 + r0;
    dst[(size_t)(rowbase + tn * 32 + r) * 768 + tk * 32 + c] = tile[c][r];
  }
}

// ---------------- bf16 MFMA GEMM: C[M,N] = A[M,768] * Bt[N,768]^T ------------
// m97 structure: global_load_lds width-16 staging into unpadded 128x32 tiles.
// mode 0: out fp32 [M_ROWS,N] + biasO[n]  (output projection)
// mode 1: scatter -> q1/q2/k1/k2 [B,H,S,64] bf16, v -> vt [B,H,64,640]
__global__ __launch_bounds__(256, 2) void gemm_bf16(
    const u16* __restrict__ A, const u16* __restrict__ Bt, int N, int mode,
    float* __restrict__ outF, const float* __restrict__ biasO,
    u16* __restrict__ q1p, u16* __restrict__ q2p,
    u16* __restrict__ k1p, u16* __restrict__ k2p, u16* __restrict__ vtp,
    const float* __restrict__ bq, const float* __restrict__ bk,
    const float* __restrict__ bvp) {
  __shared__ u16 lA[128 * 32];
  __shared__ u16 lB[128 * 32];
  const int t = threadIdx.x;
  const int lane = t & 63, wave = t >> 6;
  const int quad = lane >> 4, l16 = lane & 15;
  const int wm = wave & 1, wn = wave >> 1;
  const int m0 = blockIdx.x * 128;
  const int n0 = blockIdx.y * 128;

  f32x4 zero = {0.f, 0.f, 0.f, 0.f};
  f32x4 acc[4][4];
  for (int i = 0; i < 4; ++i) for (int j = 0; j < 4; ++j) acc[i][j] = zero;

  // staging: wave w owns rows w*32..w*32+31 (2 chunks of 16 rows);
  // lane -> row base + lane/4, col (lane%4)*8  (LDS offset == lane*16 B)
  const int srow = wave * 32 + (lane >> 2);
  const int scol = (lane & 3) * 8;
  const u16* gA = A + (size_t)(m0 + srow) * 768 + scol;
  const u16* gB = Bt + (size_t)(n0 + srow) * 768 + scol;
  u16* sA = lA + wave * 1024;   // wave-uniform LDS base
  u16* sB = lB + wave * 1024;

  for (int k0 = 0; k0 < 768; k0 += 32) {
    gl2lds16(gA + k0, sA);
    gl2lds16(gA + k0 + 16 * 768, sA + 512);
    gl2lds16(gB + k0, sB);
    gl2lds16(gB + k0 + 16 * 768, sB + 512);
    __syncthreads();
    bf16x8 af[4], bfr[4];
#pragma unroll
    for (int i = 0; i < 4; ++i)
      af[i] = *(const bf16x8*)(lA + (wm * 64 + i * 16 + l16) * 32 + quad * 8);
#pragma unroll
    for (int j = 0; j < 4; ++j)
      bfr[j] = *(const bf16x8*)(lB + (wn * 64 + j * 16 + l16) * 32 + quad * 8);
#pragma unroll
    for (int i = 0; i < 4; ++i)
#pragma unroll
      for (int j = 0; j < 4; ++j)
        acc[i][j] = __builtin_amdgcn_mfma_f32_16x16x32_bf16(af[i], bfr[j], acc[i][j], 0, 0, 0);
    __syncthreads();
  }

#pragma unroll
  for (int i = 0; i < 4; ++i) {
#pragma unroll
    for (int j = 0; j < 4; ++j) {
      int n = n0 + wn * 64 + j * 16 + l16;
#pragma unroll
      for (int r = 0; r < 4; ++r) {
        int m = m0 + wm * 64 + i * 16 + quad * 4 + r;
        if (m >= M_ROWS) continue;
        float v = acc[i][j][r];
        if (mode == 0) {
          outF[(size_t)m * N + n] = v + biasO[n];
        } else {
          int b = m / 577;
          int s = m - b * 577;
          if (n < 1536) {
            int ch = (n < 768) ? n : (n - 768);
            u16* dst = (n < 768) ? q1p : q2p;
            dst[(((size_t)b * 12 + (ch >> 6)) * 577 + s) * 64 + (ch & 63)] = f2bu(v + bq[n]);
          } else if (n < 3072) {
            int nn = n - 1536;
            int ch = (nn < 768) ? nn : (nn - 768);
            u16* dst = (nn < 768) ? k1p : k2p;
            dst[(((size_t)b * 12 + (ch >> 6)) * 577 + s) * 64 + (ch & 63)] = f2bu(v + bk[nn]);
          } else {
            int ch = n - 3072;
            vtp[(((size_t)b * 12 + (ch >> 6)) * 64 + (ch & 63)) * VT_STRIDE + s] = f2bu(v + bvp[ch]);
          }
        }
      }
    }
  }
}

// ---------------- flash-style differential attention (no-max softmax) --------
// R8 (resubmit after infra failure): shared-LDS KV staging (T3-lite 2-phase
// template). 4 waves per block share one bh; K1/K2/V KV-block tiles staged
// once into double-buffered LDS via global_load_lds (per-wave global loads
// 12 -> 3/4 each iter; block request volume /4). Next block staged while
// current computes; the compiler's vmcnt(0)-before-barrier drains it.
// K tiles XOR-swizzled on the SOURCE address (rule 21) so stride-128B
// ds_read_b128 is conflict-free; V uses a 4-slot swizzle. Tail masking
// peeled (18 unmasked + 1 masked). Per-wave compute pipeline identical to
// the R5 kernel (known-good).
__global__ __launch_bounds__(256, 4) void attn(
    const u16* __restrict__ q1, const u16* __restrict__ q2,
    const u16* __restrict__ k1, const u16* __restrict__ k2,
    const u16* __restrict__ vt, u16* __restrict__ ctx_t,
    const float* __restrict__ lam_p) {
  __shared__ u16 sk1[2][2048];      // [buf][32 kv rows][64], rows 128B, swizzled
  __shared__ u16 sk2[2][2048];
  __shared__ u16 sv[2][2048];       // [buf][64 d rows][32 kv], rows 64B, swizzled
  __shared__ u16 pls[4][2][16 * 40];// per-wave P staging (D-layout -> A-layout)

  const int tid = threadIdx.x;
  const int wave = tid >> 6;
  const int lane = tid & 63;
  const int quad = lane >> 4, l16 = lane & 15;

  // XCD-locality decode: 1920 blocks = 8 xcd * (24 bh * 10 qgroups), bh-major
  const int bid = blockIdx.x;
  const int xcd = bid & 7;
  const int slot = bid >> 3;            // 0..239
  const int bhl = slot / 10;
  const int qgroup = slot - bhl * 10;
  const int bh = xcd * 24 + bhl;
  const int q0 = (qgroup * 4 + wave) * 16;   // may exceed 576 (idle-ish wave)

  const float lam = lam_p[0];
  const float CEXP = 0.125f * 1.44269504f;   // scale * log2(e), folded
  const size_t qkbase = (size_t)bh * S_LEN * DH;
  const size_t vbase = (size_t)bh * 64 * VT_STRIDE;

  // ---- staging geometry (per thread, constant) ----
  // K tile: 32 rows x 128B; thread -> row tid/8, 16B slot tid%8; source col
  // pre-swizzled so LDS[row][cb] = G[row][cb ^ ((row&7)<<4)]
  const int krow = tid >> 3;
  const int kelem = ((((tid & 7) << 4) ^ ((krow & 7) << 4)) >> 1); // 0..56
  const u16* k1s = k1 + qkbase + (size_t)krow * 64 + kelem;
  const u16* k2s = k2 + qkbase + (size_t)krow * 64 + kelem;
  // V tile: 64 rows x 64B; thread -> row tid/4, slot tid%4;
  // LDS[row][cb] = G[row][cb ^ ((row&3)<<4)]
  const int vrow = tid >> 2;
  const int vel = ((((tid & 3) << 4) ^ ((vrow & 3) << 4)) >> 1);   // 0,8,16,24
  const u16* vs = vt + vbase + (size_t)vrow * VT_STRIDE + vel;
  const int w512 = wave * 512;   // per-wave LDS chunk (1024 B) for staging

  // ---- q fragments (registers, whole kernel) ----
  int qr = q0 + l16; if (qr > 576) qr = 576;   // clamp tail (results discarded)
  bf16x8 q1f[2], q2f[2];
#pragma unroll
  for (int c = 0; c < 2; ++c) {
    q1f[c] = *(const bf16x8*)(q1 + qkbase + (size_t)qr * 64 + c * 32 + quad * 8);
    q2f[c] = *(const bf16x8*)(q2 + qkbase + (size_t)qr * 64 + c * 32 + quad * 8);
  }

  f32x4 zero = {0.f, 0.f, 0.f, 0.f};
  f32x4 O1[4], O2[4];
  float l1[4], l2[4];
#pragma unroll
  for (int i = 0; i < 4; ++i) { O1[i] = zero; O2[i] = zero; l1[i] = 0.f; l2[i] = 0.f; }

  u16* p1w = &pls[wave][0][0];
  u16* p2w = &pls[wave][1][0];

  // read-side swizzle constants
  const int xk = (l16 & 7) << 4;
  const int xv = (l16 & 3) << 4;

  // ---- prologue: stage KV block 0 into buf 0 ----
  gl2lds16(k1s, &sk1[0][0] + w512);
  gl2lds16(k2s, &sk2[0][0] + w512);
  gl2lds16(vs, &sv[0][0] + w512);
  __syncthreads();   // compiler emits vmcnt(0) before s_barrier

  int cur = 0;
  for (int kb = 0; kb < 18; ++kb) {
    // stage next KV block into buf cur^1 (async; drained at the barrier)
    if (kb < 17) {
      gl2lds16(k1s + (kb + 1) * 2048, &sk1[cur ^ 1][0] + w512);
      gl2lds16(k2s + (kb + 1) * 2048, &sk2[cur ^ 1][0] + w512);
      gl2lds16(vs + (kb + 1) * 32, &sv[cur ^ 1][0] + w512);
    } else {
      // final block: all K rows clamp to row 576 (masked in the peel)
      gl2lds16(k1 + qkbase + 576 * 64 + kelem, &sk1[cur ^ 1][0] + w512);
      gl2lds16(k2 + qkbase + 576 * 64 + kelem, &sk2[cur ^ 1][0] + w512);
      gl2lds16(vs + 576, &sv[cur ^ 1][0] + w512);
    }

    // LDS -> register fragments (swizzled reads)
    const char* bk1 = (const char*)&sk1[cur][0];
    const char* bk2 = (const char*)&sk2[cur][0];
    const char* bv = (const char*)&sv[cur][0];
    bf16x8 k1f[2][2], k2f[2][2], vf[4];
#pragma unroll
    for (int tt = 0; tt < 2; ++tt) {
      int rb = (tt * 16 + l16) * 128;
      k1f[tt][0] = *(const bf16x8*)(bk1 + rb + ((quad * 16) ^ xk));
      k1f[tt][1] = *(const bf16x8*)(bk1 + rb + ((64 + quad * 16) ^ xk));
      k2f[tt][0] = *(const bf16x8*)(bk2 + rb + ((quad * 16) ^ xk));
      k2f[tt][1] = *(const bf16x8*)(bk2 + rb + ((64 + quad * 16) ^ xk));
    }
#pragma unroll
    for (int tt = 0; tt < 4; ++tt)
      vf[tt] = *(const bf16x8*)(bv + (tt * 16 + l16) * 64 + ((quad * 16) ^ xv));

    f32x4 s1[2], s2[2];
    __builtin_amdgcn_s_setprio(1);
#pragma unroll
    for (int tt = 0; tt < 2; ++tt) {
      s1[tt] = __builtin_amdgcn_mfma_f32_16x16x32_bf16(q1f[0], k1f[tt][0], zero, 0, 0, 0);
      s1[tt] = __builtin_amdgcn_mfma_f32_16x16x32_bf16(q1f[1], k1f[tt][1], s1[tt], 0, 0, 0);
      s2[tt] = __builtin_amdgcn_mfma_f32_16x16x32_bf16(q2f[0], k2f[tt][0], zero, 0, 0, 0);
      s2[tt] = __builtin_amdgcn_mfma_f32_16x16x32_bf16(q2f[1], k2f[tt][1], s2[tt], 0, 0, 0);
    }
    __builtin_amdgcn_s_setprio(0);

    // unmasked exp + partial sums + P staging (kv rows all < 577 here)
#pragma unroll
    for (int i = 0; i < 4; ++i) {
      float p10 = exp2f(s1[0][i] * CEXP);
      float p11 = exp2f(s1[1][i] * CEXP);
      float p20 = exp2f(s2[0][i] * CEXP);
      float p21 = exp2f(s2[1][i] * CEXP);
      l1[i] += p10 + p11;
      l2[i] += p20 + p21;
      // truncating bf16 convert (cheap; ~0.1% bias, well under budget)
      p1w[(quad * 4 + i) * 40 + l16]      = (u16)(__float_as_uint(p10) >> 16);
      p1w[(quad * 4 + i) * 40 + l16 + 16] = (u16)(__float_as_uint(p11) >> 16);
      p2w[(quad * 4 + i) * 40 + l16]      = (u16)(__float_as_uint(p20) >> 16);
      p2w[(quad * 4 + i) * 40 + l16 + 16] = (u16)(__float_as_uint(p21) >> 16);
    }
    bf16x8 p1a = *(const bf16x8*)(p1w + l16 * 40 + quad * 8);
    bf16x8 p2a = *(const bf16x8*)(p2w + l16 * 40 + quad * 8);
    __builtin_amdgcn_s_setprio(1);
#pragma unroll
    for (int tt = 0; tt < 4; ++tt) {
      O1[tt] = __builtin_amdgcn_mfma_f32_16x16x32_bf16(p1a, vf[tt], O1[tt], 0, 0, 0);
      O2[tt] = __builtin_amdgcn_mfma_f32_16x16x32_bf16(p2a, vf[tt], O2[tt], 0, 0, 0);
    }
    __builtin_amdgcn_s_setprio(0);
    __syncthreads();
    cur ^= 1;
  }

  // ---- peeled final block (kv0 = 576): only kv==576 (l16==0, tt==0) valid
  {
    const char* bk1 = (const char*)&sk1[cur][0];
    const char* bk2 = (const char*)&sk2[cur][0];
    const char* bv = (const char*)&sv[cur][0];
    int rb = l16 * 128;
    bf16x8 ka0 = *(const bf16x8*)(bk1 + rb + ((quad * 16) ^ xk));
    bf16x8 ka1 = *(const bf16x8*)(bk1 + rb + ((64 + quad * 16) ^ xk));
    bf16x8 kb0 = *(const bf16x8*)(bk2 + rb + ((quad * 16) ^ xk));
    bf16x8 kb1 = *(const bf16x8*)(bk2 + rb + ((64 + quad * 16) ^ xk));
    f32x4 s1t = __builtin_amdgcn_mfma_f32_16x16x32_bf16(q1f[0], ka0, zero, 0, 0, 0);
    s1t = __builtin_amdgcn_mfma_f32_16x16x32_bf16(q1f[1], ka1, s1t, 0, 0, 0);
    f32x4 s2t = __builtin_amdgcn_mfma_f32_16x16x32_bf16(q2f[0], kb0, zero, 0, 0, 0);
    s2t = __builtin_amdgcn_mfma_f32_16x16x32_bf16(q2f[1], kb1, s2t, 0, 0, 0);
    bf16x8 vf[4];
#pragma unroll
    for (int tt = 0; tt < 4; ++tt)
      vf[tt] = *(const bf16x8*)(bv + (tt * 16 + l16) * 64 + ((quad * 16) ^ xv));
    bool ok = (l16 == 0);
#pragma unroll
    for (int i = 0; i < 4; ++i) {
      float p10 = ok ? exp2f(s1t[i] * CEXP) : 0.f;
      float p20 = ok ? exp2f(s2t[i] * CEXP) : 0.f;
      l1[i] += p10; l2[i] += p20;
      p1w[(quad * 4 + i) * 40 + l16]      = (u16)(__float_as_uint(p10) >> 16);
      p1w[(quad * 4 + i) * 40 + l16 + 16] = 0;
      p2w[(quad * 4 + i) * 40 + l16]      = (u16)(__float_as_uint(p20) >> 16);
      p2w[(quad * 4 + i) * 40 + l16 + 16] = 0;
    }
    bf16x8 p1a = *(const bf16x8*)(p1w + l16 * 40 + quad * 8);
    bf16x8 p2a = *(const bf16x8*)(p2w + l16 * 40 + quad * 8);
#pragma unroll
    for (int tt = 0; tt < 4; ++tt) {
      O1[tt] = __builtin_amdgcn_mfma_f32_16x16x32_bf16(p1a, vf[tt], O1[tt], 0, 0, 0);
      O2[tt] = __builtin_amdgcn_mfma_f32_16x16x32_bf16(p2a, vf[tt], O2[tt], 0, 0, 0);
    }
  }

  // reduce partial row-sums across the quad's 16 lanes
#pragma unroll
  for (int d = 1; d < 16; d <<= 1)
#pragma unroll
    for (int i = 0; i < 4; ++i) {
      l1[i] += __shfl_xor(l1[i], d);
      l2[i] += __shfl_xor(l2[i], d);
    }
  float inv1[4], inv2[4];
#pragma unroll
  for (int i = 0; i < 4; ++i) { inv1[i] = 1.f / l1[i]; inv2[i] = 1.f / l2[i]; }
#pragma unroll
  for (int tt = 0; tt < 4; ++tt) {
    size_t cb = ((size_t)bh * 64 + tt * 16 + l16) * S_LEN;
#pragma unroll
    for (int i = 0; i < 4; ++i) {
      int s = q0 + quad * 4 + i;
      if (s < S_LEN)
        ctx_t[cb + s] = f2bu(O1[tt][i] * inv1[i] - lam * O2[tt][i] * inv2[i]);
    }
  }
}

// ---------------- GroupNorm over (b,h): Dh*S elements, then affine ----------
// ctx_t [B,H,64,S] -> context flat [B][D*S] (== reference's reinterpret trick)
__global__ __launch_bounds__(256) void gnorm(
    const u16* __restrict__ ctx_t, u16* __restrict__ context,
    const float* __restrict__ gw, const float* __restrict__ gb) {
  const int bh = blockIdx.x;
  const int h = bh % 12;
  const int NEL = 64 * S_LEN;          // 36928
  const int NV = NEL / 8;              // 4616
  const u16* src = ctx_t + (size_t)bh * NEL;
  float sum = 0.f, sq = 0.f;
  for (int v = threadIdx.x; v < NV; v += 256) {
    uint4 raw = *(const uint4*)(src + v * 8);
    uint32_t w[4] = {raw.x, raw.y, raw.z, raw.w};
#pragma unroll
    for (int j = 0; j < 4; ++j) {
      float f0 = bu2f((u16)(w[j] & 0xffff));
      float f1 = bu2f((u16)(w[j] >> 16));
      sum += f0 + f1; sq += f0 * f0 + f1 * f1;
    }
  }
#pragma unroll
  for (int d = 1; d < 64; d <<= 1) {
    sum += __shfl_xor(sum, d);
    sq += __shfl_xor(sq, d);
  }
  __shared__ float rs[4], rq[4];
  __shared__ float wv[64], bv2[64];
  int wave = threadIdx.x >> 6;
  if ((threadIdx.x & 63) == 0) { rs[wave] = sum; rq[wave] = sq; }
  __syncthreads();
  float ts = rs[0] + rs[1] + rs[2] + rs[3];
  float tq = rq[0] + rq[1] + rq[2] + rq[3];
  const float Ninv = 1.0f / (float)NEL;
  float mu = ts * Ninv;
  float var = tq * Ninv - mu * mu;
  float rstd = rsqrtf(var + 1e-5f);
  if (threadIdx.x < 64) {
    float w = gw[h * 64 + threadIdx.x] * rstd;
    wv[threadIdx.x] = w;
    bv2[threadIdx.x] = gb[h * 64 + threadIdx.x] - mu * w;
  }
  __syncthreads();
  u16* dst = context + (size_t)bh * NEL;   // b*(768*577) + h*(64*577)
  for (int v = threadIdx.x; v < NV; v += 256) {
    uint4 raw = *(const uint4*)(src + v * 8);
    uint32_t w[4] = {raw.x, raw.y, raw.z, raw.w};
    int base = v * 8;
    int d0 = base / 577;
    int r0 = base - d0 * 577;
    u16 o[8];
#pragma unroll
    for (int j = 0; j < 4; ++j) {
#pragma unroll
      for (int e = 0; e < 2; ++e) {
        int ii = j * 2 + e;
        int dd = (r0 + ii >= 577) ? d0 + 1 : d0;
        float f = bu2f((u16)(e == 0 ? (w[j] & 0xffff) : (w[j] >> 16)));
        o[ii] = f2bu(f * wv[dd] + bv2[dd]);
      }
    }
    *(uint4*)(dst + base) = *(const uint4*)o;
  }
}

extern "C" void kernel_launch(void* const* d_in, const int* in_sizes, int n_in,
                              void* d_out, int out_size, void* d_ws, size_t ws_size,
                              hipStream_t stream) {
  const float* x   = (const float*)d_in[0];
  const float* Wq  = (const float*)d_in[1];
  const float* bq  = (const float*)d_in[2];
  const float* Wk  = (const float*)d_in[3];
  const float* bk  = (const float*)d_in[4];
  const float* Wv  = (const float*)d_in[5];
  const float* bv  = (const float*)d_in[6];
  const float* Wo  = (const float*)d_in[7];
  const float* bo  = (const float*)d_in[8];
  const float* lam = (const float*)d_in[9];
  const float* gw  = (const float*)d_in[10];
  const float* gb  = (const float*)d_in[11];
  float* out = (float*)d_out;

  char* p = (char*)d_ws;
  auto alloc = [&](size_t bytes) {
    char* r = p;
    p += (bytes + 255) & ~(size_t)255;
    return r;
  };
  u16* xb     = (u16*)alloc((size_t)M_PAD * 768 * 2);   // also reused as ctxbuf
  u16* wtqkv  = (u16*)alloc((size_t)3840 * 768 * 2);
  u16* wot    = (u16*)alloc((size_t)768 * 768 * 2);
  u16* q1b    = (u16*)alloc((size_t)192 * 577 * 64 * 2);
  u16* q2b    = (u16*)alloc((size_t)192 * 577 * 64 * 2);
  u16* k1b    = (u16*)alloc((size_t)192 * 577 * 64 * 2);
  u16* k2b    = (u16*)alloc((size_t)192 * 577 * 64 * 2);
  u16* vtb    = (u16*)alloc((size_t)192 * 64 * VT_STRIDE * 2);
  u16* ctxt   = (u16*)alloc((size_t)192 * 64 * S_LEN * 2);
  u16* ctxbuf = xb;   // alias: xb is dead after the QKV GEMM; keeps ws ~108 MB

  prep_x<<<(M_PAD * 768 / 8 + 255) / 256, 256, 0, stream>>>(x, xb);
  prep_w<<<3456, 256, 0, stream>>>(Wq, Wk, Wv, Wo, wtqkv, wot);

  gemm_bf16<<<dim3(73, 30), 256, 0, stream>>>(xb, wtqkv, 3840, 1,
      nullptr, nullptr, q1b, q2b, k1b, k2b, vtb, bq, bk, bv);

  attn<<<dim3(1920), 256, 0, stream>>>(q1b, q2b, k1b, k2b, vtb, ctxt, lam);

  gnorm<<<192, 256, 0, stream>>>(ctxt, ctxbuf, gw, gb);

  gemm_bf16<<<dim3(73, 6), 256, 0, stream>>>(ctxbuf, wot, 768, 0,
      out, bo, nullptr, nullptr, nullptr, nullptr, nullptr, nullptr, nullptr, nullptr);
}

// Round 5
// 329.225 us; speedup vs baseline: 1.6360x; 1.1099x over previous
//
#include <hip/hip_runtime.h>
#include <hip/hip_bf16.h>
#include <stdint.h>

typedef unsigned short u16;
typedef __attribute__((ext_vector_type(8))) short bf16x8;
typedef __attribute__((ext_vector_type(4))) float f32x4;

#define S_LEN 577
#define DMODEL 768
#define NHEAD 12
#define DH 64
#define BATCH 16
#define M_ROWS (BATCH * S_LEN)   /* 9232 */
#define M_PAD 9344               /* 73 * 128 */
#define VT_STRIDE 640            /* padded S so 16B frag loads stay aligned */

__device__ __forceinline__ u16 f2bu(float f) {
  uint32_t u = __float_as_uint(f);
  u += 0x7FFFu + ((u >> 16) & 1u);      // RNE; inputs are finite
  return (u16)(u >> 16);
}
__device__ __forceinline__ float bu2f(u16 b) {
  return __uint_as_float(((uint32_t)b) << 16);
}
// async global->LDS, 16B per lane; LDS dest = wave-uniform base + lane*16
__device__ __forceinline__ void gl2lds16(const u16* g, u16* l) {
  __builtin_amdgcn_global_load_lds(
      (const __attribute__((address_space(1))) unsigned int*)g,
      (__attribute__((address_space(3))) unsigned int*)l, 16, 0, 0);
}

// ---------------- prep: x fp32 -> bf16 [M_PAD,768], pad rows zeroed ----------
__global__ __launch_bounds__(256) void prep_x(const float* __restrict__ x,
                                              u16* __restrict__ xb) {
  int e = (blockIdx.x * 256 + threadIdx.x) * 8;
  u16 o[8];
  if (e < M_ROWS * DMODEL) {
    float4 f0 = *(const float4*)(x + e);
    float4 f1 = *(const float4*)(x + e + 4);
    o[0] = f2bu(f0.x); o[1] = f2bu(f0.y); o[2] = f2bu(f0.z); o[3] = f2bu(f0.w);
    o[4] = f2bu(f1.x); o[5] = f2bu(f1.y); o[6] = f2bu(f1.z); o[7] = f2bu(f1.w);
  } else {
#pragma unroll
    for (int i = 0; i < 8; ++i) o[i] = 0;
  }
  *(uint4*)(xb + e) = *(const uint4*)o;
}

// ------------- prep: weights fp32 [K,N] -> bf16 transposed [N,K], tiled ------
// wtqkv rows: [0,1536)=Wq^T, [1536,3072)=Wk^T, [3072,3840)=Wv^T ; wot = Wo^T
__global__ __launch_bounds__(256) void prep_w(
    const float* __restrict__ Wq, const float* __restrict__ Wk,
    const float* __restrict__ Wv, const float* __restrict__ Wo,
    u16* __restrict__ wtqkv, u16* __restrict__ wot) {
  __shared__ u16 tile[32][33];
  int blk = blockIdx.x;
  const float* W; int N; u16* dst; int rowbase;
  if (blk < 1152)      { W = Wq; N = 1536; dst = wtqkv; rowbase = 0; }
  else if (blk < 2304) { W = Wk; N = 1536; dst = wtqkv; rowbase = 1536; blk -= 1152; }
  else if (blk < 2880) { W = Wv; N = 768;  dst = wtqkv; rowbase = 3072; blk -= 2304; }
  else                 { W = Wo; N = 768;  dst = wot;   rowbase = 0;    blk -= 2880; }
  const int ntiles = N >> 5;
  const int tk = blk / ntiles, tn = blk - tk * ntiles;
  const int c = threadIdx.x & 31, r0 = threadIdx.x >> 5;
#pragma unroll
  for (int i = 0; i < 4; ++i) {
    int r = i * 8 + r0;
    tile[r][c] = f2bu(W[(size_t)(tk * 32 + r) * N + tn * 32 + c]);
  }
  __syncthreads();
#pragma unroll
  for (int i = 0; i < 4; ++i) {
    int r = i * 8 + r0;
    dst[(size_t)(rowbase + tn * 32 + r) * 768 + tk * 32 + c] = tile[c][r];
  }
}

// ---------------- bf16 MFMA GEMM: C[M,N] = A[M,768] * Bt[N,768]^T ------------
// m97 structure: global_load_lds width-16 staging into unpadded 128x32 tiles.
// mode 0: out fp32 [M_ROWS,N] + biasO[n]  (output projection)
// mode 1: scatter -> q1/q2/k1/k2 [B,H,S,64] bf16, v -> vt [B,H,64,640]
// R9: mode-1 epilogue rewritten. The old per-element u16 scatter (2B per
// cacheline at 1280B stride for vt) caused massive write-allocate RMW
// (FETCH 215MB vs ~20MB input). New: reuse the (dead) 16KB staging LDS as a
// bias-applied bf16 tile per 64-col half; XOR-swizzled deposit, then all
// threads stream full 16B uint4 stores forming contiguous 128B (q/k) /
// 256B (vt, LDS-transposed) lines. vt falls back to scalar only at batch
// boundaries.
__global__ __launch_bounds__(256, 2) void gemm_bf16(
    const u16* __restrict__ A, const u16* __restrict__ Bt, int N, int mode,
    float* __restrict__ outF, const float* __restrict__ biasO,
    u16* __restrict__ q1p, u16* __restrict__ q2p,
    u16* __restrict__ k1p, u16* __restrict__ k2p, u16* __restrict__ vtp,
    const float* __restrict__ bq, const float* __restrict__ bk,
    const float* __restrict__ bvp) {
  __shared__ __align__(16) u16 smem[8192];   // lA(4096) + lB(4096); epilogue tile
  u16* lA = smem;
  u16* lB = smem + 4096;
  const int t = threadIdx.x;
  const int lane = t & 63, wave = t >> 6;
  const int quad = lane >> 4, l16 = lane & 15;
  const int wm = wave & 1, wn = wave >> 1;
  const int m0 = blockIdx.x * 128;
  const int n0 = blockIdx.y * 128;

  f32x4 zero = {0.f, 0.f, 0.f, 0.f};
  f32x4 acc[4][4];
  for (int i = 0; i < 4; ++i) for (int j = 0; j < 4; ++j) acc[i][j] = zero;

  // staging: wave w owns rows w*32..w*32+31 (2 chunks of 16 rows);
  // lane -> row base + lane/4, col (lane%4)*8  (LDS offset == lane*16 B)
  const int srow = wave * 32 + (lane >> 2);
  const int scol = (lane & 3) * 8;
  const u16* gA = A + (size_t)(m0 + srow) * 768 + scol;
  const u16* gB = Bt + (size_t)(n0 + srow) * 768 + scol;
  u16* sA = lA + wave * 1024;   // wave-uniform LDS base
  u16* sB = lB + wave * 1024;

  for (int k0 = 0; k0 < 768; k0 += 32) {
    gl2lds16(gA + k0, sA);
    gl2lds16(gA + k0 + 16 * 768, sA + 512);
    gl2lds16(gB + k0, sB);
    gl2lds16(gB + k0 + 16 * 768, sB + 512);
    __syncthreads();
    bf16x8 af[4], bfr[4];
#pragma unroll
    for (int i = 0; i < 4; ++i)
      af[i] = *(const bf16x8*)(lA + (wm * 64 + i * 16 + l16) * 32 + quad * 8);
#pragma unroll
    for (int j = 0; j < 4; ++j)
      bfr[j] = *(const bf16x8*)(lB + (wn * 64 + j * 16 + l16) * 32 + quad * 8);
#pragma unroll
    for (int i = 0; i < 4; ++i)
#pragma unroll
      for (int j = 0; j < 4; ++j)
        acc[i][j] = __builtin_amdgcn_mfma_f32_16x16x32_bf16(af[i], bfr[j], acc[i][j], 0, 0, 0);
    __syncthreads();
  }

  if (mode == 0) {
#pragma unroll
    for (int i = 0; i < 4; ++i) {
#pragma unroll
      for (int j = 0; j < 4; ++j) {
        int n = n0 + wn * 64 + j * 16 + l16;
#pragma unroll
        for (int r = 0; r < 4; ++r) {
          int m = m0 + wm * 64 + i * 16 + quad * 4 + r;
          if (m >= M_ROWS) continue;
          outF[(size_t)m * N + n] = acc[i][j][r] + biasO[n];
        }
      }
    }
    return;
  }

  // ---------------- mode 1 epilogue: LDS-staged coalesced writes ------------
  u16* tile = smem;   // 8192 u16 = 16 KB, staging data is dead now
  const bool isv = (n0 >= 3072);
  u16* dstqk = nullptr; const float* biasp = nullptr; int ch0 = 0;
  if (!isv) {
    if (n0 < 768)       { dstqk = q1p; biasp = bq + n0;          ch0 = n0; }
    else if (n0 < 1536) { dstqk = q2p; biasp = bq + n0;          ch0 = n0 - 768; }
    else if (n0 < 2304) { dstqk = k1p; biasp = bk + (n0 - 1536); ch0 = n0 - 1536; }
    else                { dstqk = k2p; biasp = bk + (n0 - 1536); ch0 = n0 - 2304; }
  }
  const int ch0v = n0 - 3072;

#pragma unroll
  for (int hf = 0; hf < 2; ++hf) {
    __syncthreads();
    if (wn == hf) {
      if (!isv) {
        // tile[m 0..127][col 0..63] (d-major lines), chunk-XOR swizzle by m&3
        float bfv[4];
#pragma unroll
        for (int j = 0; j < 4; ++j) bfv[j] = biasp[hf * 64 + j * 16 + l16];
#pragma unroll
        for (int i = 0; i < 4; ++i)
#pragma unroll
          for (int j = 0; j < 4; ++j) {
            int col = j * 16 + l16;
#pragma unroll
            for (int r = 0; r < 4; ++r) {
              int m = wm * 64 + i * 16 + quad * 4 + r;
              int addr = m * 64 + (col & 15) + ((((col >> 4) ^ (m & 3)) & 3) << 4);
              tile[addr] = f2bu(acc[i][j][r] + bfv[j]);
            }
          }
      } else {
        // transposed: tile[d 0..63][s 0..127], chunk-XOR swizzle by d&7
        float bfv[4];
#pragma unroll
        for (int j = 0; j < 4; ++j) bfv[j] = bvp[ch0v + hf * 64 + j * 16 + l16];
#pragma unroll
        for (int i = 0; i < 4; ++i)
#pragma unroll
          for (int j = 0; j < 4; ++j) {
            int d = j * 16 + l16;
#pragma unroll
            for (int r = 0; r < 4; ++r) {
              int m = wm * 64 + i * 16 + quad * 4 + r;   // s within tile
              int addr = d * 128 + (m & 15) + ((((m >> 4) ^ (d & 7)) & 7) << 4);
              tile[addr] = f2bu(acc[i][j][r] + bfv[j]);
            }
          }
      }
    }
    __syncthreads();

    if (!isv) {
      // 128 lines of 128B: line = m (one s, one head); 8 threads x uint4 each
      const int line = t >> 3;
      const int col0 = (t & 7) * 8;
      const int head = (ch0 >> 6) + hf;
#pragma unroll
      for (int p = 0; p < 4; ++p) {
        int m = p * 32 + line;
        int mg = m0 + m;
        if (mg < M_ROWS) {
          int addr = m * 64 + (col0 & 15) + ((((col0 >> 4) ^ (m & 3)) & 3) << 4);
          uint4 v4 = *(const uint4*)(tile + addr);
          int b = mg / 577;
          int s = mg - b * 577;
          *(uint4*)(dstqk + (((size_t)(b * 12 + head) * 577 + s) * 64 + col0)) = v4;
        }
      }
    } else {
      // 64 lines of 256B: line = d; 16 threads x uint4 each (s-contiguous)
      const int line = t >> 4;
      const int col0 = (t & 15) * 8;
      const int hh = (ch0v >> 6) + hf;
#pragma unroll
      for (int p = 0; p < 4; ++p) {
        int d = p * 16 + line;
        int addr = d * 128 + (col0 & 15) + ((((col0 >> 4) ^ (d & 7)) & 7) << 4);
        uint4 v4 = *(const uint4*)(tile + addr);
        int sg0 = m0 + col0;
        int b0 = sg0 / 577, b7 = (sg0 + 7) / 577;
        if (sg0 + 7 < M_ROWS && b0 == b7) {
          *(uint4*)(vtp + (((size_t)(b0 * 12 + hh) * 64 + d) * VT_STRIDE + (sg0 - b0 * 577))) = v4;
        } else {
          const u16* ev = (const u16*)&v4;
          for (int e = 0; e < 8; ++e) {
            int sg = sg0 + e;
            if (sg >= M_ROWS) break;
            int bb = sg / 577;
            vtp[((size_t)(bb * 12 + hh) * 64 + d) * VT_STRIDE + (sg - bb * 577)] = ev[e];
          }
        }
      }
    }
  }
}

// ---------------- flash-style differential attention (no-max softmax) --------
// R8: shared-LDS KV staging (T3-lite 2-phase template). 4 waves per block
// share one bh; K1/K2/V KV-block tiles staged once into double-buffered LDS
// via global_load_lds (per-wave global loads 12 -> 3/4 each iter; block
// request volume /4). Next block staged while current computes; the
// compiler's vmcnt(0)-before-barrier drains it. K tiles XOR-swizzled on the
// SOURCE address (rule 21) so stride-128B ds_read_b128 is conflict-free;
// V uses a 4-slot swizzle. Tail masking peeled (18 unmasked + 1 masked).
// Per-wave compute pipeline identical to the R5 kernel (known-good).
__global__ __launch_bounds__(256, 4) void attn(
    const u16* __restrict__ q1, const u16* __restrict__ q2,
    const u16* __restrict__ k1, const u16* __restrict__ k2,
    const u16* __restrict__ vt, u16* __restrict__ ctx_t,
    const float* __restrict__ lam_p) {
  __shared__ u16 sk1[2][2048];      // [buf][32 kv rows][64], rows 128B, swizzled
  __shared__ u16 sk2[2][2048];
  __shared__ u16 sv[2][2048];       // [buf][64 d rows][32 kv], rows 64B, swizzled
  __shared__ u16 pls[4][2][16 * 40];// per-wave P staging (D-layout -> A-layout)

  const int tid = threadIdx.x;
  const int wave = tid >> 6;
  const int lane = tid & 63;
  const int quad = lane >> 4, l16 = lane & 15;

  // XCD-locality decode: 1920 blocks = 8 xcd * (24 bh * 10 qgroups), bh-major
  const int bid = blockIdx.x;
  const int xcd = bid & 7;
  const int slot = bid >> 3;            // 0..239
  const int bhl = slot / 10;
  const int qgroup = slot - bhl * 10;
  const int bh = xcd * 24 + bhl;
  const int q0 = (qgroup * 4 + wave) * 16;   // may exceed 576 (idle-ish wave)

  const float lam = lam_p[0];
  const float CEXP = 0.125f * 1.44269504f;   // scale * log2(e), folded
  const size_t qkbase = (size_t)bh * S_LEN * DH;
  const size_t vbase = (size_t)bh * 64 * VT_STRIDE;

  // ---- staging geometry (per thread, constant) ----
  // K tile: 32 rows x 128B; thread -> row tid/8, 16B slot tid%8; source col
  // pre-swizzled so LDS[row][cb] = G[row][cb ^ ((row&7)<<4)]
  const int krow = tid >> 3;
  const int kelem = ((((tid & 7) << 4) ^ ((krow & 7) << 4)) >> 1); // 0..56
  const u16* k1s = k1 + qkbase + (size_t)krow * 64 + kelem;
  const u16* k2s = k2 + qkbase + (size_t)krow * 64 + kelem;
  // V tile: 64 rows x 64B; thread -> row tid/4, slot tid%4;
  // LDS[row][cb] = G[row][cb ^ ((row&3)<<4)]
  const int vrow = tid >> 2;
  const int vel = ((((tid & 3) << 4) ^ ((vrow & 3) << 4)) >> 1);   // 0,8,16,24
  const u16* vs = vt + vbase + (size_t)vrow * VT_STRIDE + vel;
  const int w512 = wave * 512;   // per-wave LDS chunk (1024 B) for staging

  // ---- q fragments (registers, whole kernel) ----
  int qr = q0 + l16; if (qr > 576) qr = 576;   // clamp tail (results discarded)
  bf16x8 q1f[2], q2f[2];
#pragma unroll
  for (int c = 0; c < 2; ++c) {
    q1f[c] = *(const bf16x8*)(q1 + qkbase + (size_t)qr * 64 + c * 32 + quad * 8);
    q2f[c] = *(const bf16x8*)(q2 + qkbase + (size_t)qr * 64 + c * 32 + quad * 8);
  }

  f32x4 zero = {0.f, 0.f, 0.f, 0.f};
  f32x4 O1[4], O2[4];
  float l1[4], l2[4];
#pragma unroll
  for (int i = 0; i < 4; ++i) { O1[i] = zero; O2[i] = zero; l1[i] = 0.f; l2[i] = 0.f; }

  u16* p1w = &pls[wave][0][0];
  u16* p2w = &pls[wave][1][0];

  // read-side swizzle constants
  const int xk = (l16 & 7) << 4;
  const int xv = (l16 & 3) << 4;

  // ---- prologue: stage KV block 0 into buf 0 ----
  gl2lds16(k1s, &sk1[0][0] + w512);
  gl2lds16(k2s, &sk2[0][0] + w512);
  gl2lds16(vs, &sv[0][0] + w512);
  __syncthreads();   // compiler emits vmcnt(0) before s_barrier

  int cur = 0;
  for (int kb = 0; kb < 18; ++kb) {
    // stage next KV block into buf cur^1 (async; drained at the barrier)
    if (kb < 17) {
      gl2lds16(k1s + (kb + 1) * 2048, &sk1[cur ^ 1][0] + w512);
      gl2lds16(k2s + (kb + 1) * 2048, &sk2[cur ^ 1][0] + w512);
      gl2lds16(vs + (kb + 1) * 32, &sv[cur ^ 1][0] + w512);
    } else {
      // final block: all K rows clamp to row 576 (masked in the peel)
      gl2lds16(k1 + qkbase + 576 * 64 + kelem, &sk1[cur ^ 1][0] + w512);
      gl2lds16(k2 + qkbase + 576 * 64 + kelem, &sk2[cur ^ 1][0] + w512);
      gl2lds16(vs + 576, &sv[cur ^ 1][0] + w512);
    }

    // LDS -> register fragments (swizzled reads)
    const char* bk1 = (const char*)&sk1[cur][0];
    const char* bk2 = (const char*)&sk2[cur][0];
    const char* bv = (const char*)&sv[cur][0];
    bf16x8 k1f[2][2], k2f[2][2], vf[4];
#pragma unroll
    for (int tt = 0; tt < 2; ++tt) {
      int rb = (tt * 16 + l16) * 128;
      k1f[tt][0] = *(const bf16x8*)(bk1 + rb + ((quad * 16) ^ xk));
      k1f[tt][1] = *(const bf16x8*)(bk1 + rb + ((64 + quad * 16) ^ xk));
      k2f[tt][0] = *(const bf16x8*)(bk2 + rb + ((quad * 16) ^ xk));
      k2f[tt][1] = *(const bf16x8*)(bk2 + rb + ((64 + quad * 16) ^ xk));
    }
#pragma unroll
    for (int tt = 0; tt < 4; ++tt)
      vf[tt] = *(const bf16x8*)(bv + (tt * 16 + l16) * 64 + ((quad * 16) ^ xv));

    f32x4 s1[2], s2[2];
    __builtin_amdgcn_s_setprio(1);
#pragma unroll
    for (int tt = 0; tt < 2; ++tt) {
      s1[tt] = __builtin_amdgcn_mfma_f32_16x16x32_bf16(q1f[0], k1f[tt][0], zero, 0, 0, 0);
      s1[tt] = __builtin_amdgcn_mfma_f32_16x16x32_bf16(q1f[1], k1f[tt][1], s1[tt], 0, 0, 0);
      s2[tt] = __builtin_amdgcn_mfma_f32_16x16x32_bf16(q2f[0], k2f[tt][0], zero, 0, 0, 0);
      s2[tt] = __builtin_amdgcn_mfma_f32_16x16x32_bf16(q2f[1], k2f[tt][1], s2[tt], 0, 0, 0);
    }
    __builtin_amdgcn_s_setprio(0);

    // unmasked exp + partial sums + P staging (kv rows all < 577 here)
#pragma unroll
    for (int i = 0; i < 4; ++i) {
      float p10 = exp2f(s1[0][i] * CEXP);
      float p11 = exp2f(s1[1][i] * CEXP);
      float p20 = exp2f(s2[0][i] * CEXP);
      float p21 = exp2f(s2[1][i] * CEXP);
      l1[i] += p10 + p11;
      l2[i] += p20 + p21;
      // truncating bf16 convert (cheap; ~0.1% bias, well under budget)
      p1w[(quad * 4 + i) * 40 + l16]      = (u16)(__float_as_uint(p10) >> 16);
      p1w[(quad * 4 + i) * 40 + l16 + 16] = (u16)(__float_as_uint(p11) >> 16);
      p2w[(quad * 4 + i) * 40 + l16]      = (u16)(__float_as_uint(p20) >> 16);
      p2w[(quad * 4 + i) * 40 + l16 + 16] = (u16)(__float_as_uint(p21) >> 16);
    }
    bf16x8 p1a = *(const bf16x8*)(p1w + l16 * 40 + quad * 8);
    bf16x8 p2a = *(const bf16x8*)(p2w + l16 * 40 + quad * 8);
    __builtin_amdgcn_s_setprio(1);
#pragma unroll
    for (int tt = 0; tt < 4; ++tt) {
      O1[tt] = __builtin_amdgcn_mfma_f32_16x16x32_bf16(p1a, vf[tt], O1[tt], 0, 0, 0);
      O2[tt] = __builtin_amdgcn_mfma_f32_16x16x32_bf16(p2a, vf[tt], O2[tt], 0, 0, 0);
    }
    __builtin_amdgcn_s_setprio(0);
    __syncthreads();
    cur ^= 1;
  }

  // ---- peeled final block (kv0 = 576): only kv==576 (l16==0, tt==0) valid
  {
    const char* bk1 = (const char*)&sk1[cur][0];
    const char* bk2 = (const char*)&sk2[cur][0];
    const char* bv = (const char*)&sv[cur][0];
    int rb = l16 * 128;
    bf16x8 ka0 = *(const bf16x8*)(bk1 + rb + ((quad * 16) ^ xk));
    bf16x8 ka1 = *(const bf16x8*)(bk1 + rb + ((64 + quad * 16) ^ xk));
    bf16x8 kb0 = *(const bf16x8*)(bk2 + rb + ((quad * 16) ^ xk));
    bf16x8 kb1 = *(const bf16x8*)(bk2 + rb + ((64 + quad * 16) ^ xk));
    f32x4 s1t = __builtin_amdgcn_mfma_f32_16x16x32_bf16(q1f[0], ka0, zero, 0, 0, 0);
    s1t = __builtin_amdgcn_mfma_f32_16x16x32_bf16(q1f[1], ka1, s1t, 0, 0, 0);
    f32x4 s2t = __builtin_amdgcn_mfma_f32_16x16x32_bf16(q2f[0], kb0, zero, 0, 0, 0);
    s2t = __builtin_amdgcn_mfma_f32_16x16x32_bf16(q2f[1], kb1, s2t, 0, 0, 0);
    bf16x8 vf[4];
#pragma unroll
    for (int tt = 0; tt < 4; ++tt)
      vf[tt] = *(const bf16x8*)(bv + (tt * 16 + l16) * 64 + ((quad * 16) ^ xv));
    bool ok = (l16 == 0);
#pragma unroll
    for (int i = 0; i < 4; ++i) {
      float p10 = ok ? exp2f(s1t[i] * CEXP) : 0.f;
      float p20 = ok ? exp2f(s2t[i] * CEXP) : 0.f;
      l1[i] += p10; l2[i] += p20;
      p1w[(quad * 4 + i) * 40 + l16]      = (u16)(__float_as_uint(p10) >> 16);
      p1w[(quad * 4 + i) * 40 + l16 + 16] = 0;
      p2w[(quad * 4 + i) * 40 + l16]      = (u16)(__float_as_uint(p20) >> 16);
      p2w[(quad * 4 + i) * 40 + l16 + 16] = 0;
    }
    bf16x8 p1a = *(const bf16x8*)(p1w + l16 * 40 + quad * 8);
    bf16x8 p2a = *(const bf16x8*)(p2w + l16 * 40 + quad * 8);
#pragma unroll
    for (int tt = 0; tt < 4; ++tt) {
      O1[tt] = __builtin_amdgcn_mfma_f32_16x16x32_bf16(p1a, vf[tt], O1[tt], 0, 0, 0);
      O2[tt] = __builtin_amdgcn_mfma_f32_16x16x32_bf16(p2a, vf[tt], O2[tt], 0, 0, 0);
    }
  }

  // reduce partial row-sums across the quad's 16 lanes
#pragma unroll
  for (int d = 1; d < 16; d <<= 1)
#pragma unroll
    for (int i = 0; i < 4; ++i) {
      l1[i] += __shfl_xor(l1[i], d);
      l2[i] += __shfl_xor(l2[i], d);
    }
  float inv1[4], inv2[4];
#pragma unroll
  for (int i = 0; i < 4; ++i) { inv1[i] = 1.f / l1[i]; inv2[i] = 1.f / l2[i]; }
#pragma unroll
  for (int tt = 0; tt < 4; ++tt) {
    size_t cb = ((size_t)bh * 64 + tt * 16 + l16) * S_LEN;
#pragma unroll
    for (int i = 0; i < 4; ++i) {
      int s = q0 + quad * 4 + i;
      if (s < S_LEN)
        ctx_t[cb + s] = f2bu(O1[tt][i] * inv1[i] - lam * O2[tt][i] * inv2[i]);
    }
  }
}

// ---------------- GroupNorm over (b,h): Dh*S elements, then affine ----------
// ctx_t [B,H,64,S] -> context flat [B][D*S] (== reference's reinterpret trick)
__global__ __launch_bounds__(256) void gnorm(
    const u16* __restrict__ ctx_t, u16* __restrict__ context,
    const float* __restrict__ gw, const float* __restrict__ gb) {
  const int bh = blockIdx.x;
  const int h = bh % 12;
  const int NEL = 64 * S_LEN;          // 36928
  const int NV = NEL / 8;              // 4616
  const u16* src = ctx_t + (size_t)bh * NEL;
  float sum = 0.f, sq = 0.f;
  for (int v = threadIdx.x; v < NV; v += 256) {
    uint4 raw = *(const uint4*)(src + v * 8);
    uint32_t w[4] = {raw.x, raw.y, raw.z, raw.w};
#pragma unroll
    for (int j = 0; j < 4; ++j) {
      float f0 = bu2f((u16)(w[j] & 0xffff));
      float f1 = bu2f((u16)(w[j] >> 16));
      sum += f0 + f1; sq += f0 * f0 + f1 * f1;
    }
  }
#pragma unroll
  for (int d = 1; d < 64; d <<= 1) {
    sum += __shfl_xor(sum, d);
    sq += __shfl_xor(sq, d);
  }
  __shared__ float rs[4], rq[4];
  __shared__ float wv[64], bv2[64];
  int wave = threadIdx.x >> 6;
  if ((threadIdx.x & 63) == 0) { rs[wave] = sum; rq[wave] = sq; }
  __syncthreads();
  float ts = rs[0] + rs[1] + rs[2] + rs[3];
  float tq = rq[0] + rq[1] + rq[2] + rq[3];
  const float Ninv = 1.0f / (float)NEL;
  float mu = ts * Ninv;
  float var = tq * Ninv - mu * mu;
  float rstd = rsqrtf(var + 1e-5f);
  if (threadIdx.x < 64) {
    float w = gw[h * 64 + threadIdx.x] * rstd;
    wv[threadIdx.x] = w;
    bv2[threadIdx.x] = gb[h * 64 + threadIdx.x] - mu * w;
  }
  __syncthreads();
  u16* dst = context + (size_t)bh * NEL;   // b*(768*577) + h*(64*577)
  for (int v = threadIdx.x; v < NV; v += 256) {
    uint4 raw = *(const uint4*)(src + v * 8);
    uint32_t w[4] = {raw.x, raw.y, raw.z, raw.w};
    int base = v * 8;
    int d0 = base / 577;
    int r0 = base - d0 * 577;
    u16 o[8];
#pragma unroll
    for (int j = 0; j < 4; ++j) {
#pragma unroll
      for (int e = 0; e < 2; ++e) {
        int ii = j * 2 + e;
        int dd = (r0 + ii >= 577) ? d0 + 1 : d0;
        float f = bu2f((u16)(e == 0 ? (w[j] & 0xffff) : (w[j] >> 16)));
        o[ii] = f2bu(f * wv[dd] + bv2[dd]);
      }
    }
    *(uint4*)(dst + base) = *(const uint4*)o;
  }
}

extern "C" void kernel_launch(void* const* d_in, const int* in_sizes, int n_in,
                              void* d_out, int out_size, void* d_ws, size_t ws_size,
                              hipStream_t stream) {
  const float* x   = (const float*)d_in[0];
  const float* Wq  = (const float*)d_in[1];
  const float* bq  = (const float*)d_in[2];
  const float* Wk  = (const float*)d_in[3];
  const float* bk  = (const float*)d_in[4];
  const float* Wv  = (const float*)d_in[5];
  const float* bv  = (const float*)d_in[6];
  const float* Wo  = (const float*)d_in[7];
  const float* bo  = (const float*)d_in[8];
  const float* lam = (const float*)d_in[9];
  const float* gw  = (const float*)d_in[10];
  const float* gb  = (const float*)d_in[11];
  float* out = (float*)d_out;

  char* p = (char*)d_ws;
  auto alloc = [&](size_t bytes) {
    char* r = p;
    p += (bytes + 255) & ~(size_t)255;
    return r;
  };
  u16* xb     = (u16*)alloc((size_t)M_PAD * 768 * 2);   // also reused as ctxbuf
  u16* wtqkv  = (u16*)alloc((size_t)3840 * 768 * 2);
  u16* wot    = (u16*)alloc((size_t)768 * 768 * 2);
  u16* q1b    = (u16*)alloc((size_t)192 * 577 * 64 * 2);
  u16* q2b    = (u16*)alloc((size_t)192 * 577 * 64 * 2);
  u16* k1b    = (u16*)alloc((size_t)192 * 577 * 64 * 2);
  u16* k2b    = (u16*)alloc((size_t)192 * 577 * 64 * 2);
  u16* vtb    = (u16*)alloc((size_t)192 * 64 * VT_STRIDE * 2);
  u16* ctxt   = (u16*)alloc((size_t)192 * 64 * S_LEN * 2);
  u16* ctxbuf = xb;   // alias: xb is dead after the QKV GEMM; keeps ws ~108 MB

  prep_x<<<(M_PAD * 768 / 8 + 255) / 256, 256, 0, stream>>>(x, xb);
  prep_w<<<3456, 256, 0, stream>>>(Wq, Wk, Wv, Wo, wtqkv, wot);

  gemm_bf16<<<dim3(73, 30), 256, 0, stream>>>(xb, wtqkv, 3840, 1,
      nullptr, nullptr, q1b, q2b, k1b, k2b, vtb, bq, bk, bv);

  attn<<<dim3(1920), 256, 0, stream>>>(q1b, q2b, k1b, k2b, vtb, ctxt, lam);

  gnorm<<<192, 256, 0, stream>>>(ctxt, ctxbuf, gw, gb);

  gemm_bf16<<<dim3(73, 6), 256, 0, stream>>>(ctxbuf, wot, 768, 0,
      out, bo, nullptr, nullptr, nullptr, nullptr, nullptr, nullptr, nullptr, nullptr);
}

// Round 6
// 311.952 us; speedup vs baseline: 1.7266x; 1.0554x over previous
//
#include <hip/hip_runtime.h>
#include <hip/hip_bf16.h>
#include <stdint.h>

typedef unsigned short u16;
typedef __attribute__((ext_vector_type(8))) short bf16x8;
typedef __attribute__((ext_vector_type(4))) float f32x4;

#define S_LEN 577
#define DMODEL 768
#define NHEAD 12
#define DH 64
#define BATCH 16
#define M_ROWS (BATCH * S_LEN)   /* 9232 */
#define M_PAD 9344               /* 73 * 128 */
#define VT_STRIDE 640            /* padded S so 16B frag loads stay aligned */

__device__ __forceinline__ u16 f2bu(float f) {
  uint32_t u = __float_as_uint(f);
  u += 0x7FFFu + ((u >> 16) & 1u);      // RNE; inputs are finite
  return (u16)(u >> 16);
}
__device__ __forceinline__ float bu2f(u16 b) {
  return __uint_as_float(((uint32_t)b) << 16);
}
// async global->LDS, 16B per lane; LDS dest = wave-uniform base + lane*16
__device__ __forceinline__ void gl2lds16(const u16* g, u16* l) {
  __builtin_amdgcn_global_load_lds(
      (const __attribute__((address_space(1))) unsigned int*)g,
      (__attribute__((address_space(3))) unsigned int*)l, 16, 0, 0);
}

// ---------------- prep: x fp32 -> bf16 [M_PAD,768], pad rows zeroed ----------
__global__ __launch_bounds__(256) void prep_x(const float* __restrict__ x,
                                              u16* __restrict__ xb) {
  int e = (blockIdx.x * 256 + threadIdx.x) * 8;
  u16 o[8];
  if (e < M_ROWS * DMODEL) {
    float4 f0 = *(const float4*)(x + e);
    float4 f1 = *(const float4*)(x + e + 4);
    o[0] = f2bu(f0.x); o[1] = f2bu(f0.y); o[2] = f2bu(f0.z); o[3] = f2bu(f0.w);
    o[4] = f2bu(f1.x); o[5] = f2bu(f1.y); o[6] = f2bu(f1.z); o[7] = f2bu(f1.w);
  } else {
#pragma unroll
    for (int i = 0; i < 8; ++i) o[i] = 0;
  }
  *(uint4*)(xb + e) = *(const uint4*)o;
}

// ------------- prep: weights fp32 [K,N] -> bf16 transposed [N,K], tiled ------
// wtqkv rows: [0,1536)=Wq^T, [1536,3072)=Wk^T, [3072,3840)=Wv^T ; wot = Wo^T
__global__ __launch_bounds__(256) void prep_w(
    const float* __restrict__ Wq, const float* __restrict__ Wk,
    const float* __restrict__ Wv, const float* __restrict__ Wo,
    u16* __restrict__ wtqkv, u16* __restrict__ wot) {
  __shared__ u16 tile[32][33];
  int blk = blockIdx.x;
  const float* W; int N; u16* dst; int rowbase;
  if (blk < 1152)      { W = Wq; N = 1536; dst = wtqkv; rowbase = 0; }
  else if (blk < 2304) { W = Wk; N = 1536; dst = wtqkv; rowbase = 1536; blk -= 1152; }
  else if (blk < 2880) { W = Wv; N = 768;  dst = wtqkv; rowbase = 3072; blk -= 2304; }
  else                 { W = Wo; N = 768;  dst = wot;   rowbase = 0;    blk -= 2880; }
  const int ntiles = N >> 5;
  const int tk = blk / ntiles, tn = blk - tk * ntiles;
  const int c = threadIdx.x & 31, r0 = threadIdx.x >> 5;
#pragma unroll
  for (int i = 0; i < 4; ++i) {
    int r = i * 8 + r0;
    tile[r][c] = f2bu(W[(size_t)(tk * 32 + r) * N + tn * 32 + c]);
  }
  __syncthreads();
#pragma unroll
  for (int i = 0; i < 4; ++i) {
    int r = i * 8 + r0;
    dst[(size_t)(rowbase + tn * 32 + r) * 768 + tk * 32 + c] = tile[c][r];
  }
}

// ---------------- bf16 MFMA GEMM: C[M,N] = A[M,768] * Bt[N,768]^T ------------
// m97 structure: global_load_lds width-16 staging into unpadded 128x32 tiles.
// mode 0: out fp32 [M_ROWS,N] + biasO[n]  (output projection)
// mode 1: LDS-staged coalesced scatter (R9) -> q1/q2/k1/k2 + vt.
// R10: locality-aware bijective block swizzle (T1 + nt-chunking). Dispatch
// order made each XCD's L2 thrash A/B tiles (FETCH 218MB vs 20MB unique,
// 2.9 TB/s L2-miss path = the limiter). New decode: each XCD owns a
// contiguous slot range; slots enumerate (chunk of C n-tiles) x (all
// m-tiles), so one A tile is fetched once per XCD and shared by the chunk's
// C adjacent blocks, while the B chunk-panel (~1MB) stays L2-resident.
__global__ __launch_bounds__(256, 2) void gemm_bf16(
    const u16* __restrict__ A, const u16* __restrict__ Bt, int N, int mode,
    float* __restrict__ outF, const float* __restrict__ biasO,
    u16* __restrict__ q1p, u16* __restrict__ q2p,
    u16* __restrict__ k1p, u16* __restrict__ k2p, u16* __restrict__ vtp,
    const float* __restrict__ bq, const float* __restrict__ bk,
    const float* __restrict__ bvp) {
  __shared__ __align__(16) u16 smem[8192];   // lA(4096) + lB(4096); epilogue tile
  u16* lA = smem;
  u16* lB = smem + 4096;
  const int t = threadIdx.x;
  const int lane = t & 63, wave = t >> 6;
  const int quad = lane >> 4, l16 = lane & 15;
  const int wm = wave & 1, wn = wave >> 1;

  // ---- XCD-locality swizzle (bijective; perf-only) ----
  const int NTg = gridDim.y;
  const int nwg = 73 * NTg;
  const int lin = blockIdx.y * 73 + blockIdx.x;   // dispatch-linear (x fastest)
  const int xcd8 = lin & 7;
  const int idx8 = lin >> 3;
  const int qq = nwg >> 3, rr = nwg & 7;
  const int slot = (xcd8 < rr) ? xcd8 * (qq + 1) + idx8
                               : rr * (qq + 1) + (xcd8 - rr) * qq + idx8;
  const int C = (NTg >= 10) ? 5 : NTg;   // 30 -> 6 chunks of 5; 6 -> 1 chunk
  const int bpc = 73 * C;
  const int chunk = slot / bpc;
  const int rem = slot - chunk * bpc;
  const int mt = rem / C;
  const int nt = chunk * C + (rem - mt * C);
  const int m0 = mt * 128;
  const int n0 = nt * 128;

  f32x4 zero = {0.f, 0.f, 0.f, 0.f};
  f32x4 acc[4][4];
  for (int i = 0; i < 4; ++i) for (int j = 0; j < 4; ++j) acc[i][j] = zero;

  // staging: wave w owns rows w*32..w*32+31 (2 chunks of 16 rows);
  // lane -> row base + lane/4, col (lane%4)*8  (LDS offset == lane*16 B)
  const int srow = wave * 32 + (lane >> 2);
  const int scol = (lane & 3) * 8;
  const u16* gA = A + (size_t)(m0 + srow) * 768 + scol;
  const u16* gB = Bt + (size_t)(n0 + srow) * 768 + scol;
  u16* sA = lA + wave * 1024;   // wave-uniform LDS base
  u16* sB = lB + wave * 1024;

  for (int k0 = 0; k0 < 768; k0 += 32) {
    gl2lds16(gA + k0, sA);
    gl2lds16(gA + k0 + 16 * 768, sA + 512);
    gl2lds16(gB + k0, sB);
    gl2lds16(gB + k0 + 16 * 768, sB + 512);
    __syncthreads();
    bf16x8 af[4], bfr[4];
#pragma unroll
    for (int i = 0; i < 4; ++i)
      af[i] = *(const bf16x8*)(lA + (wm * 64 + i * 16 + l16) * 32 + quad * 8);
#pragma unroll
    for (int j = 0; j < 4; ++j)
      bfr[j] = *(const bf16x8*)(lB + (wn * 64 + j * 16 + l16) * 32 + quad * 8);
#pragma unroll
    for (int i = 0; i < 4; ++i)
#pragma unroll
      for (int j = 0; j < 4; ++j)
        acc[i][j] = __builtin_amdgcn_mfma_f32_16x16x32_bf16(af[i], bfr[j], acc[i][j], 0, 0, 0);
    __syncthreads();
  }

  if (mode == 0) {
#pragma unroll
    for (int i = 0; i < 4; ++i) {
#pragma unroll
      for (int j = 0; j < 4; ++j) {
        int n = n0 + wn * 64 + j * 16 + l16;
#pragma unroll
        for (int r = 0; r < 4; ++r) {
          int m = m0 + wm * 64 + i * 16 + quad * 4 + r;
          if (m >= M_ROWS) continue;
          outF[(size_t)m * N + n] = acc[i][j][r] + biasO[n];
        }
      }
    }
    return;
  }

  // ---------------- mode 1 epilogue: LDS-staged coalesced writes ------------
  u16* tile = smem;   // 8192 u16 = 16 KB, staging data is dead now
  const bool isv = (n0 >= 3072);
  u16* dstqk = nullptr; const float* biasp = nullptr; int ch0 = 0;
  if (!isv) {
    if (n0 < 768)       { dstqk = q1p; biasp = bq + n0;          ch0 = n0; }
    else if (n0 < 1536) { dstqk = q2p; biasp = bq + n0;          ch0 = n0 - 768; }
    else if (n0 < 2304) { dstqk = k1p; biasp = bk + (n0 - 1536); ch0 = n0 - 1536; }
    else                { dstqk = k2p; biasp = bk + (n0 - 1536); ch0 = n0 - 2304; }
  }
  const int ch0v = n0 - 3072;

#pragma unroll
  for (int hf = 0; hf < 2; ++hf) {
    __syncthreads();
    if (wn == hf) {
      if (!isv) {
        // tile[m 0..127][col 0..63] (d-major lines), chunk-XOR swizzle by m&3
        float bfv[4];
#pragma unroll
        for (int j = 0; j < 4; ++j) bfv[j] = biasp[hf * 64 + j * 16 + l16];
#pragma unroll
        for (int i = 0; i < 4; ++i)
#pragma unroll
          for (int j = 0; j < 4; ++j) {
            int col = j * 16 + l16;
#pragma unroll
            for (int r = 0; r < 4; ++r) {
              int m = wm * 64 + i * 16 + quad * 4 + r;
              int addr = m * 64 + (col & 15) + ((((col >> 4) ^ (m & 3)) & 3) << 4);
              tile[addr] = f2bu(acc[i][j][r] + bfv[j]);
            }
          }
      } else {
        // transposed: tile[d 0..63][s 0..127], chunk-XOR swizzle by d&7
        float bfv[4];
#pragma unroll
        for (int j = 0; j < 4; ++j) bfv[j] = bvp[ch0v + hf * 64 + j * 16 + l16];
#pragma unroll
        for (int i = 0; i < 4; ++i)
#pragma unroll
          for (int j = 0; j < 4; ++j) {
            int d = j * 16 + l16;
#pragma unroll
            for (int r = 0; r < 4; ++r) {
              int m = wm * 64 + i * 16 + quad * 4 + r;   // s within tile
              int addr = d * 128 + (m & 15) + ((((m >> 4) ^ (d & 7)) & 7) << 4);
              tile[addr] = f2bu(acc[i][j][r] + bfv[j]);
            }
          }
      }
    }
    __syncthreads();

    if (!isv) {
      // 128 lines of 128B: line = m (one s, one head); 8 threads x uint4 each
      const int line = t >> 3;
      const int col0 = (t & 7) * 8;
      const int head = (ch0 >> 6) + hf;
#pragma unroll
      for (int p = 0; p < 4; ++p) {
        int m = p * 32 + line;
        int mg = m0 + m;
        if (mg < M_ROWS) {
          int addr = m * 64 + (col0 & 15) + ((((col0 >> 4) ^ (m & 3)) & 3) << 4);
          uint4 v4 = *(const uint4*)(tile + addr);
          int b = mg / 577;
          int s = mg - b * 577;
          *(uint4*)(dstqk + (((size_t)(b * 12 + head) * 577 + s) * 64 + col0)) = v4;
        }
      }
    } else {
      // 64 lines of 256B: line = d; 16 threads x uint4 each (s-contiguous)
      const int line = t >> 4;
      const int col0 = (t & 15) * 8;
      const int hh = (ch0v >> 6) + hf;
#pragma unroll
      for (int p = 0; p < 4; ++p) {
        int d = p * 16 + line;
        int addr = d * 128 + (col0 & 15) + ((((col0 >> 4) ^ (d & 7)) & 7) << 4);
        uint4 v4 = *(const uint4*)(tile + addr);
        int sg0 = m0 + col0;
        int b0 = sg0 / 577, b7 = (sg0 + 7) / 577;
        if (sg0 + 7 < M_ROWS && b0 == b7) {
          *(uint4*)(vtp + (((size_t)(b0 * 12 + hh) * 64 + d) * VT_STRIDE + (sg0 - b0 * 577))) = v4;
        } else {
          const u16* ev = (const u16*)&v4;
          for (int e = 0; e < 8; ++e) {
            int sg = sg0 + e;
            if (sg >= M_ROWS) break;
            int bb = sg / 577;
            vtp[((size_t)(bb * 12 + hh) * 64 + d) * VT_STRIDE + (sg - bb * 577)] = ev[e];
          }
        }
      }
    }
  }
}

// ---------------- flash-style differential attention (no-max softmax) --------
// R8: shared-LDS KV staging (T3-lite 2-phase template). 4 waves per block
// share one bh; K1/K2/V KV-block tiles staged once into double-buffered LDS
// via global_load_lds (per-wave global loads 12 -> 3/4 each iter; block
// request volume /4). Next block staged while current computes; the
// compiler's vmcnt(0)-before-barrier drains it. K tiles XOR-swizzled on the
// SOURCE address (rule 21) so stride-128B ds_read_b128 is conflict-free;
// V uses a 4-slot swizzle. Tail masking peeled (18 unmasked + 1 masked).
// Per-wave compute pipeline identical to the R5 kernel (known-good).
__global__ __launch_bounds__(256, 4) void attn(
    const u16* __restrict__ q1, const u16* __restrict__ q2,
    const u16* __restrict__ k1, const u16* __restrict__ k2,
    const u16* __restrict__ vt, u16* __restrict__ ctx_t,
    const float* __restrict__ lam_p) {
  __shared__ u16 sk1[2][2048];      // [buf][32 kv rows][64], rows 128B, swizzled
  __shared__ u16 sk2[2][2048];
  __shared__ u16 sv[2][2048];       // [buf][64 d rows][32 kv], rows 64B, swizzled
  __shared__ u16 pls[4][2][16 * 40];// per-wave P staging (D-layout -> A-layout)

  const int tid = threadIdx.x;
  const int wave = tid >> 6;
  const int lane = tid & 63;
  const int quad = lane >> 4, l16 = lane & 15;

  // XCD-locality decode: 1920 blocks = 8 xcd * (24 bh * 10 qgroups), bh-major
  const int bid = blockIdx.x;
  const int xcd = bid & 7;
  const int slot = bid >> 3;            // 0..239
  const int bhl = slot / 10;
  const int qgroup = slot - bhl * 10;
  const int bh = xcd * 24 + bhl;
  const int q0 = (qgroup * 4 + wave) * 16;   // may exceed 576 (idle-ish wave)

  const float lam = lam_p[0];
  const float CEXP = 0.125f * 1.44269504f;   // scale * log2(e), folded
  const size_t qkbase = (size_t)bh * S_LEN * DH;
  const size_t vbase = (size_t)bh * 64 * VT_STRIDE;

  // ---- staging geometry (per thread, constant) ----
  // K tile: 32 rows x 128B; thread -> row tid/8, 16B slot tid%8; source col
  // pre-swizzled so LDS[row][cb] = G[row][cb ^ ((row&7)<<4)]
  const int krow = tid >> 3;
  const int kelem = ((((tid & 7) << 4) ^ ((krow & 7) << 4)) >> 1); // 0..56
  const u16* k1s = k1 + qkbase + (size_t)krow * 64 + kelem;
  const u16* k2s = k2 + qkbase + (size_t)krow * 64 + kelem;
  // V tile: 64 rows x 64B; thread -> row tid/4, slot tid%4;
  // LDS[row][cb] = G[row][cb ^ ((row&3)<<4)]
  const int vrow = tid >> 2;
  const int vel = ((((tid & 3) << 4) ^ ((vrow & 3) << 4)) >> 1);   // 0,8,16,24
  const u16* vs = vt + vbase + (size_t)vrow * VT_STRIDE + vel;
  const int w512 = wave * 512;   // per-wave LDS chunk (1024 B) for staging

  // ---- q fragments (registers, whole kernel) ----
  int qr = q0 + l16; if (qr > 576) qr = 576;   // clamp tail (results discarded)
  bf16x8 q1f[2], q2f[2];
#pragma unroll
  for (int c = 0; c < 2; ++c) {
    q1f[c] = *(const bf16x8*)(q1 + qkbase + (size_t)qr * 64 + c * 32 + quad * 8);
    q2f[c] = *(const bf16x8*)(q2 + qkbase + (size_t)qr * 64 + c * 32 + quad * 8);
  }

  f32x4 zero = {0.f, 0.f, 0.f, 0.f};
  f32x4 O1[4], O2[4];
  float l1[4], l2[4];
#pragma unroll
  for (int i = 0; i < 4; ++i) { O1[i] = zero; O2[i] = zero; l1[i] = 0.f; l2[i] = 0.f; }

  u16* p1w = &pls[wave][0][0];
  u16* p2w = &pls[wave][1][0];

  // read-side swizzle constants
  const int xk = (l16 & 7) << 4;
  const int xv = (l16 & 3) << 4;

  // ---- prologue: stage KV block 0 into buf 0 ----
  gl2lds16(k1s, &sk1[0][0] + w512);
  gl2lds16(k2s, &sk2[0][0] + w512);
  gl2lds16(vs, &sv[0][0] + w512);
  __syncthreads();   // compiler emits vmcnt(0) before s_barrier

  int cur = 0;
  for (int kb = 0; kb < 18; ++kb) {
    // stage next KV block into buf cur^1 (async; drained at the barrier)
    if (kb < 17) {
      gl2lds16(k1s + (kb + 1) * 2048, &sk1[cur ^ 1][0] + w512);
      gl2lds16(k2s + (kb + 1) * 2048, &sk2[cur ^ 1][0] + w512);
      gl2lds16(vs + (kb + 1) * 32, &sv[cur ^ 1][0] + w512);
    } else {
      // final block: all K rows clamp to row 576 (masked in the peel)
      gl2lds16(k1 + qkbase + 576 * 64 + kelem, &sk1[cur ^ 1][0] + w512);
      gl2lds16(k2 + qkbase + 576 * 64 + kelem, &sk2[cur ^ 1][0] + w512);
      gl2lds16(vs + 576, &sv[cur ^ 1][0] + w512);
    }

    // LDS -> register fragments (swizzled reads)
    const char* bk1 = (const char*)&sk1[cur][0];
    const char* bk2 = (const char*)&sk2[cur][0];
    const char* bv = (const char*)&sv[cur][0];
    bf16x8 k1f[2][2], k2f[2][2], vf[4];
#pragma unroll
    for (int tt = 0; tt < 2; ++tt) {
      int rb = (tt * 16 + l16) * 128;
      k1f[tt][0] = *(const bf16x8*)(bk1 + rb + ((quad * 16) ^ xk));
      k1f[tt][1] = *(const bf16x8*)(bk1 + rb + ((64 + quad * 16) ^ xk));
      k2f[tt][0] = *(const bf16x8*)(bk2 + rb + ((quad * 16) ^ xk));
      k2f[tt][1] = *(const bf16x8*)(bk2 + rb + ((64 + quad * 16) ^ xk));
    }
#pragma unroll
    for (int tt = 0; tt < 4; ++tt)
      vf[tt] = *(const bf16x8*)(bv + (tt * 16 + l16) * 64 + ((quad * 16) ^ xv));

    f32x4 s1[2], s2[2];
    __builtin_amdgcn_s_setprio(1);
#pragma unroll
    for (int tt = 0; tt < 2; ++tt) {
      s1[tt] = __builtin_amdgcn_mfma_f32_16x16x32_bf16(q1f[0], k1f[tt][0], zero, 0, 0, 0);
      s1[tt] = __builtin_amdgcn_mfma_f32_16x16x32_bf16(q1f[1], k1f[tt][1], s1[tt], 0, 0, 0);
      s2[tt] = __builtin_amdgcn_mfma_f32_16x16x32_bf16(q2f[0], k2f[tt][0], zero, 0, 0, 0);
      s2[tt] = __builtin_amdgcn_mfma_f32_16x16x32_bf16(q2f[1], k2f[tt][1], s2[tt], 0, 0, 0);
    }
    __builtin_amdgcn_s_setprio(0);

    // unmasked exp + partial sums + P staging (kv rows all < 577 here)
#pragma unroll
    for (int i = 0; i < 4; ++i) {
      float p10 = exp2f(s1[0][i] * CEXP);
      float p11 = exp2f(s1[1][i] * CEXP);
      float p20 = exp2f(s2[0][i] * CEXP);
      float p21 = exp2f(s2[1][i] * CEXP);
      l1[i] += p10 + p11;
      l2[i] += p20 + p21;
      // truncating bf16 convert (cheap; ~0.1% bias, well under budget)
      p1w[(quad * 4 + i) * 40 + l16]      = (u16)(__float_as_uint(p10) >> 16);
      p1w[(quad * 4 + i) * 40 + l16 + 16] = (u16)(__float_as_uint(p11) >> 16);
      p2w[(quad * 4 + i) * 40 + l16]      = (u16)(__float_as_uint(p20) >> 16);
      p2w[(quad * 4 + i) * 40 + l16 + 16] = (u16)(__float_as_uint(p21) >> 16);
    }
    bf16x8 p1a = *(const bf16x8*)(p1w + l16 * 40 + quad * 8);
    bf16x8 p2a = *(const bf16x8*)(p2w + l16 * 40 + quad * 8);
    __builtin_amdgcn_s_setprio(1);
#pragma unroll
    for (int tt = 0; tt < 4; ++tt) {
      O1[tt] = __builtin_amdgcn_mfma_f32_16x16x32_bf16(p1a, vf[tt], O1[tt], 0, 0, 0);
      O2[tt] = __builtin_amdgcn_mfma_f32_16x16x32_bf16(p2a, vf[tt], O2[tt], 0, 0, 0);
    }
    __builtin_amdgcn_s_setprio(0);
    __syncthreads();
    cur ^= 1;
  }

  // ---- peeled final block (kv0 = 576): only kv==576 (l16==0, tt==0) valid
  {
    const char* bk1 = (const char*)&sk1[cur][0];
    const char* bk2 = (const char*)&sk2[cur][0];
    const char* bv = (const char*)&sv[cur][0];
    int rb = l16 * 128;
    bf16x8 ka0 = *(const bf16x8*)(bk1 + rb + ((quad * 16) ^ xk));
    bf16x8 ka1 = *(const bf16x8*)(bk1 + rb + ((64 + quad * 16) ^ xk));
    bf16x8 kb0 = *(const bf16x8*)(bk2 + rb + ((quad * 16) ^ xk));
    bf16x8 kb1 = *(const bf16x8*)(bk2 + rb + ((64 + quad * 16) ^ xk));
    f32x4 s1t = __builtin_amdgcn_mfma_f32_16x16x32_bf16(q1f[0], ka0, zero, 0, 0, 0);
    s1t = __builtin_amdgcn_mfma_f32_16x16x32_bf16(q1f[1], ka1, s1t, 0, 0, 0);
    f32x4 s2t = __builtin_amdgcn_mfma_f32_16x16x32_bf16(q2f[0], kb0, zero, 0, 0, 0);
    s2t = __builtin_amdgcn_mfma_f32_16x16x32_bf16(q2f[1], kb1, s2t, 0, 0, 0);
    bf16x8 vf[4];
#pragma unroll
    for (int tt = 0; tt < 4; ++tt)
      vf[tt] = *(const bf16x8*)(bv + (tt * 16 + l16) * 64 + ((quad * 16) ^ xv));
    bool ok = (l16 == 0);
#pragma unroll
    for (int i = 0; i < 4; ++i) {
      float p10 = ok ? exp2f(s1t[i] * CEXP) : 0.f;
      float p20 = ok ? exp2f(s2t[i] * CEXP) : 0.f;
      l1[i] += p10; l2[i] += p20;
      p1w[(quad * 4 + i) * 40 + l16]      = (u16)(__float_as_uint(p10) >> 16);
      p1w[(quad * 4 + i) * 40 + l16 + 16] = 0;
      p2w[(quad * 4 + i) * 40 + l16]      = (u16)(__float_as_uint(p20) >> 16);
      p2w[(quad * 4 + i) * 40 + l16 + 16] = 0;
    }
    bf16x8 p1a = *(const bf16x8*)(p1w + l16 * 40 + quad * 8);
    bf16x8 p2a = *(const bf16x8*)(p2w + l16 * 40 + quad * 8);
#pragma unroll
    for (int tt = 0; tt < 4; ++tt) {
      O1[tt] = __builtin_amdgcn_mfma_f32_16x16x32_bf16(p1a, vf[tt], O1[tt], 0, 0, 0);
      O2[tt] = __builtin_amdgcn_mfma_f32_16x16x32_bf16(p2a, vf[tt], O2[tt], 0, 0, 0);
    }
  }

  // reduce partial row-sums across the quad's 16 lanes
#pragma unroll
  for (int d = 1; d < 16; d <<= 1)
#pragma unroll
    for (int i = 0; i < 4; ++i) {
      l1[i] += __shfl_xor(l1[i], d);
      l2[i] += __shfl_xor(l2[i], d);
    }
  float inv1[4], inv2[4];
#pragma unroll
  for (int i = 0; i < 4; ++i) { inv1[i] = 1.f / l1[i]; inv2[i] = 1.f / l2[i]; }
#pragma unroll
  for (int tt = 0; tt < 4; ++tt) {
    size_t cb = ((size_t)bh * 64 + tt * 16 + l16) * S_LEN;
#pragma unroll
    for (int i = 0; i < 4; ++i) {
      int s = q0 + quad * 4 + i;
      if (s < S_LEN)
        ctx_t[cb + s] = f2bu(O1[tt][i] * inv1[i] - lam * O2[tt][i] * inv2[i]);
    }
  }
}

// ---------------- GroupNorm over (b,h): Dh*S elements, then affine ----------
// ctx_t [B,H,64,S] -> context flat [B][D*S] (== reference's reinterpret trick)
__global__ __launch_bounds__(256) void gnorm(
    const u16* __restrict__ ctx_t, u16* __restrict__ context,
    const float* __restrict__ gw, const float* __restrict__ gb) {
  const int bh = blockIdx.x;
  const int h = bh % 12;
  const int NEL = 64 * S_LEN;          // 36928
  const int NV = NEL / 8;              // 4616
  const u16* src = ctx_t + (size_t)bh * NEL;
  float sum = 0.f, sq = 0.f;
  for (int v = threadIdx.x; v < NV; v += 256) {
    uint4 raw = *(const uint4*)(src + v * 8);
    uint32_t w[4] = {raw.x, raw.y, raw.z, raw.w};
#pragma unroll
    for (int j = 0; j < 4; ++j) {
      float f0 = bu2f((u16)(w[j] & 0xffff));
      float f1 = bu2f((u16)(w[j] >> 16));
      sum += f0 + f1; sq += f0 * f0 + f1 * f1;
    }
  }
#pragma unroll
  for (int d = 1; d < 64; d <<= 1) {
    sum += __shfl_xor(sum, d);
    sq += __shfl_xor(sq, d);
  }
  __shared__ float rs[4], rq[4];
  __shared__ float wv[64], bv2[64];
  int wave = threadIdx.x >> 6;
  if ((threadIdx.x & 63) == 0) { rs[wave] = sum; rq[wave] = sq; }
  __syncthreads();
  float ts = rs[0] + rs[1] + rs[2] + rs[3];
  float tq = rq[0] + rq[1] + rq[2] + rq[3];
  const float Ninv = 1.0f / (float)NEL;
  float mu = ts * Ninv;
  float var = tq * Ninv - mu * mu;
  float rstd = rsqrtf(var + 1e-5f);
  if (threadIdx.x < 64) {
    float w = gw[h * 64 + threadIdx.x] * rstd;
    wv[threadIdx.x] = w;
    bv2[threadIdx.x] = gb[h * 64 + threadIdx.x] - mu * w;
  }
  __syncthreads();
  u16* dst = context + (size_t)bh * NEL;   // b*(768*577) + h*(64*577)
  for (int v = threadIdx.x; v < NV; v += 256) {
    uint4 raw = *(const uint4*)(src + v * 8);
    uint32_t w[4] = {raw.x, raw.y, raw.z, raw.w};
    int base = v * 8;
    int d0 = base / 577;
    int r0 = base - d0 * 577;
    u16 o[8];
#pragma unroll
    for (int j = 0; j < 4; ++j) {
#pragma unroll
      for (int e = 0; e < 2; ++e) {
        int ii = j * 2 + e;
        int dd = (r0 + ii >= 577) ? d0 + 1 : d0;
        float f = bu2f((u16)(e == 0 ? (w[j] & 0xffff) : (w[j] >> 16)));
        o[ii] = f2bu(f * wv[dd] + bv2[dd]);
      }
    }
    *(uint4*)(dst + base) = *(const uint4*)o;
  }
}

extern "C" void kernel_launch(void* const* d_in, const int* in_sizes, int n_in,
                              void* d_out, int out_size, void* d_ws, size_t ws_size,
                              hipStream_t stream) {
  const float* x   = (const float*)d_in[0];
  const float* Wq  = (const float*)d_in[1];
  const float* bq  = (const float*)d_in[2];
  const float* Wk  = (const float*)d_in[3];
  const float* bk  = (const float*)d_in[4];
  const float* Wv  = (const float*)d_in[5];
  const float* bv  = (const float*)d_in[6];
  const float* Wo  = (const float*)d_in[7];
  const float* bo  = (const float*)d_in[8];
  const float* lam = (const float*)d_in[9];
  const float* gw  = (const float*)d_in[10];
  const float* gb  = (const float*)d_in[11];
  float* out = (float*)d_out;

  char* p = (char*)d_ws;
  auto alloc = [&](size_t bytes) {
    char* r = p;
    p += (bytes + 255) & ~(size_t)255;
    return r;
  };
  u16* xb     = (u16*)alloc((size_t)M_PAD * 768 * 2);   // also reused as ctxbuf
  u16* wtqkv  = (u16*)alloc((size_t)3840 * 768 * 2);
  u16* wot    = (u16*)alloc((size_t)768 * 768 * 2);
  u16* q1b    = (u16*)alloc((size_t)192 * 577 * 64 * 2);
  u16* q2b    = (u16*)alloc((size_t)192 * 577 * 64 * 2);
  u16* k1b    = (u16*)alloc((size_t)192 * 577 * 64 * 2);
  u16* k2b    = (u16*)alloc((size_t)192 * 577 * 64 * 2);
  u16* vtb    = (u16*)alloc((size_t)192 * 64 * VT_STRIDE * 2);
  u16* ctxt   = (u16*)alloc((size_t)192 * 64 * S_LEN * 2);
  u16* ctxbuf = xb;   // alias: xb is dead after the QKV GEMM; keeps ws ~108 MB

  prep_x<<<(M_PAD * 768 / 8 + 255) / 256, 256, 0, stream>>>(x, xb);
  prep_w<<<3456, 256, 0, stream>>>(Wq, Wk, Wv, Wo, wtqkv, wot);

  gemm_bf16<<<dim3(73, 30), 256, 0, stream>>>(xb, wtqkv, 3840, 1,
      nullptr, nullptr, q1b, q2b, k1b, k2b, vtb, bq, bk, bv);

  attn<<<dim3(1920), 256, 0, stream>>>(q1b, q2b, k1b, k2b, vtb, ctxt, lam);

  gnorm<<<192, 256, 0, stream>>>(ctxt, ctxbuf, gw, gb);

  gemm_bf16<<<dim3(73, 6), 256, 0, stream>>>(ctxbuf, wot, 768, 0,
      out, bo, nullptr, nullptr, nullptr, nullptr, nullptr, nullptr, nullptr, nullptr);
}

// Round 7
// 305.967 us; speedup vs baseline: 1.7604x; 1.0196x over previous
//
#include <hip/hip_runtime.h>
#include <hip/hip_bf16.h>
#include <stdint.h>

typedef unsigned short u16;
typedef __attribute__((ext_vector_type(8))) short bf16x8;
typedef __attribute__((ext_vector_type(4))) float f32x4;

#define S_LEN 577
#define DMODEL 768
#define NHEAD 12
#define DH 64
#define BATCH 16
#define M_ROWS (BATCH * S_LEN)   /* 9232 */
#define M_PAD 9344               /* 73 * 128 */
#define VT_STRIDE 640            /* padded S so 16B frag loads stay aligned */

__device__ __forceinline__ u16 f2bu(float f) {
  uint32_t u = __float_as_uint(f);
  u += 0x7FFFu + ((u >> 16) & 1u);      // RNE; inputs are finite
  return (u16)(u >> 16);
}
__device__ __forceinline__ float bu2f(u16 b) {
  return __uint_as_float(((uint32_t)b) << 16);
}
// async global->LDS, 16B per lane; LDS dest = wave-uniform base + lane*16
__device__ __forceinline__ void gl2lds16(const u16* g, u16* l) {
  __builtin_amdgcn_global_load_lds(
      (const __attribute__((address_space(1))) unsigned int*)g,
      (__attribute__((address_space(3))) unsigned int*)l, 16, 0, 0);
}

// ---------------- prep: x fp32 -> bf16 [M_PAD,768], pad rows zeroed ----------
__global__ __launch_bounds__(256) void prep_x(const float* __restrict__ x,
                                              u16* __restrict__ xb) {
  int e = (blockIdx.x * 256 + threadIdx.x) * 8;
  u16 o[8];
  if (e < M_ROWS * DMODEL) {
    float4 f0 = *(const float4*)(x + e);
    float4 f1 = *(const float4*)(x + e + 4);
    o[0] = f2bu(f0.x); o[1] = f2bu(f0.y); o[2] = f2bu(f0.z); o[3] = f2bu(f0.w);
    o[4] = f2bu(f1.x); o[5] = f2bu(f1.y); o[6] = f2bu(f1.z); o[7] = f2bu(f1.w);
  } else {
#pragma unroll
    for (int i = 0; i < 8; ++i) o[i] = 0;
  }
  *(uint4*)(xb + e) = *(const uint4*)o;
}

// ------------- prep: weights fp32 [K,N] -> bf16 transposed [N,K], tiled ------
// wtqkv rows: [0,1536)=Wq^T, [1536,3072)=Wk^T, [3072,3840)=Wv^T ; wot = Wo^T
__global__ __launch_bounds__(256) void prep_w(
    const float* __restrict__ Wq, const float* __restrict__ Wk,
    const float* __restrict__ Wv, const float* __restrict__ Wo,
    u16* __restrict__ wtqkv, u16* __restrict__ wot) {
  __shared__ u16 tile[32][33];
  int blk = blockIdx.x;
  const float* W; int N; u16* dst; int rowbase;
  if (blk < 1152)      { W = Wq; N = 1536; dst = wtqkv; rowbase = 0; }
  else if (blk < 2304) { W = Wk; N = 1536; dst = wtqkv; rowbase = 1536; blk -= 1152; }
  else if (blk < 2880) { W = Wv; N = 768;  dst = wtqkv; rowbase = 3072; blk -= 2304; }
  else                 { W = Wo; N = 768;  dst = wot;   rowbase = 0;    blk -= 2880; }
  const int ntiles = N >> 5;
  const int tk = blk / ntiles, tn = blk - tk * ntiles;
  const int c = threadIdx.x & 31, r0 = threadIdx.x >> 5;
#pragma unroll
  for (int i = 0; i < 4; ++i) {
    int r = i * 8 + r0;
    tile[r][c] = f2bu(W[(size_t)(tk * 32 + r) * N + tn * 32 + c]);
  }
  __syncthreads();
#pragma unroll
  for (int i = 0; i < 4; ++i) {
    int r = i * 8 + r0;
    dst[(size_t)(rowbase + tn * 32 + r) * 768 + tk * 32 + c] = tile[c][r];
  }
}

// ---------------- bf16 MFMA GEMM: C[M,N] = A[M,768] * Bt[N,768]^T ------------
// mode 0: out fp32 [M_ROWS,N] + biasO[n]  (output projection)
// mode 1: LDS-staged coalesced scatter (R9) -> q1/q2/k1/k2 + vt.
// R10: bijective XCD/chunk swizzle (FETCH 218->56MB).
// R11: LDS DOUBLE-BUFFER (attn-R8 structure). Old single-buffer loop was
// stage -> barrier(vmcnt(0) drains JUST-ISSUED loads, zero cover) -> compute
// -> barrier: every iter exposed a full L2/L3 round trip. New: stage tile
// k+1 into buf^1 AFTER the barrier, compute buf cur, then one barrier whose
// vmcnt(0) drain is covered by the ds_read+MFMA phase. 1 barrier/iter.
__global__ __launch_bounds__(256, 2) void gemm_bf16(
    const u16* __restrict__ A, const u16* __restrict__ Bt, int N, int mode,
    float* __restrict__ outF, const float* __restrict__ biasO,
    u16* __restrict__ q1p, u16* __restrict__ q2p,
    u16* __restrict__ k1p, u16* __restrict__ k2p, u16* __restrict__ vtp,
    const float* __restrict__ bq, const float* __restrict__ bk,
    const float* __restrict__ bvp) {
  __shared__ __align__(16) u16 smem[16384];  // 32KB: [buf][lA 4096 | lB 4096]
  const int t = threadIdx.x;
  const int lane = t & 63, wave = t >> 6;
  const int quad = lane >> 4, l16 = lane & 15;
  const int wm = wave & 1, wn = wave >> 1;

  // ---- XCD-locality swizzle (bijective; perf-only) ----
  const int NTg = gridDim.y;
  const int nwg = 73 * NTg;
  const int lin = blockIdx.y * 73 + blockIdx.x;   // dispatch-linear (x fastest)
  const int xcd8 = lin & 7;
  const int idx8 = lin >> 3;
  const int qq = nwg >> 3, rr = nwg & 7;
  const int slot = (xcd8 < rr) ? xcd8 * (qq + 1) + idx8
                               : rr * (qq + 1) + (xcd8 - rr) * qq + idx8;
  const int C = (NTg >= 10) ? 5 : NTg;   // 30 -> 6 chunks of 5; 6 -> 1 chunk
  const int bpc = 73 * C;
  const int chunk = slot / bpc;
  const int rem = slot - chunk * bpc;
  const int mt = rem / C;
  const int nt = chunk * C + (rem - mt * C);
  const int m0 = mt * 128;
  const int n0 = nt * 128;

  f32x4 zero = {0.f, 0.f, 0.f, 0.f};
  f32x4 acc[4][4];
  for (int i = 0; i < 4; ++i) for (int j = 0; j < 4; ++j) acc[i][j] = zero;

  // staging: wave w owns rows w*32..w*32+31 (2 chunks of 16 rows);
  // lane -> row base + lane/4, col (lane%4)*8  (LDS offset == lane*16 B)
  const int srow = wave * 32 + (lane >> 2);
  const int scol = (lane & 3) * 8;
  const u16* gA = A + (size_t)(m0 + srow) * 768 + scol;
  const u16* gB = Bt + (size_t)(n0 + srow) * 768 + scol;
  const int wofs = wave * 1024;

  // ---- prologue: stage K-tile 0 into buf 0 ----
  {
    u16* sA = smem + wofs;
    u16* sB = smem + 4096 + wofs;
    gl2lds16(gA, sA);
    gl2lds16(gA + 16 * 768, sA + 512);
    gl2lds16(gB, sB);
    gl2lds16(gB + 16 * 768, sB + 512);
  }
  __syncthreads();

  int cur = 0;
  for (int k0 = 0; k0 < 768; k0 += 32) {
    // stage next K-tile into buf cur^1 (issued first; drained at the barrier
    // below, after the whole ds_read+MFMA phase has covered its latency)
    if (k0 < 736) {
      u16* sA = smem + (cur ^ 1) * 8192 + wofs;
      u16* sB = smem + (cur ^ 1) * 8192 + 4096 + wofs;
      gl2lds16(gA + k0 + 32, sA);
      gl2lds16(gA + k0 + 32 + 16 * 768, sA + 512);
      gl2lds16(gB + k0 + 32, sB);
      gl2lds16(gB + k0 + 32 + 16 * 768, sB + 512);
    }
    const u16* cA = smem + cur * 8192;
    const u16* cB = smem + cur * 8192 + 4096;
    bf16x8 af[4], bfr[4];
#pragma unroll
    for (int i = 0; i < 4; ++i)
      af[i] = *(const bf16x8*)(cA + (wm * 64 + i * 16 + l16) * 32 + quad * 8);
#pragma unroll
    for (int j = 0; j < 4; ++j)
      bfr[j] = *(const bf16x8*)(cB + (wn * 64 + j * 16 + l16) * 32 + quad * 8);
#pragma unroll
    for (int i = 0; i < 4; ++i)
#pragma unroll
      for (int j = 0; j < 4; ++j)
        acc[i][j] = __builtin_amdgcn_mfma_f32_16x16x32_bf16(af[i], bfr[j], acc[i][j], 0, 0, 0);
    __syncthreads();
    cur ^= 1;
  }

  if (mode == 0) {
#pragma unroll
    for (int i = 0; i < 4; ++i) {
#pragma unroll
      for (int j = 0; j < 4; ++j) {
        int n = n0 + wn * 64 + j * 16 + l16;
#pragma unroll
        for (int r = 0; r < 4; ++r) {
          int m = m0 + wm * 64 + i * 16 + quad * 4 + r;
          if (m >= M_ROWS) continue;
          outF[(size_t)m * N + n] = acc[i][j][r] + biasO[n];
        }
      }
    }
    return;
  }

  // ---------------- mode 1 epilogue: LDS-staged coalesced writes ------------
  u16* tile = smem;   // first 16 KB, staging data is dead now
  const bool isv = (n0 >= 3072);
  u16* dstqk = nullptr; const float* biasp = nullptr; int ch0 = 0;
  if (!isv) {
    if (n0 < 768)       { dstqk = q1p; biasp = bq + n0;          ch0 = n0; }
    else if (n0 < 1536) { dstqk = q2p; biasp = bq + n0;          ch0 = n0 - 768; }
    else if (n0 < 2304) { dstqk = k1p; biasp = bk + (n0 - 1536); ch0 = n0 - 1536; }
    else                { dstqk = k2p; biasp = bk + (n0 - 1536); ch0 = n0 - 2304; }
  }
  const int ch0v = n0 - 3072;

#pragma unroll
  for (int hf = 0; hf < 2; ++hf) {
    __syncthreads();
    if (wn == hf) {
      if (!isv) {
        // tile[m 0..127][col 0..63] (d-major lines), chunk-XOR swizzle by m&3
        float bfv[4];
#pragma unroll
        for (int j = 0; j < 4; ++j) bfv[j] = biasp[hf * 64 + j * 16 + l16];
#pragma unroll
        for (int i = 0; i < 4; ++i)
#pragma unroll
          for (int j = 0; j < 4; ++j) {
            int col = j * 16 + l16;
#pragma unroll
            for (int r = 0; r < 4; ++r) {
              int m = wm * 64 + i * 16 + quad * 4 + r;
              int addr = m * 64 + (col & 15) + ((((col >> 4) ^ (m & 3)) & 3) << 4);
              tile[addr] = f2bu(acc[i][j][r] + bfv[j]);
            }
          }
      } else {
        // transposed: tile[d 0..63][s 0..127], chunk-XOR swizzle by d&7
        float bfv[4];
#pragma unroll
        for (int j = 0; j < 4; ++j) bfv[j] = bvp[ch0v + hf * 64 + j * 16 + l16];
#pragma unroll
        for (int i = 0; i < 4; ++i)
#pragma unroll
          for (int j = 0; j < 4; ++j) {
            int d = j * 16 + l16;
#pragma unroll
            for (int r = 0; r < 4; ++r) {
              int m = wm * 64 + i * 16 + quad * 4 + r;   // s within tile
              int addr = d * 128 + (m & 15) + ((((m >> 4) ^ (d & 7)) & 7) << 4);
              tile[addr] = f2bu(acc[i][j][r] + bfv[j]);
            }
          }
      }
    }
    __syncthreads();

    if (!isv) {
      // 128 lines of 128B: line = m (one s, one head); 8 threads x uint4 each
      const int line = t >> 3;
      const int col0 = (t & 7) * 8;
      const int head = (ch0 >> 6) + hf;
#pragma unroll
      for (int p = 0; p < 4; ++p) {
        int m = p * 32 + line;
        int mg = m0 + m;
        if (mg < M_ROWS) {
          int addr = m * 64 + (col0 & 15) + ((((col0 >> 4) ^ (m & 3)) & 3) << 4);
          uint4 v4 = *(const uint4*)(tile + addr);
          int b = mg / 577;
          int s = mg - b * 577;
          *(uint4*)(dstqk + (((size_t)(b * 12 + head) * 577 + s) * 64 + col0)) = v4;
        }
      }
    } else {
      // 64 lines of 256B: line = d; 16 threads x uint4 each (s-contiguous)
      const int line = t >> 4;
      const int col0 = (t & 15) * 8;
      const int hh = (ch0v >> 6) + hf;
#pragma unroll
      for (int p = 0; p < 4; ++p) {
        int d = p * 16 + line;
        int addr = d * 128 + (col0 & 15) + ((((col0 >> 4) ^ (d & 7)) & 7) << 4);
        uint4 v4 = *(const uint4*)(tile + addr);
        int sg0 = m0 + col0;
        int b0 = sg0 / 577, b7 = (sg0 + 7) / 577;
        if (sg0 + 7 < M_ROWS && b0 == b7) {
          *(uint4*)(vtp + (((size_t)(b0 * 12 + hh) * 64 + d) * VT_STRIDE + (sg0 - b0 * 577))) = v4;
        } else {
          const u16* ev = (const u16*)&v4;
          for (int e = 0; e < 8; ++e) {
            int sg = sg0 + e;
            if (sg >= M_ROWS) break;
            int bb = sg / 577;
            vtp[((size_t)(bb * 12 + hh) * 64 + d) * VT_STRIDE + (sg - bb * 577)] = ev[e];
          }
        }
      }
    }
  }
}

// ---------------- flash-style differential attention (no-max softmax) --------
// R8: shared-LDS KV staging (T3-lite 2-phase template). 4 waves per block
// share one bh; K1/K2/V KV-block tiles staged once into double-buffered LDS
// via global_load_lds (per-wave global loads 12 -> 3/4 each iter; block
// request volume /4). Next block staged while current computes; the
// compiler's vmcnt(0)-before-barrier drains it. K tiles XOR-swizzled on the
// SOURCE address (rule 21) so stride-128B ds_read_b128 is conflict-free;
// V uses a 4-slot swizzle. Tail masking peeled (18 unmasked + 1 masked).
// Per-wave compute pipeline identical to the R5 kernel (known-good).
__global__ __launch_bounds__(256, 4) void attn(
    const u16* __restrict__ q1, const u16* __restrict__ q2,
    const u16* __restrict__ k1, const u16* __restrict__ k2,
    const u16* __restrict__ vt, u16* __restrict__ ctx_t,
    const float* __restrict__ lam_p) {
  __shared__ u16 sk1[2][2048];      // [buf][32 kv rows][64], rows 128B, swizzled
  __shared__ u16 sk2[2][2048];
  __shared__ u16 sv[2][2048];       // [buf][64 d rows][32 kv], rows 64B, swizzled
  __shared__ u16 pls[4][2][16 * 40];// per-wave P staging (D-layout -> A-layout)

  const int tid = threadIdx.x;
  const int wave = tid >> 6;
  const int lane = tid & 63;
  const int quad = lane >> 4, l16 = lane & 15;

  // XCD-locality decode: 1920 blocks = 8 xcd * (24 bh * 10 qgroups), bh-major
  const int bid = blockIdx.x;
  const int xcd = bid & 7;
  const int slot = bid >> 3;            // 0..239
  const int bhl = slot / 10;
  const int qgroup = slot - bhl * 10;
  const int bh = xcd * 24 + bhl;
  const int q0 = (qgroup * 4 + wave) * 16;   // may exceed 576 (idle-ish wave)

  const float lam = lam_p[0];
  const float CEXP = 0.125f * 1.44269504f;   // scale * log2(e), folded
  const size_t qkbase = (size_t)bh * S_LEN * DH;
  const size_t vbase = (size_t)bh * 64 * VT_STRIDE;

  // ---- staging geometry (per thread, constant) ----
  // K tile: 32 rows x 128B; thread -> row tid/8, 16B slot tid%8; source col
  // pre-swizzled so LDS[row][cb] = G[row][cb ^ ((row&7)<<4)]
  const int krow = tid >> 3;
  const int kelem = ((((tid & 7) << 4) ^ ((krow & 7) << 4)) >> 1); // 0..56
  const u16* k1s = k1 + qkbase + (size_t)krow * 64 + kelem;
  const u16* k2s = k2 + qkbase + (size_t)krow * 64 + kelem;
  // V tile: 64 rows x 64B; thread -> row tid/4, slot tid%4;
  // LDS[row][cb] = G[row][cb ^ ((row&3)<<4)]
  const int vrow = tid >> 2;
  const int vel = ((((tid & 3) << 4) ^ ((vrow & 3) << 4)) >> 1);   // 0,8,16,24
  const u16* vs = vt + vbase + (size_t)vrow * VT_STRIDE + vel;
  const int w512 = wave * 512;   // per-wave LDS chunk (1024 B) for staging

  // ---- q fragments (registers, whole kernel) ----
  int qr = q0 + l16; if (qr > 576) qr = 576;   // clamp tail (results discarded)
  bf16x8 q1f[2], q2f[2];
#pragma unroll
  for (int c = 0; c < 2; ++c) {
    q1f[c] = *(const bf16x8*)(q1 + qkbase + (size_t)qr * 64 + c * 32 + quad * 8);
    q2f[c] = *(const bf16x8*)(q2 + qkbase + (size_t)qr * 64 + c * 32 + quad * 8);
  }

  f32x4 zero = {0.f, 0.f, 0.f, 0.f};
  f32x4 O1[4], O2[4];
  float l1[4], l2[4];
#pragma unroll
  for (int i = 0; i < 4; ++i) { O1[i] = zero; O2[i] = zero; l1[i] = 0.f; l2[i] = 0.f; }

  u16* p1w = &pls[wave][0][0];
  u16* p2w = &pls[wave][1][0];

  // read-side swizzle constants
  const int xk = (l16 & 7) << 4;
  const int xv = (l16 & 3) << 4;

  // ---- prologue: stage KV block 0 into buf 0 ----
  gl2lds16(k1s, &sk1[0][0] + w512);
  gl2lds16(k2s, &sk2[0][0] + w512);
  gl2lds16(vs, &sv[0][0] + w512);
  __syncthreads();   // compiler emits vmcnt(0) before s_barrier

  int cur = 0;
  for (int kb = 0; kb < 18; ++kb) {
    // stage next KV block into buf cur^1 (async; drained at the barrier)
    if (kb < 17) {
      gl2lds16(k1s + (kb + 1) * 2048, &sk1[cur ^ 1][0] + w512);
      gl2lds16(k2s + (kb + 1) * 2048, &sk2[cur ^ 1][0] + w512);
      gl2lds16(vs + (kb + 1) * 32, &sv[cur ^ 1][0] + w512);
    } else {
      // final block: all K rows clamp to row 576 (masked in the peel)
      gl2lds16(k1 + qkbase + 576 * 64 + kelem, &sk1[cur ^ 1][0] + w512);
      gl2lds16(k2 + qkbase + 576 * 64 + kelem, &sk2[cur ^ 1][0] + w512);
      gl2lds16(vs + 576, &sv[cur ^ 1][0] + w512);
    }

    // LDS -> register fragments (swizzled reads)
    const char* bk1 = (const char*)&sk1[cur][0];
    const char* bk2 = (const char*)&sk2[cur][0];
    const char* bv = (const char*)&sv[cur][0];
    bf16x8 k1f[2][2], k2f[2][2], vf[4];
#pragma unroll
    for (int tt = 0; tt < 2; ++tt) {
      int rb = (tt * 16 + l16) * 128;
      k1f[tt][0] = *(const bf16x8*)(bk1 + rb + ((quad * 16) ^ xk));
      k1f[tt][1] = *(const bf16x8*)(bk1 + rb + ((64 + quad * 16) ^ xk));
      k2f[tt][0] = *(const bf16x8*)(bk2 + rb + ((quad * 16) ^ xk));
      k2f[tt][1] = *(const bf16x8*)(bk2 + rb + ((64 + quad * 16) ^ xk));
    }
#pragma unroll
    for (int tt = 0; tt < 4; ++tt)
      vf[tt] = *(const bf16x8*)(bv + (tt * 16 + l16) * 64 + ((quad * 16) ^ xv));

    f32x4 s1[2], s2[2];
    __builtin_amdgcn_s_setprio(1);
#pragma unroll
    for (int tt = 0; tt < 2; ++tt) {
      s1[tt] = __builtin_amdgcn_mfma_f32_16x16x32_bf16(q1f[0], k1f[tt][0], zero, 0, 0, 0);
      s1[tt] = __builtin_amdgcn_mfma_f32_16x16x32_bf16(q1f[1], k1f[tt][1], s1[tt], 0, 0, 0);
      s2[tt] = __builtin_amdgcn_mfma_f32_16x16x32_bf16(q2f[0], k2f[tt][0], zero, 0, 0, 0);
      s2[tt] = __builtin_amdgcn_mfma_f32_16x16x32_bf16(q2f[1], k2f[tt][1], s2[tt], 0, 0, 0);
    }
    __builtin_amdgcn_s_setprio(0);

    // unmasked exp + partial sums + P staging (kv rows all < 577 here)
#pragma unroll
    for (int i = 0; i < 4; ++i) {
      float p10 = exp2f(s1[0][i] * CEXP);
      float p11 = exp2f(s1[1][i] * CEXP);
      float p20 = exp2f(s2[0][i] * CEXP);
      float p21 = exp2f(s2[1][i] * CEXP);
      l1[i] += p10 + p11;
      l2[i] += p20 + p21;
      // truncating bf16 convert (cheap; ~0.1% bias, well under budget)
      p1w[(quad * 4 + i) * 40 + l16]      = (u16)(__float_as_uint(p10) >> 16);
      p1w[(quad * 4 + i) * 40 + l16 + 16] = (u16)(__float_as_uint(p11) >> 16);
      p2w[(quad * 4 + i) * 40 + l16]      = (u16)(__float_as_uint(p20) >> 16);
      p2w[(quad * 4 + i) * 40 + l16 + 16] = (u16)(__float_as_uint(p21) >> 16);
    }
    bf16x8 p1a = *(const bf16x8*)(p1w + l16 * 40 + quad * 8);
    bf16x8 p2a = *(const bf16x8*)(p2w + l16 * 40 + quad * 8);
    __builtin_amdgcn_s_setprio(1);
#pragma unroll
    for (int tt = 0; tt < 4; ++tt) {
      O1[tt] = __builtin_amdgcn_mfma_f32_16x16x32_bf16(p1a, vf[tt], O1[tt], 0, 0, 0);
      O2[tt] = __builtin_amdgcn_mfma_f32_16x16x32_bf16(p2a, vf[tt], O2[tt], 0, 0, 0);
    }
    __builtin_amdgcn_s_setprio(0);
    __syncthreads();
    cur ^= 1;
  }

  // ---- peeled final block (kv0 = 576): only kv==576 (l16==0, tt==0) valid
  {
    const char* bk1 = (const char*)&sk1[cur][0];
    const char* bk2 = (const char*)&sk2[cur][0];
    const char* bv = (const char*)&sv[cur][0];
    int rb = l16 * 128;
    bf16x8 ka0 = *(const bf16x8*)(bk1 + rb + ((quad * 16) ^ xk));
    bf16x8 ka1 = *(const bf16x8*)(bk1 + rb + ((64 + quad * 16) ^ xk));
    bf16x8 kb0 = *(const bf16x8*)(bk2 + rb + ((quad * 16) ^ xk));
    bf16x8 kb1 = *(const bf16x8*)(bk2 + rb + ((64 + quad * 16) ^ xk));
    f32x4 s1t = __builtin_amdgcn_mfma_f32_16x16x32_bf16(q1f[0], ka0, zero, 0, 0, 0);
    s1t = __builtin_amdgcn_mfma_f32_16x16x32_bf16(q1f[1], ka1, s1t, 0, 0, 0);
    f32x4 s2t = __builtin_amdgcn_mfma_f32_16x16x32_bf16(q2f[0], kb0, zero, 0, 0, 0);
    s2t = __builtin_amdgcn_mfma_f32_16x16x32_bf16(q2f[1], kb1, s2t, 0, 0, 0);
    bf16x8 vf[4];
#pragma unroll
    for (int tt = 0; tt < 4; ++tt)
      vf[tt] = *(const bf16x8*)(bv + (tt * 16 + l16) * 64 + ((quad * 16) ^ xv));
    bool ok = (l16 == 0);
#pragma unroll
    for (int i = 0; i < 4; ++i) {
      float p10 = ok ? exp2f(s1t[i] * CEXP) : 0.f;
      float p20 = ok ? exp2f(s2t[i] * CEXP) : 0.f;
      l1[i] += p10; l2[i] += p20;
      p1w[(quad * 4 + i) * 40 + l16]      = (u16)(__float_as_uint(p10) >> 16);
      p1w[(quad * 4 + i) * 40 + l16 + 16] = 0;
      p2w[(quad * 4 + i) * 40 + l16]      = (u16)(__float_as_uint(p20) >> 16);
      p2w[(quad * 4 + i) * 40 + l16 + 16] = 0;
    }
    bf16x8 p1a = *(const bf16x8*)(p1w + l16 * 40 + quad * 8);
    bf16x8 p2a = *(const bf16x8*)(p2w + l16 * 40 + quad * 8);
#pragma unroll
    for (int tt = 0; tt < 4; ++tt) {
      O1[tt] = __builtin_amdgcn_mfma_f32_16x16x32_bf16(p1a, vf[tt], O1[tt], 0, 0, 0);
      O2[tt] = __builtin_amdgcn_mfma_f32_16x16x32_bf16(p2a, vf[tt], O2[tt], 0, 0, 0);
    }
  }

  // reduce partial row-sums across the quad's 16 lanes
#pragma unroll
  for (int d = 1; d < 16; d <<= 1)
#pragma unroll
    for (int i = 0; i < 4; ++i) {
      l1[i] += __shfl_xor(l1[i], d);
      l2[i] += __shfl_xor(l2[i], d);
    }
  float inv1[4], inv2[4];
#pragma unroll
  for (int i = 0; i < 4; ++i) { inv1[i] = 1.f / l1[i]; inv2[i] = 1.f / l2[i]; }
#pragma unroll
  for (int tt = 0; tt < 4; ++tt) {
    size_t cb = ((size_t)bh * 64 + tt * 16 + l16) * S_LEN;
#pragma unroll
    for (int i = 0; i < 4; ++i) {
      int s = q0 + quad * 4 + i;
      if (s < S_LEN)
        ctx_t[cb + s] = f2bu(O1[tt][i] * inv1[i] - lam * O2[tt][i] * inv2[i]);
    }
  }
}

// ---------------- GroupNorm over (b,h): Dh*S elements, then affine ----------
// ctx_t [B,H,64,S] -> context flat [B][D*S] (== reference's reinterpret trick)
__global__ __launch_bounds__(256) void gnorm(
    const u16* __restrict__ ctx_t, u16* __restrict__ context,
    const float* __restrict__ gw, const float* __restrict__ gb) {
  const int bh = blockIdx.x;
  const int h = bh % 12;
  const int NEL = 64 * S_LEN;          // 36928
  const int NV = NEL / 8;              // 4616
  const u16* src = ctx_t + (size_t)bh * NEL;
  float sum = 0.f, sq = 0.f;
  for (int v = threadIdx.x; v < NV; v += 256) {
    uint4 raw = *(const uint4*)(src + v * 8);
    uint32_t w[4] = {raw.x, raw.y, raw.z, raw.w};
#pragma unroll
    for (int j = 0; j < 4; ++j) {
      float f0 = bu2f((u16)(w[j] & 0xffff));
      float f1 = bu2f((u16)(w[j] >> 16));
      sum += f0 + f1; sq += f0 * f0 + f1 * f1;
    }
  }
#pragma unroll
  for (int d = 1; d < 64; d <<= 1) {
    sum += __shfl_xor(sum, d);
    sq += __shfl_xor(sq, d);
  }
  __shared__ float rs[4], rq[4];
  __shared__ float wv[64], bv2[64];
  int wave = threadIdx.x >> 6;
  if ((threadIdx.x & 63) == 0) { rs[wave] = sum; rq[wave] = sq; }
  __syncthreads();
  float ts = rs[0] + rs[1] + rs[2] + rs[3];
  float tq = rq[0] + rq[1] + rq[2] + rq[3];
  const float Ninv = 1.0f / (float)NEL;
  float mu = ts * Ninv;
  float var = tq * Ninv - mu * mu;
  float rstd = rsqrtf(var + 1e-5f);
  if (threadIdx.x < 64) {
    float w = gw[h * 64 + threadIdx.x] * rstd;
    wv[threadIdx.x] = w;
    bv2[threadIdx.x] = gb[h * 64 + threadIdx.x] - mu * w;
  }
  __syncthreads();
  u16* dst = context + (size_t)bh * NEL;   // b*(768*577) + h*(64*577)
  for (int v = threadIdx.x; v < NV; v += 256) {
    uint4 raw = *(const uint4*)(src + v * 8);
    uint32_t w[4] = {raw.x, raw.y, raw.z, raw.w};
    int base = v * 8;
    int d0 = base / 577;
    int r0 = base - d0 * 577;
    u16 o[8];
#pragma unroll
    for (int j = 0; j < 4; ++j) {
#pragma unroll
      for (int e = 0; e < 2; ++e) {
        int ii = j * 2 + e;
        int dd = (r0 + ii >= 577) ? d0 + 1 : d0;
        float f = bu2f((u16)(e == 0 ? (w[j] & 0xffff) : (w[j] >> 16)));
        o[ii] = f2bu(f * wv[dd] + bv2[dd]);
      }
    }
    *(uint4*)(dst + base) = *(const uint4*)o;
  }
}

extern "C" void kernel_launch(void* const* d_in, const int* in_sizes, int n_in,
                              void* d_out, int out_size, void* d_ws, size_t ws_size,
                              hipStream_t stream) {
  const float* x   = (const float*)d_in[0];
  const float* Wq  = (const float*)d_in[1];
  const float* bq  = (const float*)d_in[2];
  const float* Wk  = (const float*)d_in[3];
  const float* bk  = (const float*)d_in[4];
  const float* Wv  = (const float*)d_in[5];
  const float* bv  = (const float*)d_in[6];
  const float* Wo  = (const float*)d_in[7];
  const float* bo  = (const float*)d_in[8];
  const float* lam = (const float*)d_in[9];
  const float* gw  = (const float*)d_in[10];
  const float* gb  = (const float*)d_in[11];
  float* out = (float*)d_out;

  char* p = (char*)d_ws;
  auto alloc = [&](size_t bytes) {
    char* r = p;
    p += (bytes + 255) & ~(size_t)255;
    return r;
  };
  u16* xb     = (u16*)alloc((size_t)M_PAD * 768 * 2);   // also reused as ctxbuf
  u16* wtqkv  = (u16*)alloc((size_t)3840 * 768 * 2);
  u16* wot    = (u16*)alloc((size_t)768 * 768 * 2);
  u16* q1b    = (u16*)alloc((size_t)192 * 577 * 64 * 2);
  u16* q2b    = (u16*)alloc((size_t)192 * 577 * 64 * 2);
  u16* k1b    = (u16*)alloc((size_t)192 * 577 * 64 * 2);
  u16* k2b    = (u16*)alloc((size_t)192 * 577 * 64 * 2);
  u16* vtb    = (u16*)alloc((size_t)192 * 64 * VT_STRIDE * 2);
  u16* ctxt   = (u16*)alloc((size_t)192 * 64 * S_LEN * 2);
  u16* ctxbuf = xb;   // alias: xb is dead after the QKV GEMM; keeps ws ~108 MB

  prep_x<<<(M_PAD * 768 / 8 + 255) / 256, 256, 0, stream>>>(x, xb);
  prep_w<<<3456, 256, 0, stream>>>(Wq, Wk, Wv, Wo, wtqkv, wot);

  gemm_bf16<<<dim3(73, 30), 256, 0, stream>>>(xb, wtqkv, 3840, 1,
      nullptr, nullptr, q1b, q2b, k1b, k2b, vtb, bq, bk, bv);

  attn<<<dim3(1920), 256, 0, stream>>>(q1b, q2b, k1b, k2b, vtb, ctxt, lam);

  gnorm<<<192, 256, 0, stream>>>(ctxt, ctxbuf, gw, gb);

  gemm_bf16<<<dim3(73, 6), 256, 0, stream>>>(ctxbuf, wot, 768, 0,
      out, bo, nullptr, nullptr, nullptr, nullptr, nullptr, nullptr, nullptr, nullptr);
}

// Round 8
// 295.334 us; speedup vs baseline: 1.8237x; 1.0360x over previous
//
#include <hip/hip_runtime.h>
#include <hip/hip_bf16.h>
#include <stdint.h>

typedef unsigned short u16;
typedef __attribute__((ext_vector_type(8))) short bf16x8;
typedef __attribute__((ext_vector_type(4))) float f32x4;

#define S_LEN 577
#define DMODEL 768
#define NHEAD 12
#define DH 64
#define BATCH 16
#define M_ROWS (BATCH * S_LEN)   /* 9232 */
#define M_PAD 9344               /* 73 * 128 */
#define VT_STRIDE 640            /* padded S so 16B frag loads stay aligned */
#define CEXPF 0.18033688f        /* 0.125 * log2(e), folded into Q at the GEMM */

__device__ __forceinline__ u16 f2bu(float f) {
  uint32_t u = __float_as_uint(f);
  u += 0x7FFFu + ((u >> 16) & 1u);      // RNE; inputs are finite
  return (u16)(u >> 16);
}
__device__ __forceinline__ float bu2f(u16 b) {
  return __uint_as_float(((uint32_t)b) << 16);
}
// async global->LDS, 16B per lane; LDS dest = wave-uniform base + lane*16
__device__ __forceinline__ void gl2lds16(const u16* g, u16* l) {
  __builtin_amdgcn_global_load_lds(
      (const __attribute__((address_space(1))) unsigned int*)g,
      (__attribute__((address_space(3))) unsigned int*)l, 16, 0, 0);
}

// ---------------- prep: x fp32 -> bf16 [M_PAD,768], pad rows zeroed ----------
// R12: also zeroes the gnorm stats buffer (192*2 floats) before attn runs.
__global__ __launch_bounds__(256) void prep_x(const float* __restrict__ x,
                                              u16* __restrict__ xb,
                                              float* __restrict__ stats) {
  if (blockIdx.x == 0 && threadIdx.x < 384) stats[threadIdx.x] = 0.f;
  int e = (blockIdx.x * 256 + threadIdx.x) * 8;
  u16 o[8];
  if (e < M_ROWS * DMODEL) {
    float4 f0 = *(const float4*)(x + e);
    float4 f1 = *(const float4*)(x + e + 4);
    o[0] = f2bu(f0.x); o[1] = f2bu(f0.y); o[2] = f2bu(f0.z); o[3] = f2bu(f0.w);
    o[4] = f2bu(f1.x); o[5] = f2bu(f1.y); o[6] = f2bu(f1.z); o[7] = f2bu(f1.w);
  } else {
#pragma unroll
    for (int i = 0; i < 8; ++i) o[i] = 0;
  }
  *(uint4*)(xb + e) = *(const uint4*)o;
}

// ------------- prep: weights fp32 [K,N] -> bf16 transposed [N,K], tiled ------
// wtqkv rows: [0,1536)=Wq^T, [1536,3072)=Wk^T, [3072,3840)=Wv^T ; wot = Wo^T
__global__ __launch_bounds__(256) void prep_w(
    const float* __restrict__ Wq, const float* __restrict__ Wk,
    const float* __restrict__ Wv, const float* __restrict__ Wo,
    u16* __restrict__ wtqkv, u16* __restrict__ wot) {
  __shared__ u16 tile[32][33];
  int blk = blockIdx.x;
  const float* W; int N; u16* dst; int rowbase;
  if (blk < 1152)      { W = Wq; N = 1536; dst = wtqkv; rowbase = 0; }
  else if (blk < 2304) { W = Wk; N = 1536; dst = wtqkv; rowbase = 1536; blk -= 1152; }
  else if (blk < 2880) { W = Wv; N = 768;  dst = wtqkv; rowbase = 3072; blk -= 2304; }
  else                 { W = Wo; N = 768;  dst = wot;   rowbase = 0;    blk -= 2880; }
  const int ntiles = N >> 5;
  const int tk = blk / ntiles, tn = blk - tk * ntiles;
  const int c = threadIdx.x & 31, r0 = threadIdx.x >> 5;
#pragma unroll
  for (int i = 0; i < 4; ++i) {
    int r = i * 8 + r0;
    tile[r][c] = f2bu(W[(size_t)(tk * 32 + r) * N + tn * 32 + c]);
  }
  __syncthreads();
#pragma unroll
  for (int i = 0; i < 4; ++i) {
    int r = i * 8 + r0;
    dst[(size_t)(rowbase + tn * 32 + r) * 768 + tk * 32 + c] = tile[c][r];
  }
}

// ---------------- bf16 MFMA GEMM: C[M,N] = A[M,768] * Bt[N,768]^T ------------
// mode 0: out fp32 [M_ROWS,N] + biasO[n]  (output projection)
// mode 1: LDS-staged coalesced scatter (R9) -> q1/q2/k1/k2 + vt.
// R10: bijective XCD/chunk swizzle. R11: LDS double-buffer, 1 barrier/iter.
// R12: q1/q2 outputs are pre-scaled by CEXPF (softmax scale*log2e folded in
// fp32 here, so attn can call exp2f(s) directly).
__global__ __launch_bounds__(256, 2) void gemm_bf16(
    const u16* __restrict__ A, const u16* __restrict__ Bt, int N, int mode,
    float* __restrict__ outF, const float* __restrict__ biasO,
    u16* __restrict__ q1p, u16* __restrict__ q2p,
    u16* __restrict__ k1p, u16* __restrict__ k2p, u16* __restrict__ vtp,
    const float* __restrict__ bq, const float* __restrict__ bk,
    const float* __restrict__ bvp) {
  __shared__ __align__(16) u16 smem[16384];  // 32KB: [buf][lA 4096 | lB 4096]
  const int t = threadIdx.x;
  const int lane = t & 63, wave = t >> 6;
  const int quad = lane >> 4, l16 = lane & 15;
  const int wm = wave & 1, wn = wave >> 1;

  // ---- XCD-locality swizzle (bijective; perf-only) ----
  const int NTg = gridDim.y;
  const int nwg = 73 * NTg;
  const int lin = blockIdx.y * 73 + blockIdx.x;   // dispatch-linear (x fastest)
  const int xcd8 = lin & 7;
  const int idx8 = lin >> 3;
  const int qq = nwg >> 3, rr = nwg & 7;
  const int slot = (xcd8 < rr) ? xcd8 * (qq + 1) + idx8
                               : rr * (qq + 1) + (xcd8 - rr) * qq + idx8;
  const int C = (NTg >= 10) ? 5 : NTg;   // 30 -> 6 chunks of 5; 6 -> 1 chunk
  const int bpc = 73 * C;
  const int chunk = slot / bpc;
  const int rem = slot - chunk * bpc;
  const int mt = rem / C;
  const int nt = chunk * C + (rem - mt * C);
  const int m0 = mt * 128;
  const int n0 = nt * 128;

  f32x4 zero = {0.f, 0.f, 0.f, 0.f};
  f32x4 acc[4][4];
  for (int i = 0; i < 4; ++i) for (int j = 0; j < 4; ++j) acc[i][j] = zero;

  // staging: wave w owns rows w*32..w*32+31 (2 chunks of 16 rows);
  // lane -> row base + lane/4, col (lane%4)*8  (LDS offset == lane*16 B)
  const int srow = wave * 32 + (lane >> 2);
  const int scol = (lane & 3) * 8;
  const u16* gA = A + (size_t)(m0 + srow) * 768 + scol;
  const u16* gB = Bt + (size_t)(n0 + srow) * 768 + scol;
  const int wofs = wave * 1024;

  // ---- prologue: stage K-tile 0 into buf 0 ----
  {
    u16* sA = smem + wofs;
    u16* sB = smem + 4096 + wofs;
    gl2lds16(gA, sA);
    gl2lds16(gA + 16 * 768, sA + 512);
    gl2lds16(gB, sB);
    gl2lds16(gB + 16 * 768, sB + 512);
  }
  __syncthreads();

  int cur = 0;
  for (int k0 = 0; k0 < 768; k0 += 32) {
    // stage next K-tile into buf cur^1 (issued first; drained at the barrier
    // below, after the whole ds_read+MFMA phase has covered its latency)
    if (k0 < 736) {
      u16* sA = smem + (cur ^ 1) * 8192 + wofs;
      u16* sB = smem + (cur ^ 1) * 8192 + 4096 + wofs;
      gl2lds16(gA + k0 + 32, sA);
      gl2lds16(gA + k0 + 32 + 16 * 768, sA + 512);
      gl2lds16(gB + k0 + 32, sB);
      gl2lds16(gB + k0 + 32 + 16 * 768, sB + 512);
    }
    const u16* cA = smem + cur * 8192;
    const u16* cB = smem + cur * 8192 + 4096;
    bf16x8 af[4], bfr[4];
#pragma unroll
    for (int i = 0; i < 4; ++i)
      af[i] = *(const bf16x8*)(cA + (wm * 64 + i * 16 + l16) * 32 + quad * 8);
#pragma unroll
    for (int j = 0; j < 4; ++j)
      bfr[j] = *(const bf16x8*)(cB + (wn * 64 + j * 16 + l16) * 32 + quad * 8);
#pragma unroll
    for (int i = 0; i < 4; ++i)
#pragma unroll
      for (int j = 0; j < 4; ++j)
        acc[i][j] = __builtin_amdgcn_mfma_f32_16x16x32_bf16(af[i], bfr[j], acc[i][j], 0, 0, 0);
    __syncthreads();
    cur ^= 1;
  }

  if (mode == 0) {
#pragma unroll
    for (int i = 0; i < 4; ++i) {
#pragma unroll
      for (int j = 0; j < 4; ++j) {
        int n = n0 + wn * 64 + j * 16 + l16;
#pragma unroll
        for (int r = 0; r < 4; ++r) {
          int m = m0 + wm * 64 + i * 16 + quad * 4 + r;
          if (m >= M_ROWS) continue;
          outF[(size_t)m * N + n] = acc[i][j][r] + biasO[n];
        }
      }
    }
    return;
  }

  // ---------------- mode 1 epilogue: LDS-staged coalesced writes ------------
  u16* tile = smem;   // first 16 KB, staging data is dead now
  const bool isv = (n0 >= 3072);
  u16* dstqk = nullptr; const float* biasp = nullptr; int ch0 = 0;
  if (!isv) {
    if (n0 < 768)       { dstqk = q1p; biasp = bq + n0;          ch0 = n0; }
    else if (n0 < 1536) { dstqk = q2p; biasp = bq + n0;          ch0 = n0 - 768; }
    else if (n0 < 2304) { dstqk = k1p; biasp = bk + (n0 - 1536); ch0 = n0 - 1536; }
    else                { dstqk = k2p; biasp = bk + (n0 - 1536); ch0 = n0 - 2304; }
  }
  const float qscl = (n0 < 1536) ? CEXPF : 1.0f;   // fold softmax scale into Q
  const int ch0v = n0 - 3072;

#pragma unroll
  for (int hf = 0; hf < 2; ++hf) {
    __syncthreads();
    if (wn == hf) {
      if (!isv) {
        // tile[m 0..127][col 0..63] (d-major lines), chunk-XOR swizzle by m&3
        float bfv[4];
#pragma unroll
        for (int j = 0; j < 4; ++j) bfv[j] = biasp[hf * 64 + j * 16 + l16];
#pragma unroll
        for (int i = 0; i < 4; ++i)
#pragma unroll
          for (int j = 0; j < 4; ++j) {
            int col = j * 16 + l16;
#pragma unroll
            for (int r = 0; r < 4; ++r) {
              int m = wm * 64 + i * 16 + quad * 4 + r;
              int addr = m * 64 + (col & 15) + ((((col >> 4) ^ (m & 3)) & 3) << 4);
              tile[addr] = f2bu((acc[i][j][r] + bfv[j]) * qscl);
            }
          }
      } else {
        // transposed: tile[d 0..63][s 0..127], chunk-XOR swizzle by d&7
        float bfv[4];
#pragma unroll
        for (int j = 0; j < 4; ++j) bfv[j] = bvp[ch0v + hf * 64 + j * 16 + l16];
#pragma unroll
        for (int i = 0; i < 4; ++i)
#pragma unroll
          for (int j = 0; j < 4; ++j) {
            int d = j * 16 + l16;
#pragma unroll
            for (int r = 0; r < 4; ++r) {
              int m = wm * 64 + i * 16 + quad * 4 + r;   // s within tile
              int addr = d * 128 + (m & 15) + ((((m >> 4) ^ (d & 7)) & 7) << 4);
              tile[addr] = f2bu(acc[i][j][r] + bfv[j]);
            }
          }
      }
    }
    __syncthreads();

    if (!isv) {
      // 128 lines of 128B: line = m (one s, one head); 8 threads x uint4 each
      const int line = t >> 3;
      const int col0 = (t & 7) * 8;
      const int head = (ch0 >> 6) + hf;
#pragma unroll
      for (int p = 0; p < 4; ++p) {
        int m = p * 32 + line;
        int mg = m0 + m;
        if (mg < M_ROWS) {
          int addr = m * 64 + (col0 & 15) + ((((col0 >> 4) ^ (m & 3)) & 3) << 4);
          uint4 v4 = *(const uint4*)(tile + addr);
          int b = mg / 577;
          int s = mg - b * 577;
          *(uint4*)(dstqk + (((size_t)(b * 12 + head) * 577 + s) * 64 + col0)) = v4;
        }
      }
    } else {
      // 64 lines of 256B: line = d; 16 threads x uint4 each (s-contiguous)
      const int line = t >> 4;
      const int col0 = (t & 15) * 8;
      const int hh = (ch0v >> 6) + hf;
#pragma unroll
      for (int p = 0; p < 4; ++p) {
        int d = p * 16 + line;
        int addr = d * 128 + (col0 & 15) + ((((col0 >> 4) ^ (d & 7)) & 7) << 4);
        uint4 v4 = *(const uint4*)(tile + addr);
        int sg0 = m0 + col0;
        int b0 = sg0 / 577, b7 = (sg0 + 7) / 577;
        if (sg0 + 7 < M_ROWS && b0 == b7) {
          *(uint4*)(vtp + (((size_t)(b0 * 12 + hh) * 64 + d) * VT_STRIDE + (sg0 - b0 * 577))) = v4;
        } else {
          const u16* ev = (const u16*)&v4;
          for (int e = 0; e < 8; ++e) {
            int sg = sg0 + e;
            if (sg >= M_ROWS) break;
            int bb = sg / 577;
            vtp[((size_t)(bb * 12 + hh) * 64 + d) * VT_STRIDE + (sg - bb * 577)] = ev[e];
          }
        }
      }
    }
  }
}

// ---------------- flash-style differential attention (no-max softmax) --------
// R8 structure (shared-LDS KV staging, dbuf, source-swizzled). R12 adds:
//  * Q pre-scaled by CEXPF at the GEMM -> exp2f(s) directly (-16 vmul/iter).
//  * idle-wave guard: waves with q0 >= 577 skip all compute (barriers kept).
//  * fused GroupNorm stats: per-block fp32 sum/sumsq -> atomicAdd(stats[bh]).
__global__ __launch_bounds__(256, 4) void attn(
    const u16* __restrict__ q1, const u16* __restrict__ q2,
    const u16* __restrict__ k1, const u16* __restrict__ k2,
    const u16* __restrict__ vt, u16* __restrict__ ctx_t,
    const float* __restrict__ lam_p, float* __restrict__ stats) {
  __shared__ u16 sk1[2][2048];      // [buf][32 kv rows][64], rows 128B, swizzled
  __shared__ u16 sk2[2][2048];
  __shared__ u16 sv[2][2048];       // [buf][64 d rows][32 kv], rows 64B, swizzled
  __shared__ u16 pls[4][2][16 * 40];// per-wave P staging (D-layout -> A-layout)

  const int tid = threadIdx.x;
  const int wave = tid >> 6;
  const int lane = tid & 63;
  const int quad = lane >> 4, l16 = lane & 15;

  // XCD-locality decode: 1920 blocks = 8 xcd * (24 bh * 10 qgroups), bh-major
  const int bid = blockIdx.x;
  const int xcd = bid & 7;
  const int slot = bid >> 3;            // 0..239
  const int bhl = slot / 10;
  const int qgroup = slot - bhl * 10;
  const int bh = xcd * 24 + bhl;
  const int q0 = (qgroup * 4 + wave) * 16;   // may exceed 576 (idle wave)
  const bool active = (q0 < S_LEN);

  const float lam = lam_p[0];
  const size_t qkbase = (size_t)bh * S_LEN * DH;
  const size_t vbase = (size_t)bh * 64 * VT_STRIDE;

  // ---- staging geometry (per thread, constant) ----
  const int krow = tid >> 3;
  const int kelem = ((((tid & 7) << 4) ^ ((krow & 7) << 4)) >> 1); // 0..56
  const u16* k1s = k1 + qkbase + (size_t)krow * 64 + kelem;
  const u16* k2s = k2 + qkbase + (size_t)krow * 64 + kelem;
  const int vrow = tid >> 2;
  const int vel = ((((tid & 3) << 4) ^ ((vrow & 3) << 4)) >> 1);   // 0,8,16,24
  const u16* vs = vt + vbase + (size_t)vrow * VT_STRIDE + vel;
  const int w512 = wave * 512;   // per-wave LDS chunk (1024 B) for staging

  // ---- q fragments (registers, whole kernel) ----
  int qr = q0 + l16; if (qr > 576) qr = 576;   // clamp tail (results discarded)
  bf16x8 q1f[2], q2f[2];
#pragma unroll
  for (int c = 0; c < 2; ++c) {
    q1f[c] = *(const bf16x8*)(q1 + qkbase + (size_t)qr * 64 + c * 32 + quad * 8);
    q2f[c] = *(const bf16x8*)(q2 + qkbase + (size_t)qr * 64 + c * 32 + quad * 8);
  }

  f32x4 zero = {0.f, 0.f, 0.f, 0.f};
  f32x4 O1[4], O2[4];
  float l1[4], l2[4];
#pragma unroll
  for (int i = 0; i < 4; ++i) { O1[i] = zero; O2[i] = zero; l1[i] = 0.f; l2[i] = 0.f; }

  u16* p1w = &pls[wave][0][0];
  u16* p2w = &pls[wave][1][0];

  // read-side swizzle constants
  const int xk = (l16 & 7) << 4;
  const int xv = (l16 & 3) << 4;

  // ---- prologue: stage KV block 0 into buf 0 ----
  gl2lds16(k1s, &sk1[0][0] + w512);
  gl2lds16(k2s, &sk2[0][0] + w512);
  gl2lds16(vs, &sv[0][0] + w512);
  __syncthreads();   // compiler emits vmcnt(0) before s_barrier

  int cur = 0;
  for (int kb = 0; kb < 18; ++kb) {
    // stage next KV block into buf cur^1 (async; drained at the barrier)
    if (kb < 17) {
      gl2lds16(k1s + (kb + 1) * 2048, &sk1[cur ^ 1][0] + w512);
      gl2lds16(k2s + (kb + 1) * 2048, &sk2[cur ^ 1][0] + w512);
      gl2lds16(vs + (kb + 1) * 32, &sv[cur ^ 1][0] + w512);
    } else {
      // final block: all K rows clamp to row 576 (masked in the peel)
      gl2lds16(k1 + qkbase + 576 * 64 + kelem, &sk1[cur ^ 1][0] + w512);
      gl2lds16(k2 + qkbase + 576 * 64 + kelem, &sk2[cur ^ 1][0] + w512);
      gl2lds16(vs + 576, &sv[cur ^ 1][0] + w512);
    }

    if (active) {
      // LDS -> register fragments (swizzled reads)
      const char* bk1 = (const char*)&sk1[cur][0];
      const char* bk2 = (const char*)&sk2[cur][0];
      const char* bv = (const char*)&sv[cur][0];
      bf16x8 k1f[2][2], k2f[2][2], vf[4];
#pragma unroll
      for (int tt = 0; tt < 2; ++tt) {
        int rb = (tt * 16 + l16) * 128;
        k1f[tt][0] = *(const bf16x8*)(bk1 + rb + ((quad * 16) ^ xk));
        k1f[tt][1] = *(const bf16x8*)(bk1 + rb + ((64 + quad * 16) ^ xk));
        k2f[tt][0] = *(const bf16x8*)(bk2 + rb + ((quad * 16) ^ xk));
        k2f[tt][1] = *(const bf16x8*)(bk2 + rb + ((64 + quad * 16) ^ xk));
      }
#pragma unroll
      for (int tt = 0; tt < 4; ++tt)
        vf[tt] = *(const bf16x8*)(bv + (tt * 16 + l16) * 64 + ((quad * 16) ^ xv));

      f32x4 s1[2], s2[2];
      __builtin_amdgcn_s_setprio(1);
#pragma unroll
      for (int tt = 0; tt < 2; ++tt) {
        s1[tt] = __builtin_amdgcn_mfma_f32_16x16x32_bf16(q1f[0], k1f[tt][0], zero, 0, 0, 0);
        s1[tt] = __builtin_amdgcn_mfma_f32_16x16x32_bf16(q1f[1], k1f[tt][1], s1[tt], 0, 0, 0);
        s2[tt] = __builtin_amdgcn_mfma_f32_16x16x32_bf16(q2f[0], k2f[tt][0], zero, 0, 0, 0);
        s2[tt] = __builtin_amdgcn_mfma_f32_16x16x32_bf16(q2f[1], k2f[tt][1], s2[tt], 0, 0, 0);
      }
      __builtin_amdgcn_s_setprio(0);

      // unmasked exp + partial sums + P staging (Q pre-scaled -> exp2f direct)
#pragma unroll
      for (int i = 0; i < 4; ++i) {
        float p10 = exp2f(s1[0][i]);
        float p11 = exp2f(s1[1][i]);
        float p20 = exp2f(s2[0][i]);
        float p21 = exp2f(s2[1][i]);
        l1[i] += p10 + p11;
        l2[i] += p20 + p21;
        // truncating bf16 convert (cheap; ~0.1% bias, well under budget)
        p1w[(quad * 4 + i) * 40 + l16]      = (u16)(__float_as_uint(p10) >> 16);
        p1w[(quad * 4 + i) * 40 + l16 + 16] = (u16)(__float_as_uint(p11) >> 16);
        p2w[(quad * 4 + i) * 40 + l16]      = (u16)(__float_as_uint(p20) >> 16);
        p2w[(quad * 4 + i) * 40 + l16 + 16] = (u16)(__float_as_uint(p21) >> 16);
      }
      bf16x8 p1a = *(const bf16x8*)(p1w + l16 * 40 + quad * 8);
      bf16x8 p2a = *(const bf16x8*)(p2w + l16 * 40 + quad * 8);
      __builtin_amdgcn_s_setprio(1);
#pragma unroll
      for (int tt = 0; tt < 4; ++tt) {
        O1[tt] = __builtin_amdgcn_mfma_f32_16x16x32_bf16(p1a, vf[tt], O1[tt], 0, 0, 0);
        O2[tt] = __builtin_amdgcn_mfma_f32_16x16x32_bf16(p2a, vf[tt], O2[tt], 0, 0, 0);
      }
      __builtin_amdgcn_s_setprio(0);
    }
    __syncthreads();
    cur ^= 1;
  }

  if (active) {
    // ---- peeled final block (kv0 = 576): only kv==576 (l16==0, tt==0) valid
    {
      const char* bk1 = (const char*)&sk1[cur][0];
      const char* bk2 = (const char*)&sk2[cur][0];
      const char* bv = (const char*)&sv[cur][0];
      int rb = l16 * 128;
      bf16x8 ka0 = *(const bf16x8*)(bk1 + rb + ((quad * 16) ^ xk));
      bf16x8 ka1 = *(const bf16x8*)(bk1 + rb + ((64 + quad * 16) ^ xk));
      bf16x8 kb0 = *(const bf16x8*)(bk2 + rb + ((quad * 16) ^ xk));
      bf16x8 kb1 = *(const bf16x8*)(bk2 + rb + ((64 + quad * 16) ^ xk));
      f32x4 s1t = __builtin_amdgcn_mfma_f32_16x16x32_bf16(q1f[0], ka0, zero, 0, 0, 0);
      s1t = __builtin_amdgcn_mfma_f32_16x16x32_bf16(q1f[1], ka1, s1t, 0, 0, 0);
      f32x4 s2t = __builtin_amdgcn_mfma_f32_16x16x32_bf16(q2f[0], kb0, zero, 0, 0, 0);
      s2t = __builtin_amdgcn_mfma_f32_16x16x32_bf16(q2f[1], kb1, s2t, 0, 0, 0);
      bf16x8 vf[4];
#pragma unroll
      for (int tt = 0; tt < 4; ++tt)
        vf[tt] = *(const bf16x8*)(bv + (tt * 16 + l16) * 64 + ((quad * 16) ^ xv));
      bool ok = (l16 == 0);
#pragma unroll
      for (int i = 0; i < 4; ++i) {
        float p10 = ok ? exp2f(s1t[i]) : 0.f;
        float p20 = ok ? exp2f(s2t[i]) : 0.f;
        l1[i] += p10; l2[i] += p20;
        p1w[(quad * 4 + i) * 40 + l16]      = (u16)(__float_as_uint(p10) >> 16);
        p1w[(quad * 4 + i) * 40 + l16 + 16] = 0;
        p2w[(quad * 4 + i) * 40 + l16]      = (u16)(__float_as_uint(p20) >> 16);
        p2w[(quad * 4 + i) * 40 + l16 + 16] = 0;
      }
      bf16x8 p1a = *(const bf16x8*)(p1w + l16 * 40 + quad * 8);
      bf16x8 p2a = *(const bf16x8*)(p2w + l16 * 40 + quad * 8);
#pragma unroll
      for (int tt = 0; tt < 4; ++tt) {
        O1[tt] = __builtin_amdgcn_mfma_f32_16x16x32_bf16(p1a, vf[tt], O1[tt], 0, 0, 0);
        O2[tt] = __builtin_amdgcn_mfma_f32_16x16x32_bf16(p2a, vf[tt], O2[tt], 0, 0, 0);
      }
    }

    // reduce partial row-sums across the quad's 16 lanes
#pragma unroll
    for (int d = 1; d < 16; d <<= 1)
#pragma unroll
      for (int i = 0; i < 4; ++i) {
        l1[i] += __shfl_xor(l1[i], d);
        l2[i] += __shfl_xor(l2[i], d);
      }
    float inv1[4], inv2[4];
#pragma unroll
    for (int i = 0; i < 4; ++i) { inv1[i] = 1.f / l1[i]; inv2[i] = 1.f / l2[i]; }

    float ssum = 0.f, ssq = 0.f;   // fused GroupNorm partial stats (fp32)
#pragma unroll
    for (int tt = 0; tt < 4; ++tt) {
      size_t cb = ((size_t)bh * 64 + tt * 16 + l16) * S_LEN;
#pragma unroll
      for (int i = 0; i < 4; ++i) {
        int s = q0 + quad * 4 + i;
        if (s < S_LEN) {
          float val = O1[tt][i] * inv1[i] - lam * O2[tt][i] * inv2[i];
          ctx_t[cb + s] = f2bu(val);
          ssum += val; ssq += val * val;
        }
      }
    }
#pragma unroll
    for (int d = 1; d < 64; d <<= 1) {
      ssum += __shfl_xor(ssum, d);
      ssq += __shfl_xor(ssq, d);
    }
    if (lane == 0) {
      atomicAdd(&stats[bh * 2], ssum);
      atomicAdd(&stats[bh * 2 + 1], ssq);
    }
  }
}

// ---------------- GroupNorm over (b,h): single pass (stats fused in attn) ---
// ctx_t [B,H,64,S] -> context flat [B][D*S] (== reference's reinterpret trick)
__global__ __launch_bounds__(256) void gnorm(
    const u16* __restrict__ ctx_t, u16* __restrict__ context,
    const float* __restrict__ gw, const float* __restrict__ gb,
    const float* __restrict__ stats) {
  const int bh = blockIdx.x;
  const int h = bh % 12;
  const int NEL = 64 * S_LEN;          // 36928
  const int NV = NEL / 8;              // 4616
  const u16* src = ctx_t + (size_t)bh * NEL;
  const float ts = stats[bh * 2];
  const float tq = stats[bh * 2 + 1];
  const float Ninv = 1.0f / (float)NEL;
  const float mu = ts * Ninv;
  const float var = tq * Ninv - mu * mu;
  const float rstd = rsqrtf(var + 1e-5f);
  __shared__ float wv[64], bv2[64];
  if (threadIdx.x < 64) {
    float w = gw[h * 64 + threadIdx.x] * rstd;
    wv[threadIdx.x] = w;
    bv2[threadIdx.x] = gb[h * 64 + threadIdx.x] - mu * w;
  }
  __syncthreads();
  u16* dst = context + (size_t)bh * NEL;   // b*(768*577) + h*(64*577)
  for (int v = threadIdx.x; v < NV; v += 256) {
    uint4 raw = *(const uint4*)(src + v * 8);
    uint32_t w[4] = {raw.x, raw.y, raw.z, raw.w};
    int base = v * 8;
    int d0 = base / 577;
    int r0 = base - d0 * 577;
    u16 o[8];
#pragma unroll
    for (int j = 0; j < 4; ++j) {
#pragma unroll
      for (int e = 0; e < 2; ++e) {
        int ii = j * 2 + e;
        int dd = (r0 + ii >= 577) ? d0 + 1 : d0;
        float f = bu2f((u16)(e == 0 ? (w[j] & 0xffff) : (w[j] >> 16)));
        o[ii] = f2bu(f * wv[dd] + bv2[dd]);
      }
    }
    *(uint4*)(dst + base) = *(const uint4*)o;
  }
}

extern "C" void kernel_launch(void* const* d_in, const int* in_sizes, int n_in,
                              void* d_out, int out_size, void* d_ws, size_t ws_size,
                              hipStream_t stream) {
  const float* x   = (const float*)d_in[0];
  const float* Wq  = (const float*)d_in[1];
  const float* bq  = (const float*)d_in[2];
  const float* Wk  = (const float*)d_in[3];
  const float* bk  = (const float*)d_in[4];
  const float* Wv  = (const float*)d_in[5];
  const float* bv  = (const float*)d_in[6];
  const float* Wo  = (const float*)d_in[7];
  const float* bo  = (const float*)d_in[8];
  const float* lam = (const float*)d_in[9];
  const float* gw  = (const float*)d_in[10];
  const float* gb  = (const float*)d_in[11];
  float* out = (float*)d_out;

  char* p = (char*)d_ws;
  auto alloc = [&](size_t bytes) {
    char* r = p;
    p += (bytes + 255) & ~(size_t)255;
    return r;
  };
  u16* xb     = (u16*)alloc((size_t)M_PAD * 768 * 2);   // also reused as ctxbuf
  u16* wtqkv  = (u16*)alloc((size_t)3840 * 768 * 2);
  u16* wot    = (u16*)alloc((size_t)768 * 768 * 2);
  u16* q1b    = (u16*)alloc((size_t)192 * 577 * 64 * 2);
  u16* q2b    = (u16*)alloc((size_t)192 * 577 * 64 * 2);
  u16* k1b    = (u16*)alloc((size_t)192 * 577 * 64 * 2);
  u16* k2b    = (u16*)alloc((size_t)192 * 577 * 64 * 2);
  u16* vtb    = (u16*)alloc((size_t)192 * 64 * VT_STRIDE * 2);
  u16* ctxt   = (u16*)alloc((size_t)192 * 64 * S_LEN * 2);
  float* stats = (float*)alloc((size_t)192 * 2 * 4);
  u16* ctxbuf = xb;   // alias: xb is dead after the QKV GEMM; keeps ws ~108 MB

  prep_x<<<(M_PAD * 768 / 8 + 255) / 256, 256, 0, stream>>>(x, xb, stats);
  prep_w<<<3456, 256, 0, stream>>>(Wq, Wk, Wv, Wo, wtqkv, wot);

  gemm_bf16<<<dim3(73, 30), 256, 0, stream>>>(xb, wtqkv, 3840, 1,
      nullptr, nullptr, q1b, q2b, k1b, k2b, vtb, bq, bk, bv);

  attn<<<dim3(1920), 256, 0, stream>>>(q1b, q2b, k1b, k2b, vtb, ctxt, lam, stats);

  gnorm<<<192, 256, 0, stream>>>(ctxt, ctxbuf, gw, gb, stats);

  gemm_bf16<<<dim3(73, 6), 256, 0, stream>>>(ctxbuf, wot, 768, 0,
      out, bo, nullptr, nullptr, nullptr, nullptr, nullptr, nullptr, nullptr, nullptr);
}

// Round 9
// 293.289 us; speedup vs baseline: 1.8365x; 1.0070x over previous
//
#include <hip/hip_runtime.h>
#include <hip/hip_bf16.h>
#include <stdint.h>

typedef unsigned short u16;
typedef __attribute__((ext_vector_type(8))) short bf16x8;
typedef __attribute__((ext_vector_type(4))) float f32x4;

#define S_LEN 577
#define DMODEL 768
#define NHEAD 12
#define DH 64
#define BATCH 16
#define M_ROWS (BATCH * S_LEN)   /* 9232 */
#define M_PAD 9344               /* 73 * 128 */
#define VT_STRIDE 640            /* padded S so 16B frag loads stay aligned */
#define CEXPF 0.18033688f        /* 0.125 * log2(e), folded into Q at the GEMM */

__device__ __forceinline__ u16 f2bu(float f) {
  uint32_t u = __float_as_uint(f);
  u += 0x7FFFu + ((u >> 16) & 1u);      // RNE; inputs are finite
  return (u16)(u >> 16);
}
__device__ __forceinline__ float bu2f(u16 b) {
  return __uint_as_float(((uint32_t)b) << 16);
}
// async global->LDS, 16B per lane; LDS dest = wave-uniform base + lane*16
__device__ __forceinline__ void gl2lds16(const u16* g, u16* l) {
  __builtin_amdgcn_global_load_lds(
      (const __attribute__((address_space(1))) unsigned int*)g,
      (__attribute__((address_space(3))) unsigned int*)l, 16, 0, 0);
}

// ---------------- prep: x fp32 -> bf16 [M_PAD,768], pad rows zeroed ----------
// R12: also zeroes the gnorm stats buffer (192*2 floats) before attn runs.
__global__ __launch_bounds__(256) void prep_x(const float* __restrict__ x,
                                              u16* __restrict__ xb,
                                              float* __restrict__ stats) {
  if (blockIdx.x == 0 && threadIdx.x < 384) stats[threadIdx.x] = 0.f;
  int e = (blockIdx.x * 256 + threadIdx.x) * 8;
  u16 o[8];
  if (e < M_ROWS * DMODEL) {
    float4 f0 = *(const float4*)(x + e);
    float4 f1 = *(const float4*)(x + e + 4);
    o[0] = f2bu(f0.x); o[1] = f2bu(f0.y); o[2] = f2bu(f0.z); o[3] = f2bu(f0.w);
    o[4] = f2bu(f1.x); o[5] = f2bu(f1.y); o[6] = f2bu(f1.z); o[7] = f2bu(f1.w);
  } else {
#pragma unroll
    for (int i = 0; i < 8; ++i) o[i] = 0;
  }
  *(uint4*)(xb + e) = *(const uint4*)o;
}

// ------------- prep: weights fp32 [K,N] -> bf16 transposed [N,K], tiled ------
// wtqkv rows: [0,1536)=Wq^T, [1536,3072)=Wk^T, [3072,3840)=Wv^T ; wot = Wo^T
__global__ __launch_bounds__(256) void prep_w(
    const float* __restrict__ Wq, const float* __restrict__ Wk,
    const float* __restrict__ Wv, const float* __restrict__ Wo,
    u16* __restrict__ wtqkv, u16* __restrict__ wot) {
  __shared__ u16 tile[32][33];
  int blk = blockIdx.x;
  const float* W; int N; u16* dst; int rowbase;
  if (blk < 1152)      { W = Wq; N = 1536; dst = wtqkv; rowbase = 0; }
  else if (blk < 2304) { W = Wk; N = 1536; dst = wtqkv; rowbase = 1536; blk -= 1152; }
  else if (blk < 2880) { W = Wv; N = 768;  dst = wtqkv; rowbase = 3072; blk -= 2304; }
  else                 { W = Wo; N = 768;  dst = wot;   rowbase = 0;    blk -= 2880; }
  const int ntiles = N >> 5;
  const int tk = blk / ntiles, tn = blk - tk * ntiles;
  const int c = threadIdx.x & 31, r0 = threadIdx.x >> 5;
#pragma unroll
  for (int i = 0; i < 4; ++i) {
    int r = i * 8 + r0;
    tile[r][c] = f2bu(W[(size_t)(tk * 32 + r) * N + tn * 32 + c]);
  }
  __syncthreads();
#pragma unroll
  for (int i = 0; i < 4; ++i) {
    int r = i * 8 + r0;
    dst[(size_t)(rowbase + tn * 32 + r) * 768 + tk * 32 + c] = tile[c][r];
  }
}

// ---------------- bf16 MFMA GEMM: C[M,N] = A[M,768] * Bt[N,768]^T ------------
// mode 0: out fp32 [M_ROWS,N] + biasO[n]  (output projection)
// mode 1: LDS-staged coalesced scatter (R9) -> q1/q2/k1/k2 + vt.
// R10: bijective XCD/chunk swizzle. R11: LDS double-buffer, 1 barrier/iter.
// R12: q1/q2 outputs pre-scaled by CEXPF.
__global__ __launch_bounds__(256, 2) void gemm_bf16(
    const u16* __restrict__ A, const u16* __restrict__ Bt, int N, int mode,
    float* __restrict__ outF, const float* __restrict__ biasO,
    u16* __restrict__ q1p, u16* __restrict__ q2p,
    u16* __restrict__ k1p, u16* __restrict__ k2p, u16* __restrict__ vtp,
    const float* __restrict__ bq, const float* __restrict__ bk,
    const float* __restrict__ bvp) {
  __shared__ __align__(16) u16 smem[16384];  // 32KB: [buf][lA 4096 | lB 4096]
  const int t = threadIdx.x;
  const int lane = t & 63, wave = t >> 6;
  const int quad = lane >> 4, l16 = lane & 15;
  const int wm = wave & 1, wn = wave >> 1;

  // ---- XCD-locality swizzle (bijective; perf-only) ----
  const int NTg = gridDim.y;
  const int nwg = 73 * NTg;
  const int lin = blockIdx.y * 73 + blockIdx.x;   // dispatch-linear (x fastest)
  const int xcd8 = lin & 7;
  const int idx8 = lin >> 3;
  const int qq = nwg >> 3, rr = nwg & 7;
  const int slot = (xcd8 < rr) ? xcd8 * (qq + 1) + idx8
                               : rr * (qq + 1) + (xcd8 - rr) * qq + idx8;
  const int C = (NTg >= 10) ? 5 : NTg;   // 30 -> 6 chunks of 5; 6 -> 1 chunk
  const int bpc = 73 * C;
  const int chunk = slot / bpc;
  const int rem = slot - chunk * bpc;
  const int mt = rem / C;
  const int nt = chunk * C + (rem - mt * C);
  const int m0 = mt * 128;
  const int n0 = nt * 128;

  f32x4 zero = {0.f, 0.f, 0.f, 0.f};
  f32x4 acc[4][4];
  for (int i = 0; i < 4; ++i) for (int j = 0; j < 4; ++j) acc[i][j] = zero;

  // staging: wave w owns rows w*32..w*32+31 (2 chunks of 16 rows);
  // lane -> row base + lane/4, col (lane%4)*8  (LDS offset == lane*16 B)
  const int srow = wave * 32 + (lane >> 2);
  const int scol = (lane & 3) * 8;
  const u16* gA = A + (size_t)(m0 + srow) * 768 + scol;
  const u16* gB = Bt + (size_t)(n0 + srow) * 768 + scol;
  const int wofs = wave * 1024;

  // ---- prologue: stage K-tile 0 into buf 0 ----
  {
    u16* sA = smem + wofs;
    u16* sB = smem + 4096 + wofs;
    gl2lds16(gA, sA);
    gl2lds16(gA + 16 * 768, sA + 512);
    gl2lds16(gB, sB);
    gl2lds16(gB + 16 * 768, sB + 512);
  }
  __syncthreads();

  int cur = 0;
  for (int k0 = 0; k0 < 768; k0 += 32) {
    // stage next K-tile into buf cur^1 (issued first; drained at the barrier
    // below, after the whole ds_read+MFMA phase has covered its latency)
    if (k0 < 736) {
      u16* sA = smem + (cur ^ 1) * 8192 + wofs;
      u16* sB = smem + (cur ^ 1) * 8192 + 4096 + wofs;
      gl2lds16(gA + k0 + 32, sA);
      gl2lds16(gA + k0 + 32 + 16 * 768, sA + 512);
      gl2lds16(gB + k0 + 32, sB);
      gl2lds16(gB + k0 + 32 + 16 * 768, sB + 512);
    }
    const u16* cA = smem + cur * 8192;
    const u16* cB = smem + cur * 8192 + 4096;
    bf16x8 af[4], bfr[4];
#pragma unroll
    for (int i = 0; i < 4; ++i)
      af[i] = *(const bf16x8*)(cA + (wm * 64 + i * 16 + l16) * 32 + quad * 8);
#pragma unroll
    for (int j = 0; j < 4; ++j)
      bfr[j] = *(const bf16x8*)(cB + (wn * 64 + j * 16 + l16) * 32 + quad * 8);
#pragma unroll
    for (int i = 0; i < 4; ++i)
#pragma unroll
      for (int j = 0; j < 4; ++j)
        acc[i][j] = __builtin_amdgcn_mfma_f32_16x16x32_bf16(af[i], bfr[j], acc[i][j], 0, 0, 0);
    __syncthreads();
    cur ^= 1;
  }

  if (mode == 0) {
#pragma unroll
    for (int i = 0; i < 4; ++i) {
#pragma unroll
      for (int j = 0; j < 4; ++j) {
        int n = n0 + wn * 64 + j * 16 + l16;
#pragma unroll
        for (int r = 0; r < 4; ++r) {
          int m = m0 + wm * 64 + i * 16 + quad * 4 + r;
          if (m >= M_ROWS) continue;
          outF[(size_t)m * N + n] = acc[i][j][r] + biasO[n];
        }
      }
    }
    return;
  }

  // ---------------- mode 1 epilogue: LDS-staged coalesced writes ------------
  u16* tile = smem;   // first 16 KB, staging data is dead now
  const bool isv = (n0 >= 3072);
  u16* dstqk = nullptr; const float* biasp = nullptr; int ch0 = 0;
  if (!isv) {
    if (n0 < 768)       { dstqk = q1p; biasp = bq + n0;          ch0 = n0; }
    else if (n0 < 1536) { dstqk = q2p; biasp = bq + n0;          ch0 = n0 - 768; }
    else if (n0 < 2304) { dstqk = k1p; biasp = bk + (n0 - 1536); ch0 = n0 - 1536; }
    else                { dstqk = k2p; biasp = bk + (n0 - 1536); ch0 = n0 - 2304; }
  }
  const float qscl = (n0 < 1536) ? CEXPF : 1.0f;   // fold softmax scale into Q
  const int ch0v = n0 - 3072;

#pragma unroll
  for (int hf = 0; hf < 2; ++hf) {
    __syncthreads();
    if (wn == hf) {
      if (!isv) {
        // tile[m 0..127][col 0..63] (d-major lines), chunk-XOR swizzle by m&3
        float bfv[4];
#pragma unroll
        for (int j = 0; j < 4; ++j) bfv[j] = biasp[hf * 64 + j * 16 + l16];
#pragma unroll
        for (int i = 0; i < 4; ++i)
#pragma unroll
          for (int j = 0; j < 4; ++j) {
            int col = j * 16 + l16;
#pragma unroll
            for (int r = 0; r < 4; ++r) {
              int m = wm * 64 + i * 16 + quad * 4 + r;
              int addr = m * 64 + (col & 15) + ((((col >> 4) ^ (m & 3)) & 3) << 4);
              tile[addr] = f2bu((acc[i][j][r] + bfv[j]) * qscl);
            }
          }
      } else {
        // transposed: tile[d 0..63][s 0..127], chunk-XOR swizzle by d&7
        float bfv[4];
#pragma unroll
        for (int j = 0; j < 4; ++j) bfv[j] = bvp[ch0v + hf * 64 + j * 16 + l16];
#pragma unroll
        for (int i = 0; i < 4; ++i)
#pragma unroll
          for (int j = 0; j < 4; ++j) {
            int d = j * 16 + l16;
#pragma unroll
            for (int r = 0; r < 4; ++r) {
              int m = wm * 64 + i * 16 + quad * 4 + r;   // s within tile
              int addr = d * 128 + (m & 15) + ((((m >> 4) ^ (d & 7)) & 7) << 4);
              tile[addr] = f2bu(acc[i][j][r] + bfv[j]);
            }
          }
      }
    }
    __syncthreads();

    if (!isv) {
      // 128 lines of 128B: line = m (one s, one head); 8 threads x uint4 each
      const int line = t >> 3;
      const int col0 = (t & 7) * 8;
      const int head = (ch0 >> 6) + hf;
#pragma unroll
      for (int p = 0; p < 4; ++p) {
        int m = p * 32 + line;
        int mg = m0 + m;
        if (mg < M_ROWS) {
          int addr = m * 64 + (col0 & 15) + ((((col0 >> 4) ^ (m & 3)) & 3) << 4);
          uint4 v4 = *(const uint4*)(tile + addr);
          int b = mg / 577;
          int s = mg - b * 577;
          *(uint4*)(dstqk + (((size_t)(b * 12 + head) * 577 + s) * 64 + col0)) = v4;
        }
      }
    } else {
      // 64 lines of 256B: line = d; 16 threads x uint4 each (s-contiguous)
      const int line = t >> 4;
      const int col0 = (t & 15) * 8;
      const int hh = (ch0v >> 6) + hf;
#pragma unroll
      for (int p = 0; p < 4; ++p) {
        int d = p * 16 + line;
        int addr = d * 128 + (col0 & 15) + ((((col0 >> 4) ^ (d & 7)) & 7) << 4);
        uint4 v4 = *(const uint4*)(tile + addr);
        int sg0 = m0 + col0;
        int b0 = sg0 / 577, b7 = (sg0 + 7) / 577;
        if (sg0 + 7 < M_ROWS && b0 == b7) {
          *(uint4*)(vtp + (((size_t)(b0 * 12 + hh) * 64 + d) * VT_STRIDE + (sg0 - b0 * 577))) = v4;
        } else {
          const u16* ev = (const u16*)&v4;
          for (int e = 0; e < 8; ++e) {
            int sg = sg0 + e;
            if (sg >= M_ROWS) break;
            int bb = sg / 577;
            vtp[((size_t)(bb * 12 + hh) * 64 + d) * VT_STRIDE + (sg - bb * 577)] = ev[e];
          }
        }
      }
    }
  }
}

// ---------------- flash-style differential attention (no-max softmax) --------
// R8 structure (shared-LDS KV staging, dbuf, source-swizzled) + R12 fusions.
// R13: SWAPPED QK^T — s = mfma(K,Q) gives C[k][q], so each lane's 4 P-values
// per (tt,stream) are column-adjacent in the [q][k] staging layout:
// 32 scalar ds_write_b16 (4-way conflicted) -> 4 packed ds_write_b64
// (conflict-free). Row-sums become 2 lane-local scalars (reduce = 2 shfl).
// P-staging READ layout unchanged ([q][k], stride 40).
__global__ __launch_bounds__(256, 4) void attn(
    const u16* __restrict__ q1, const u16* __restrict__ q2,
    const u16* __restrict__ k1, const u16* __restrict__ k2,
    const u16* __restrict__ vt, u16* __restrict__ ctx_t,
    const float* __restrict__ lam_p, float* __restrict__ stats) {
  __shared__ u16 sk1[2][2048];      // [buf][32 kv rows][64], rows 128B, swizzled
  __shared__ u16 sk2[2][2048];
  __shared__ u16 sv[2][2048];       // [buf][64 d rows][32 kv], rows 64B, swizzled
  __shared__ u16 pls[4][2][16 * 40];// per-wave P staging, layout [q][k] pad 40

  const int tid = threadIdx.x;
  const int wave = tid >> 6;
  const int lane = tid & 63;
  const int quad = lane >> 4, l16 = lane & 15;

  // XCD-locality decode: 1920 blocks = 8 xcd * (24 bh * 10 qgroups), bh-major
  const int bid = blockIdx.x;
  const int xcd = bid & 7;
  const int slot = bid >> 3;            // 0..239
  const int bhl = slot / 10;
  const int qgroup = slot - bhl * 10;
  const int bh = xcd * 24 + bhl;
  const int q0 = (qgroup * 4 + wave) * 16;   // may exceed 576 (idle wave)
  const bool active = (q0 < S_LEN);

  const float lam = lam_p[0];
  const size_t qkbase = (size_t)bh * S_LEN * DH;
  const size_t vbase = (size_t)bh * 64 * VT_STRIDE;

  // ---- staging geometry (per thread, constant) ----
  const int krow = tid >> 3;
  const int kelem = ((((tid & 7) << 4) ^ ((krow & 7) << 4)) >> 1); // 0..56
  const u16* k1s = k1 + qkbase + (size_t)krow * 64 + kelem;
  const u16* k2s = k2 + qkbase + (size_t)krow * 64 + kelem;
  const int vrow = tid >> 2;
  const int vel = ((((tid & 3) << 4) ^ ((vrow & 3) << 4)) >> 1);   // 0,8,16,24
  const u16* vs = vt + vbase + (size_t)vrow * VT_STRIDE + vel;
  const int w512 = wave * 512;   // per-wave LDS chunk (1024 B) for staging

  // ---- q fragments (registers, whole kernel) ----
  int qr = q0 + l16; if (qr > 576) qr = 576;   // clamp tail (results discarded)
  bf16x8 q1f[2], q2f[2];
#pragma unroll
  for (int c = 0; c < 2; ++c) {
    q1f[c] = *(const bf16x8*)(q1 + qkbase + (size_t)qr * 64 + c * 32 + quad * 8);
    q2f[c] = *(const bf16x8*)(q2 + qkbase + (size_t)qr * 64 + c * 32 + quad * 8);
  }

  f32x4 zero = {0.f, 0.f, 0.f, 0.f};
  f32x4 O1[4], O2[4];
#pragma unroll
  for (int i = 0; i < 4; ++i) { O1[i] = zero; O2[i] = zero; }
  float l1p = 0.f, l2p = 0.f;   // lane-local partial row-sums (q-row = l16)

  u16* p1w = &pls[wave][0][0];
  u16* p2w = &pls[wave][1][0];

  // read-side swizzle constants
  const int xk = (l16 & 7) << 4;
  const int xv = (l16 & 3) << 4;

  // ---- prologue: stage KV block 0 into buf 0 ----
  gl2lds16(k1s, &sk1[0][0] + w512);
  gl2lds16(k2s, &sk2[0][0] + w512);
  gl2lds16(vs, &sv[0][0] + w512);
  __syncthreads();   // compiler emits vmcnt(0) before s_barrier

  int cur = 0;
  for (int kb = 0; kb < 18; ++kb) {
    // stage next KV block into buf cur^1 (async; drained at the barrier)
    if (kb < 17) {
      gl2lds16(k1s + (kb + 1) * 2048, &sk1[cur ^ 1][0] + w512);
      gl2lds16(k2s + (kb + 1) * 2048, &sk2[cur ^ 1][0] + w512);
      gl2lds16(vs + (kb + 1) * 32, &sv[cur ^ 1][0] + w512);
    } else {
      // final block: all K rows clamp to row 576 (masked in the peel)
      gl2lds16(k1 + qkbase + 576 * 64 + kelem, &sk1[cur ^ 1][0] + w512);
      gl2lds16(k2 + qkbase + 576 * 64 + kelem, &sk2[cur ^ 1][0] + w512);
      gl2lds16(vs + 576, &sv[cur ^ 1][0] + w512);
    }

    if (active) {
      // LDS -> register fragments (swizzled reads)
      const char* bk1 = (const char*)&sk1[cur][0];
      const char* bk2 = (const char*)&sk2[cur][0];
      const char* bv = (const char*)&sv[cur][0];
      bf16x8 k1f[2][2], k2f[2][2], vf[4];
#pragma unroll
      for (int tt = 0; tt < 2; ++tt) {
        int rb = (tt * 16 + l16) * 128;
        k1f[tt][0] = *(const bf16x8*)(bk1 + rb + ((quad * 16) ^ xk));
        k1f[tt][1] = *(const bf16x8*)(bk1 + rb + ((64 + quad * 16) ^ xk));
        k2f[tt][0] = *(const bf16x8*)(bk2 + rb + ((quad * 16) ^ xk));
        k2f[tt][1] = *(const bf16x8*)(bk2 + rb + ((64 + quad * 16) ^ xk));
      }
#pragma unroll
      for (int tt = 0; tt < 4; ++tt)
        vf[tt] = *(const bf16x8*)(bv + (tt * 16 + l16) * 64 + ((quad * 16) ^ xv));

      f32x4 s1[2], s2[2];
      __builtin_amdgcn_s_setprio(1);
#pragma unroll
      for (int tt = 0; tt < 2; ++tt) {
        s1[tt] = __builtin_amdgcn_mfma_f32_16x16x32_bf16(k1f[tt][0], q1f[0], zero, 0, 0, 0);
        s1[tt] = __builtin_amdgcn_mfma_f32_16x16x32_bf16(k1f[tt][1], q1f[1], s1[tt], 0, 0, 0);
        s2[tt] = __builtin_amdgcn_mfma_f32_16x16x32_bf16(k2f[tt][0], q2f[0], zero, 0, 0, 0);
        s2[tt] = __builtin_amdgcn_mfma_f32_16x16x32_bf16(k2f[tt][1], q2f[1], s2[tt], 0, 0, 0);
      }
      __builtin_amdgcn_s_setprio(0);

      // exp + lane-local sums + packed b64 P staging.
      // s[tt][i] = S[k = kv0 + tt*16 + quad*4 + i][q = l16]  (swapped C layout)
#pragma unroll
      for (int tt = 0; tt < 2; ++tt) {
        float pa[4], pb[4];
#pragma unroll
        for (int i = 0; i < 4; ++i) {
          pa[i] = exp2f(s1[tt][i]); l1p += pa[i];
          pb[i] = exp2f(s2[tt][i]); l2p += pb[i];
        }
        // truncating bf16 convert (cheap; ~0.1% bias, well under budget)
        uint2 wa, wb;
        wa.x = (__float_as_uint(pa[1]) & 0xffff0000u) | (__float_as_uint(pa[0]) >> 16);
        wa.y = (__float_as_uint(pa[3]) & 0xffff0000u) | (__float_as_uint(pa[2]) >> 16);
        wb.x = (__float_as_uint(pb[1]) & 0xffff0000u) | (__float_as_uint(pb[0]) >> 16);
        wb.y = (__float_as_uint(pb[3]) & 0xffff0000u) | (__float_as_uint(pb[2]) >> 16);
        *(uint2*)(p1w + l16 * 40 + tt * 16 + quad * 4) = wa;
        *(uint2*)(p2w + l16 * 40 + tt * 16 + quad * 4) = wb;
      }
      bf16x8 p1a = *(const bf16x8*)(p1w + l16 * 40 + quad * 8);
      bf16x8 p2a = *(const bf16x8*)(p2w + l16 * 40 + quad * 8);
      __builtin_amdgcn_s_setprio(1);
#pragma unroll
      for (int tt = 0; tt < 4; ++tt) {
        O1[tt] = __builtin_amdgcn_mfma_f32_16x16x32_bf16(p1a, vf[tt], O1[tt], 0, 0, 0);
        O2[tt] = __builtin_amdgcn_mfma_f32_16x16x32_bf16(p2a, vf[tt], O2[tt], 0, 0, 0);
      }
      __builtin_amdgcn_s_setprio(0);
    }
    __syncthreads();
    cur ^= 1;
  }

  if (active) {
    // ---- peeled final block (kv0 = 576): every staged row holds K[576];
    // only (quad==0, i==0) contributes (k == 576).
    {
      const char* bk1 = (const char*)&sk1[cur][0];
      const char* bk2 = (const char*)&sk2[cur][0];
      const char* bv = (const char*)&sv[cur][0];
      int rb = l16 * 128;
      bf16x8 ka0 = *(const bf16x8*)(bk1 + rb + ((quad * 16) ^ xk));
      bf16x8 ka1 = *(const bf16x8*)(bk1 + rb + ((64 + quad * 16) ^ xk));
      bf16x8 kb0 = *(const bf16x8*)(bk2 + rb + ((quad * 16) ^ xk));
      bf16x8 kb1 = *(const bf16x8*)(bk2 + rb + ((64 + quad * 16) ^ xk));
      f32x4 s1t = __builtin_amdgcn_mfma_f32_16x16x32_bf16(ka0, q1f[0], zero, 0, 0, 0);
      s1t = __builtin_amdgcn_mfma_f32_16x16x32_bf16(ka1, q1f[1], s1t, 0, 0, 0);
      f32x4 s2t = __builtin_amdgcn_mfma_f32_16x16x32_bf16(kb0, q2f[0], zero, 0, 0, 0);
      s2t = __builtin_amdgcn_mfma_f32_16x16x32_bf16(kb1, q2f[1], s2t, 0, 0, 0);
      bf16x8 vf[4];
#pragma unroll
      for (int tt = 0; tt < 4; ++tt)
        vf[tt] = *(const bf16x8*)(bv + (tt * 16 + l16) * 64 + ((quad * 16) ^ xv));
      bool okp = (quad == 0);
      float pa[4], pb[4];
#pragma unroll
      for (int i = 0; i < 4; ++i) {
        pa[i] = (okp && i == 0) ? exp2f(s1t[i]) : 0.f;
        pb[i] = (okp && i == 0) ? exp2f(s2t[i]) : 0.f;
        l1p += pa[i]; l2p += pb[i];
      }
      uint2 wa, wb, wz;
      wa.x = (__float_as_uint(pa[1]) & 0xffff0000u) | (__float_as_uint(pa[0]) >> 16);
      wa.y = (__float_as_uint(pa[3]) & 0xffff0000u) | (__float_as_uint(pa[2]) >> 16);
      wb.x = (__float_as_uint(pb[1]) & 0xffff0000u) | (__float_as_uint(pb[0]) >> 16);
      wb.y = (__float_as_uint(pb[3]) & 0xffff0000u) | (__float_as_uint(pb[2]) >> 16);
      wz.x = 0; wz.y = 0;
      *(uint2*)(p1w + l16 * 40 + quad * 4) = wa;        // k 0..15 region
      *(uint2*)(p1w + l16 * 40 + 16 + quad * 4) = wz;   // k 16..31 region = 0
      *(uint2*)(p2w + l16 * 40 + quad * 4) = wb;
      *(uint2*)(p2w + l16 * 40 + 16 + quad * 4) = wz;
      bf16x8 p1a = *(const bf16x8*)(p1w + l16 * 40 + quad * 8);
      bf16x8 p2a = *(const bf16x8*)(p2w + l16 * 40 + quad * 8);
#pragma unroll
      for (int tt = 0; tt < 4; ++tt) {
        O1[tt] = __builtin_amdgcn_mfma_f32_16x16x32_bf16(p1a, vf[tt], O1[tt], 0, 0, 0);
        O2[tt] = __builtin_amdgcn_mfma_f32_16x16x32_bf16(p2a, vf[tt], O2[tt], 0, 0, 0);
      }
    }

    // full row-sums: combine the 4 quads holding the same q-row (l16)
    l1p += __shfl_xor(l1p, 16); l1p += __shfl_xor(l1p, 32);
    l2p += __shfl_xor(l2p, 16); l2p += __shfl_xor(l2p, 32);
    float inv1 = 1.f / l1p, inv2 = 1.f / l2p;   // valid for q-row = l16
    float a1[4], a2[4];
#pragma unroll
    for (int i = 0; i < 4; ++i) {
      a1[i] = __shfl(inv1, quad * 4 + i);   // lane (quad*4+i) holds q-row quad*4+i
      a2[i] = __shfl(inv2, quad * 4 + i);
    }

    float ssum = 0.f, ssq = 0.f;   // fused GroupNorm partial stats (fp32)
#pragma unroll
    for (int tt = 0; tt < 4; ++tt) {
      size_t cb = ((size_t)bh * 64 + tt * 16 + l16) * S_LEN;
#pragma unroll
      for (int i = 0; i < 4; ++i) {
        int s = q0 + quad * 4 + i;
        if (s < S_LEN) {
          float val = O1[tt][i] * a1[i] - lam * O2[tt][i] * a2[i];
          ctx_t[cb + s] = f2bu(val);
          ssum += val; ssq += val * val;
        }
      }
    }
#pragma unroll
    for (int d = 1; d < 64; d <<= 1) {
      ssum += __shfl_xor(ssum, d);
      ssq += __shfl_xor(ssq, d);
    }
    if (lane == 0) {
      atomicAdd(&stats[bh * 2], ssum);
      atomicAdd(&stats[bh * 2 + 1], ssq);
    }
  }
}

// ---------------- GroupNorm over (b,h): single pass (stats fused in attn) ---
// ctx_t [B,H,64,S] -> context flat [B][D*S] (== reference's reinterpret trick)
__global__ __launch_bounds__(256) void gnorm(
    const u16* __restrict__ ctx_t, u16* __restrict__ context,
    const float* __restrict__ gw, const float* __restrict__ gb,
    const float* __restrict__ stats) {
  const int bh = blockIdx.x;
  const int h = bh % 12;
  const int NEL = 64 * S_LEN;          // 36928
  const int NV = NEL / 8;              // 4616
  const u16* src = ctx_t + (size_t)bh * NEL;
  const float ts = stats[bh * 2];
  const float tq = stats[bh * 2 + 1];
  const float Ninv = 1.0f / (float)NEL;
  const float mu = ts * Ninv;
  const float var = tq * Ninv - mu * mu;
  const float rstd = rsqrtf(var + 1e-5f);
  __shared__ float wv[64], bv2[64];
  if (threadIdx.x < 64) {
    float w = gw[h * 64 + threadIdx.x] * rstd;
    wv[threadIdx.x] = w;
    bv2[threadIdx.x] = gb[h * 64 + threadIdx.x] - mu * w;
  }
  __syncthreads();
  u16* dst = context + (size_t)bh * NEL;   // b*(768*577) + h*(64*577)
  for (int v = threadIdx.x; v < NV; v += 256) {
    uint4 raw = *(const uint4*)(src + v * 8);
    uint32_t w[4] = {raw.x, raw.y, raw.z, raw.w};
    int base = v * 8;
    int d0 = base / 577;
    int r0 = base - d0 * 577;
    u16 o[8];
#pragma unroll
    for (int j = 0; j < 4; ++j) {
#pragma unroll
      for (int e = 0; e < 2; ++e) {
        int ii = j * 2 + e;
        int dd = (r0 + ii >= 577) ? d0 + 1 : d0;
        float f = bu2f((u16)(e == 0 ? (w[j] & 0xffff) : (w[j] >> 16)));
        o[ii] = f2bu(f * wv[dd] + bv2[dd]);
      }
    }
    *(uint4*)(dst + base) = *(const uint4*)o;
  }
}

extern "C" void kernel_launch(void* const* d_in, const int* in_sizes, int n_in,
                              void* d_out, int out_size, void* d_ws, size_t ws_size,
                              hipStream_t stream) {
  const float* x   = (const float*)d_in[0];
  const float* Wq  = (const float*)d_in[1];
  const float* bq  = (const float*)d_in[2];
  const float* Wk  = (const float*)d_in[3];
  const float* bk  = (const float*)d_in[4];
  const float* Wv  = (const float*)d_in[5];
  const float* bv  = (const float*)d_in[6];
  const float* Wo  = (const float*)d_in[7];
  const float* bo  = (const float*)d_in[8];
  const float* lam = (const float*)d_in[9];
  const float* gw  = (const float*)d_in[10];
  const float* gb  = (const float*)d_in[11];
  float* out = (float*)d_out;

  char* p = (char*)d_ws;
  auto alloc = [&](size_t bytes) {
    char* r = p;
    p += (bytes + 255) & ~(size_t)255;
    return r;
  };
  u16* xb     = (u16*)alloc((size_t)M_PAD * 768 * 2);   // also reused as ctxbuf
  u16* wtqkv  = (u16*)alloc((size_t)3840 * 768 * 2);
  u16* wot    = (u16*)alloc((size_t)768 * 768 * 2);
  u16* q1b    = (u16*)alloc((size_t)192 * 577 * 64 * 2);
  u16* q2b    = (u16*)alloc((size_t)192 * 577 * 64 * 2);
  u16* k1b    = (u16*)alloc((size_t)192 * 577 * 64 * 2);
  u16* k2b    = (u16*)alloc((size_t)192 * 577 * 64 * 2);
  u16* vtb    = (u16*)alloc((size_t)192 * 64 * VT_STRIDE * 2);
  u16* ctxt   = (u16*)alloc((size_t)192 * 64 * S_LEN * 2);
  float* stats = (float*)alloc((size_t)192 * 2 * 4);
  u16* ctxbuf = xb;   // alias: xb is dead after the QKV GEMM; keeps ws ~108 MB

  prep_x<<<(M_PAD * 768 / 8 + 255) / 256, 256, 0, stream>>>(x, xb, stats);
  prep_w<<<3456, 256, 0, stream>>>(Wq, Wk, Wv, Wo, wtqkv, wot);

  gemm_bf16<<<dim3(73, 30), 256, 0, stream>>>(xb, wtqkv, 3840, 1,
      nullptr, nullptr, q1b, q2b, k1b, k2b, vtb, bq, bk, bv);

  attn<<<dim3(1920), 256, 0, stream>>>(q1b, q2b, k1b, k2b, vtb, ctxt, lam, stats);

  gnorm<<<192, 256, 0, stream>>>(ctxt, ctxbuf, gw, gb, stats);

  gemm_bf16<<<dim3(73, 6), 256, 0, stream>>>(ctxbuf, wot, 768, 0,
      out, bo, nullptr, nullptr, nullptr, nullptr, nullptr, nullptr, nullptr, nullptr);
}